// Round 11
// baseline (312.202 us; speedup 1.0000x reference)
//
#include <hip/hip_runtime.h>
#include <hip/hip_bf16.h>
#include <stdint.h>

#define N_ALL   16384
#define NPOINT  4096
#define KNN_K   32
#define BATCH   2
#define P_TOT   (BATCH*NPOINT*KNN_K)   /* 262144 */
#define P_TOTF  262144.0f
#define EPSV    1e-5f

typedef __attribute__((ext_vector_type(8))) short bf16x8;
typedef __attribute__((ext_vector_type(4))) float f32x4;

// ---- all scratch in module-static device memory; d_ws untouched ----
__device__ unsigned short g_knn[P_TOT];                                   // 512 KB
__device__ __attribute__((aligned(16))) float g_pxyzn[BATCH*N_ALL*4];     // 512 KB (x,y,z,|x|^2)
__device__ __attribute__((aligned(16))) short g_ptb[BATCH*N_ALL*64];      // 4 MB  [b,n][64c] bf16
__device__ __attribute__((aligned(16))) short g_x0b[(size_t)P_TOT*64];    // 32 MB [p][64] bf16
__device__ __attribute__((aligned(16))) short g_x1b[(size_t)P_TOT*64];    // 32 MB
__device__ __attribute__((aligned(16))) short g_x2b[(size_t)P_TOT*128];   // 64 MB
__device__ __attribute__((aligned(16))) float g_mx[(size_t)BATCH*NPOINT*128];  // 4 MB
__device__ __attribute__((aligned(16))) float g_mn[(size_t)BATCH*NPOINT*128];  // 4 MB
__device__ __attribute__((aligned(16))) short g_Wb0[4*3*64*8];            // swizzled A-frags
__device__ __attribute__((aligned(16))) short g_Wb1[4*2*64*8];
__device__ __attribute__((aligned(16))) short g_Wb2[8*2*64*8];
__device__ float g_part0[128], g_part1[128], g_part2[256];

__device__ __forceinline__ float b2f(short s) {
  union { unsigned u; float f; } v; v.u = ((unsigned)(unsigned short)s) << 16; return v.f;
}
__device__ __forceinline__ short f2b(float f) {
  union { float f; unsigned u; } v; v.f = f;
  unsigned u = v.u;
  u += 0x7FFFu + ((u >> 16) & 1u);
  return (short)(u >> 16);
}
// packed f32x2 -> bf16x2 (v_cvt_pk_bf16_f32, RNE — bit-identical to f2b pairs)
__device__ __forceinline__ unsigned pkbf(float a, float b) {
  union { __hip_bfloat162 h; unsigned u; } v;
  v.h = __float22bfloat162_rn(make_float2(a, b));
  return v.u;
}
__device__ __forceinline__ unsigned long long bperm64(unsigned long long v, int byteaddr) {
  int lo = __builtin_amdgcn_ds_bpermute(byteaddr, (int)(unsigned)(v & 0xFFFFFFFFULL));
  int hi = __builtin_amdgcn_ds_bpermute(byteaddr, (int)(unsigned)(v >> 32));
  return (((unsigned long long)(unsigned)hi) << 32) | (unsigned)lo;
}
__device__ __forceinline__ unsigned long long u64min(unsigned long long a, unsigned long long b) {
  return a < b ? a : b;
}
// bitonic compare-exchange step: keep min (mx=0) or max (mx=1) of (v, pv)
__device__ __forceinline__ unsigned long long selstage(unsigned long long v,
                                                       unsigned long long pv, bool mx) {
  bool lt = v < pv;
  return (lt != mx) ? v : pv;
}

// sort 32 buffered candidates (vB, one per lane within a 32-lane half) ascending,
// merge lowest-32 of (vL ∪ vB) back into vL (sorted), refresh worst_hi/wd.
__device__ __forceinline__ void knn_merge32(unsigned long long& vL,
                                            unsigned long long& worst,
                                            unsigned& worst_hi, float& wd,
                                            unsigned long long vB, int hl,
                                            int aX1, int aX2, int aX4, int aX8,
                                            int aX16, int aRev, int aW) {
  vB = selstage(vB, bperm64(vB, aX1),  ((hl & 1) != 0) != ((hl & 2) != 0));
  vB = selstage(vB, bperm64(vB, aX2),  ((hl & 2) != 0) != ((hl & 4) != 0));
  vB = selstage(vB, bperm64(vB, aX1),  ((hl & 1) != 0) != ((hl & 4) != 0));
  vB = selstage(vB, bperm64(vB, aX4),  ((hl & 4) != 0) != ((hl & 8) != 0));
  vB = selstage(vB, bperm64(vB, aX2),  ((hl & 2) != 0) != ((hl & 8) != 0));
  vB = selstage(vB, bperm64(vB, aX1),  ((hl & 1) != 0) != ((hl & 8) != 0));
  vB = selstage(vB, bperm64(vB, aX8),  ((hl & 8) != 0) != ((hl & 16) != 0));
  vB = selstage(vB, bperm64(vB, aX4),  ((hl & 4) != 0) != ((hl & 16) != 0));
  vB = selstage(vB, bperm64(vB, aX2),  ((hl & 2) != 0) != ((hl & 16) != 0));
  vB = selstage(vB, bperm64(vB, aX1),  ((hl & 1) != 0) != ((hl & 16) != 0));
  vB = selstage(vB, bperm64(vB, aX16), (hl & 16) != 0);
  vB = selstage(vB, bperm64(vB, aX8),  (hl & 8) != 0);
  vB = selstage(vB, bperm64(vB, aX4),  (hl & 4) != 0);
  vB = selstage(vB, bperm64(vB, aX2),  (hl & 2) != 0);
  vB = selstage(vB, bperm64(vB, aX1),  (hl & 1) != 0);
  // vL asc, vB asc: pair lane i with reversed buffer -> lowest 32 (bitonic), then cleanup
  vL = u64min(vL, bperm64(vB, aRev));
  vL = selstage(vL, bperm64(vL, aX16), (hl & 16) != 0);
  vL = selstage(vL, bperm64(vL, aX8),  (hl & 8) != 0);
  vL = selstage(vL, bperm64(vL, aX4),  (hl & 4) != 0);
  vL = selstage(vL, bperm64(vL, aX2),  (hl & 2) != 0);
  vL = selstage(vL, bperm64(vL, aX1),  (hl & 1) != 0);
  worst = bperm64(vL, aW);
  worst_hi = (unsigned)(worst >> 32);
  unsigned wh = worst_hi;
  unsigned ub = (wh & 0x80000000u) ? (wh ^ 0x80000000u) : ~wh;
  wd = (wh == 0xFFFFFFFFu) ? __builtin_inff() : __uint_as_float(ub);
}

// ---------------- setup: tpose (blk<512) | copy+pack (512..639) | wprep (640) ----------------
__global__ __launch_bounds__(256) void k_setup(const float* __restrict__ xyz,
                                               const float* __restrict__ points,
                                               const float* __restrict__ W0,
                                               const float* __restrict__ W1,
                                               const float* __restrict__ W2,
                                               float* __restrict__ out) {
#pragma clang fp contract(off)
  __shared__ float tile[64][65];
  int blk = blockIdx.x;
  int t = threadIdx.x;
  if (blk < 512) {
    int b  = blk >> 8;
    int n0 = (blk & 255) << 6;
#pragma unroll
    for (int r = 0; r < 16; r++) {
      int lin = r * 256 + t;
      int c = lin >> 6, nn = lin & 63;
      tile[c][nn] = points[((size_t)(b * 64 + c)) * N_ALL + n0 + nn];
    }
    __syncthreads();
#pragma unroll
    for (int r = 0; r < 16; r++) {
      int lin = r * 256 + t;
      int nn = lin >> 6, c = lin & 63;
      g_ptb[((size_t)(b * N_ALL + n0 + nn)) * 64 + c] = f2b(tile[c][nn]);
    }
  } else if (blk < 640) {
    int i = (blk - 512) * 256 + t;   // < 32768
    if (i < 24576) {
      int s = i & 4095;
      int c = (i >> 12) % 3;
      int b = i / 12288;
      out[i] = xyz[(b * 3 + c) * N_ALL + s];
    }
    int b = i >> 14, n = i & 16383;
    const float* xb = xyz + b * 3 * N_ALL;
    float x = xb[n], y = xb[N_ALL + n], z = xb[2 * N_ALL + n];
    float4 p; p.x = x; p.y = y; p.z = z; p.w = x * x + y * y + z * z;
    ((float4*)g_pxyzn)[i] = p;
  } else {
    for (int i = t; i < 4 * 3 * 64 * 8; i += 256) {
      int j = i & 7, lane = (i >> 3) & 63, rest = i >> 9;
      int kt = rest % 3, mt = rest / 3;
      int m = 16 * mt + (lane & 15);
      int k = 32 * kt + (lane >> 4) * 8 + j;
      float v = 0.f;
      if (k < 64) v = W0[m * 67 + 3 + k];
      else if (k < 67) v = W0[m * 67 + (k - 64)];
      g_Wb0[i] = f2b(v);
    }
    for (int i = t; i < 4 * 2 * 64 * 8; i += 256) {
      int j = i & 7, lane = (i >> 3) & 63;
      int kt = (i >> 9) & 1, mt = i >> 10;
      int m = 16 * mt + (lane & 15);
      int k = 32 * kt + (lane >> 4) * 8 + j;
      g_Wb1[i] = f2b(W1[m * 64 + k]);
    }
    for (int i = t; i < 8 * 2 * 64 * 8; i += 256) {
      int j = i & 7, lane = (i >> 3) & 63;
      int kt = (i >> 9) & 1, mt = i >> 10;
      int m = 16 * mt + (lane & 15);
      int k = 32 * kt + (lane >> 4) * 8 + j;
      g_Wb2[i] = f2b(W2[m * 64 + k]);
    }
    if (t < 128) { g_part0[t] = 0.f; g_part1[t] = 0.f; }
    g_part2[t] = 0.f;
  }
}

// ---------------- KNN: split-N 2-way, 2 queries/wave, float gate + survivor-only keys ----------------
__global__ __launch_bounds__(256, 8) void k_knn() {
#pragma clang fp contract(off)
  __shared__ unsigned long long buf[4][2][64];
  int wv = threadIdx.x >> 6;
  int lane = threadIdx.x & 63;
  int half = lane >> 5;            // 0: lanes 0..31 (query A), 1: lanes 32..63 (query B)
  int hl = lane & 31;
  int lanebase = lane & 32;
  unsigned long long* bufh = buf[wv][half];

  int qpair = wv >> 1;             // waves {0,1} share queries, {2,3} share queries
  int range = wv & 1;              // 0: points [0,8192), 1: [8192,16384)
  int q = blockIdx.x * 4 + qpair * 2 + half;   // 0..8191
  int b = q >> 12, s = q & 4095;
  const float4* pb = (const float4*)g_pxyzn + (b << 14);
  float4 qp = pb[s];
  float qx = qp.x, qy = qp.y, qz = qp.z, qn = qp.w;

  // hoisted cross-lane byte addresses (stay within own 32-lane half)
  int aX1  = (lanebase | (hl ^ 1))  << 2;
  int aX2  = (lanebase | (hl ^ 2))  << 2;
  int aX4  = (lanebase | (hl ^ 4))  << 2;
  int aX8  = (lanebase | (hl ^ 8))  << 2;
  int aX16 = (lanebase | (hl ^ 16)) << 2;
  int aRev = (lanebase | (31 - hl)) << 2;
  int aW   = (lanebase | 31)        << 2;

  unsigned long long vL = ~0ULL;      // per-half sorted top-32 (ascending by lane)
  unsigned long long worst = ~0ULL;   // per-lane copy of own half's vL[31]
  unsigned worst_hi = 0xFFFFFFFFu;
  float wd = __builtin_inff();        // worst distance as float (conservative gate)
  int F = 0;                          // buffered-candidate count (uniform within half)

  int base = range << 13;
  for (int n0 = base; n0 < base + 8192; n0 += 128) {
    float4 p0 = pb[n0 + hl];
    float4 p1 = pb[n0 + 32 + hl];
    float4 p2 = pb[n0 + 64 + hl];
    float4 p3 = pb[n0 + 96 + hl];
    float d[4];
    {
      float dt0 = (qx * p0.x + qy * p0.y) + qz * p0.z;   // contract off: exact ref order
      float dt1 = (qx * p1.x + qy * p1.y) + qz * p1.z;
      float dt2 = (qx * p2.x + qy * p2.y) + qz * p2.z;
      float dt3 = (qx * p3.x + qy * p3.y) + qz * p3.z;
      d[0] = __builtin_fmaf(-2.0f, dt0, qn + p0.w);      // == (qn+pn) - 2*dt exactly
      d[1] = __builtin_fmaf(-2.0f, dt1, qn + p1.w);
      d[2] = __builtin_fmaf(-2.0f, dt2, qn + p2.w);
      d[3] = __builtin_fmaf(-2.0f, dt3, qn + p3.w);
    }
    float md = fminf(fminf(d[0], d[1]), fminf(d[2], d[3]));
    if (__ballot(md <= wd)) {
#pragma unroll
      for (int t = 0; t < 4; t++) {
        bool sv = d[t] <= wd;           // float gate: conservative superset of exact u64 test
        unsigned long long bl = __ballot(sv);
        unsigned mb = half ? (unsigned)(bl >> 32) : (unsigned)bl;
        if (sv) {                       // survivors only: build exact u64 key (masked, no branch)
          unsigned u = __float_as_uint(d[t]);
          u ^= ((unsigned)(((int)u) >> 31)) | 0x80000000u;   // order-preserving map
          unsigned long long c = (((unsigned long long)u) << 32)
                               | (unsigned)(n0 + 32 * t + hl);
          bufh[F + __popc(mb & ((1u << hl) - 1u))] = c;
        }
        F += __popc(mb);
        if (__ballot(F >= 32)) {          // coherent: both halves merge together
          int take = F >= 32 ? 32 : F;    // partner half consumes its partial buffer
          unsigned long long vB = (hl < take) ? bufh[hl] : ~0ULL;
          knn_merge32(vL, worst, worst_hi, wd, vB, hl,
                      aX1, aX2, aX4, aX8, aX16, aRev, aW);
          int R = F - take;               // 0..31
          if (hl < R) bufh[hl] = bufh[32 + hl];   // reads 32..62, writes 0..30: disjoint
          F = R;
        }
      }
    }
  }
  if (__ballot(F > 0)) {   // flush remaining (<32) with +inf padding
    unsigned long long vB = (hl < F) ? bufh[hl] : ~0ULL;
    knn_merge32(vL, worst, worst_hi, wd, vB, hl, aX1, aX2, aX4, aX8, aX16, aRev, aW);
  }

  // cross-wave combine: waves (2k, 2k+1) hold lo/hi top-32 for the same queries
  bufh[hl] = vL;
  __syncthreads();
  unsigned long long vB = buf[wv ^ 1][half][hl];
  vL = u64min(vL, bperm64(vB, aRev));            // both sorted asc: reverse-pair min
  vL = selstage(vL, bperm64(vL, aX16), (hl & 16) != 0);
  vL = selstage(vL, bperm64(vL, aX8),  (hl & 8) != 0);
  vL = selstage(vL, bperm64(vL, aX4),  (hl & 4) != 0);
  vL = selstage(vL, bperm64(vL, aX2),  (hl & 2) != 0);
  vL = selstage(vL, bperm64(vL, aX1),  (hl & 1) != 0);
  if (range == 0)
    g_knn[((size_t)q << 5) | hl] = (unsigned short)(vL & 0xFFFF);
}

// ---------------- layer0: gather feats to LDS, MFMA K=96 -> x0 bf16 ----------------
__global__ __launch_bounds__(256) void k_l0(const float* __restrict__ xyz) {
  __shared__ short feats[256][104];   // row 208B: 16B-aligned
  int t = threadIdx.x;
  int p0 = blockIdx.x * 256;
  {
    int p = p0 + t;
    int idx = g_knn[p];
    int s = (p >> 5) & 4095;
    int b = p >> 17;
    const short* src = g_ptb + ((size_t)((b << 14) + idx) << 6);
#pragma unroll
    for (int i = 0; i < 8; i++)
      ((int4*)&feats[t][0])[i] = ((const int4*)src)[i];
    const float* xb = xyz + b * 3 * N_ALL;
    int4 z; z.x = 0; z.y = 0; z.z = 0; z.w = 0;      // vectorized zero-fill [64..95]
    *(int4*)&feats[t][64] = z;
    *(int4*)&feats[t][72] = z;
    *(int4*)&feats[t][80] = z;
    *(int4*)&feats[t][88] = z;
    short4 d3;
    d3.x = f2b(xb[idx] - xb[s]);
    d3.y = f2b(xb[N_ALL + idx] - xb[N_ALL + s]);
    d3.z = f2b(xb[2 * N_ALL + idx] - xb[2 * N_ALL + s]);
    d3.w = 0;
    *(short4*)&feats[t][64] = d3;                     // overwrites [64..67]
  }
  __syncthreads();
  int lane = t & 63, wv = t >> 6;
  int l15 = lane & 15, quad = lane >> 4;
  bf16x8 A[4][3];
#pragma unroll
  for (int mt = 0; mt < 4; mt++)
#pragma unroll
    for (int kt = 0; kt < 3; kt++)
      A[mt][kt] = *(const bf16x8*)(g_Wb0 + (((mt * 3 + kt) * 64 + lane) << 3));
  f32x4 C[4][4];
#pragma unroll
  for (int mt = 0; mt < 4; mt++)
#pragma unroll
    for (int nt = 0; nt < 4; nt++) C[mt][nt] = 0.f;
#pragma unroll
  for (int kt = 0; kt < 3; kt++)
#pragma unroll
    for (int nt = 0; nt < 4; nt++) {
      bf16x8 B = *(const bf16x8*)(&feats[wv * 64 + nt * 16 + l15][kt * 32 + quad * 8]);
#pragma unroll
      for (int mt = 0; mt < 4; mt++)
        C[mt][nt] = __builtin_amdgcn_mfma_f32_16x16x32_bf16(A[mt][kt], B, C[mt][nt], 0, 0, 0);
    }
#pragma unroll
  for (int mt = 0; mt < 4; mt++)
#pragma unroll
    for (int nt = 0; nt < 4; nt++) {
      int p = p0 + wv * 64 + nt * 16 + l15;
      int c0 = mt * 16 + quad * 4;
      uint2 o;
      o.x = pkbf(C[mt][nt][0], C[mt][nt][1]);
      o.y = pkbf(C[mt][nt][2], C[mt][nt][3]);
      *(uint2*)(g_x0b + ((size_t)p << 6) + c0) = o;
    }
}

// ---------------- layer1: BN0+leaky on x0 frags, MFMA K=64 -> x1 bf16 ----------------
__global__ __launch_bounds__(256) void k_l1(const float* __restrict__ g0,
                                            const float* __restrict__ b0) {
  __shared__ float scA[64], shA[64];
  int t = threadIdx.x;
  if (t < 64) {
    float m = g_part0[t] / P_TOTF;
    float v = g_part0[64 + t] / P_TOTF - m * m;
    float sc = g0[t] / sqrtf(v + EPSV);
    scA[t] = sc; shA[t] = b0[t] - m * sc;
  }
  __syncthreads();
  int lane = t & 63, wv = t >> 6;
  int l15 = lane & 15, quad = lane >> 4;
  int p0 = blockIdx.x * 256 + wv * 64;
  float scv[2][8], shv[2][8];
#pragma unroll
  for (int kt = 0; kt < 2; kt++)
#pragma unroll
    for (int j = 0; j < 8; j++) {
      int c = kt * 32 + quad * 8 + j;
      scv[kt][j] = scA[c]; shv[kt][j] = shA[c];
    }
  bf16x8 A[4][2];
#pragma unroll
  for (int mt = 0; mt < 4; mt++)
#pragma unroll
    for (int kt = 0; kt < 2; kt++)
      A[mt][kt] = *(const bf16x8*)(g_Wb1 + (((mt * 2 + kt) * 64 + lane) << 3));
  f32x4 C[4][4];
#pragma unroll
  for (int mt = 0; mt < 4; mt++)
#pragma unroll
    for (int nt = 0; nt < 4; nt++) C[mt][nt] = 0.f;
#pragma unroll
  for (int kt = 0; kt < 2; kt++)
#pragma unroll
    for (int nt = 0; nt < 4; nt++) {
      const short* src = g_x0b + (((size_t)(p0 + nt * 16 + l15)) << 6) + kt * 32 + quad * 8;
      uint4 raw = *(const uint4*)src;
      bf16x8 B;
      unsigned* Bu = (unsigned*)&B;
      unsigned ru[4] = {raw.x, raw.y, raw.z, raw.w};
#pragma unroll
      for (int jj = 0; jj < 4; jj++) {
        float lo = __uint_as_float(ru[jj] << 16);
        float hi = __uint_as_float(ru[jj] & 0xFFFF0000u);
        float a0 = lo * scv[kt][2*jj]   + shv[kt][2*jj];
        float a1 = hi * scv[kt][2*jj+1] + shv[kt][2*jj+1];
        a0 = fmaxf(a0, 0.1f * a0);
        a1 = fmaxf(a1, 0.1f * a1);
        Bu[jj] = pkbf(a0, a1);
      }
#pragma unroll
      for (int mt = 0; mt < 4; mt++)
        C[mt][nt] = __builtin_amdgcn_mfma_f32_16x16x32_bf16(A[mt][kt], B, C[mt][nt], 0, 0, 0);
    }
#pragma unroll
  for (int mt = 0; mt < 4; mt++)
#pragma unroll
    for (int nt = 0; nt < 4; nt++) {
      int p = p0 + nt * 16 + l15;
      int c0 = mt * 16 + quad * 4;
      uint2 o;
      o.x = pkbf(C[mt][nt][0], C[mt][nt][1]);
      o.y = pkbf(C[mt][nt][2], C[mt][nt][3]);
      *(uint2*)(g_x1b + ((size_t)p << 6) + c0) = o;
    }
}

// ---------------- layer2: BN1+leaky on x1 frags, MFMA K=64 M=128 -> x2 bf16 ----------------
__global__ __launch_bounds__(256) void k_l2(const float* __restrict__ g1,
                                            const float* __restrict__ b1) {
  __shared__ float scA[64], shA[64];
  int t = threadIdx.x;
  if (t < 64) {
    float m = g_part1[t] / P_TOTF;
    float v = g_part1[64 + t] / P_TOTF - m * m;
    float sc = g1[t] / sqrtf(v + EPSV);
    scA[t] = sc; shA[t] = b1[t] - m * sc;
  }
  __syncthreads();
  int lane = t & 63, wv = t >> 6;
  int l15 = lane & 15, quad = lane >> 4;
  int chh = wv & 1;                      // channel half
  int p0 = blockIdx.x * 128 + (wv >> 1) * 64;
  float scv[2][8], shv[2][8];
#pragma unroll
  for (int kt = 0; kt < 2; kt++)
#pragma unroll
    for (int j = 0; j < 8; j++) {
      int c = kt * 32 + quad * 8 + j;
      scv[kt][j] = scA[c]; shv[kt][j] = shA[c];
    }
  bf16x8 A[4][2];
#pragma unroll
  for (int mt = 0; mt < 4; mt++)
#pragma unroll
    for (int kt = 0; kt < 2; kt++)
      A[mt][kt] = *(const bf16x8*)(g_Wb2 + ((((4 * chh + mt) * 2 + kt) * 64 + lane) << 3));
  f32x4 C[4][4];
#pragma unroll
  for (int mt = 0; mt < 4; mt++)
#pragma unroll
    for (int nt = 0; nt < 4; nt++) C[mt][nt] = 0.f;
#pragma unroll
  for (int kt = 0; kt < 2; kt++)
#pragma unroll
    for (int nt = 0; nt < 4; nt++) {
      const short* src = g_x1b + (((size_t)(p0 + nt * 16 + l15)) << 6) + kt * 32 + quad * 8;
      uint4 raw = *(const uint4*)src;
      bf16x8 B;
      unsigned* Bu = (unsigned*)&B;
      unsigned ru[4] = {raw.x, raw.y, raw.z, raw.w};
#pragma unroll
      for (int jj = 0; jj < 4; jj++) {
        float lo = __uint_as_float(ru[jj] << 16);
        float hi = __uint_as_float(ru[jj] & 0xFFFF0000u);
        float a0 = lo * scv[kt][2*jj]   + shv[kt][2*jj];
        float a1 = hi * scv[kt][2*jj+1] + shv[kt][2*jj+1];
        a0 = fmaxf(a0, 0.1f * a0);
        a1 = fmaxf(a1, 0.1f * a1);
        Bu[jj] = pkbf(a0, a1);
      }
#pragma unroll
      for (int mt = 0; mt < 4; mt++)
        C[mt][nt] = __builtin_amdgcn_mfma_f32_16x16x32_bf16(A[mt][kt], B, C[mt][nt], 0, 0, 0);
    }
#pragma unroll
  for (int mt = 0; mt < 4; mt++)
#pragma unroll
    for (int nt = 0; nt < 4; nt++) {
      int p = p0 + nt * 16 + l15;
      int c0 = (4 * chh + mt) * 16 + quad * 4;
      uint2 o;
      o.x = pkbf(C[mt][nt][0], C[mt][nt][1]);
      o.y = pkbf(C[mt][nt][2], C[mt][nt][3]);
      *(uint2*)(g_x2b + ((size_t)p << 7) + c0) = o;
    }
}

// ---------------- streaming stats over bf16 [p][64] — 1024 thr, uint2 loads, 16 waves/CU ----------------
__global__ __launch_bounds__(1024) void k_red64(const short* __restrict__ x,
                                                float* __restrict__ part) {
  __shared__ float sm[64][68], sq[64][68];
  int t = threadIdx.x;
  int cl = t & 15, pr = t >> 4;        // cl: channel quad (4 ch), pr: point row 0..63
  float s0 = 0.f, s1 = 0.f, s2 = 0.f, s3 = 0.f;
  float q0 = 0.f, q1 = 0.f, q2 = 0.f, q3 = 0.f;
  int pbase = blockIdx.x * 1024;
  for (int i = 0; i < 16; i++) {
    int p = pbase + pr + i * 64;
    uint2 d = *(const uint2*)(x + ((size_t)p << 6) + cl * 4);
    float a0 = __uint_as_float(d.x << 16);
    float a1 = __uint_as_float(d.x & 0xFFFF0000u);
    float a2 = __uint_as_float(d.y << 16);
    float a3 = __uint_as_float(d.y & 0xFFFF0000u);
    s0 += a0; q0 = fmaf(a0, a0, q0);
    s1 += a1; q1 = fmaf(a1, a1, q1);
    s2 += a2; q2 = fmaf(a2, a2, q2);
    s3 += a3; q3 = fmaf(a3, a3, q3);
  }
  float4 vs; vs.x = s0; vs.y = s1; vs.z = s2; vs.w = s3;
  float4 vq; vq.x = q0; vq.y = q1; vq.z = q2; vq.w = q3;
  *(float4*)&sm[pr][cl * 4] = vs;
  *(float4*)&sq[pr][cl * 4] = vq;
  __syncthreads();
  if (t < 64) {
    float S = 0.f, Q = 0.f;
#pragma unroll
    for (int r = 0; r < 64; r++) { S += sm[r][t]; Q += sq[r][t]; }
    atomicAdd(part + t, S); atomicAdd(part + 64 + t, Q);
  }
}

// ---------------- stats + per-(s,c) max/min over bf16 [p][128] — 1024 thr, uint2 loads ----------------
__global__ __launch_bounds__(1024) void k_red128mx(const short* __restrict__ x,
                                                   float* __restrict__ part) {
  __shared__ float sm[32][132], sq[32][132];
  int t = threadIdx.x;
  int cl = t & 31, wv = t >> 5;        // cl: channel quad (4 ch), wv: group slice 0..31
  int g = blockIdx.x * 32 + wv;        // 32 k-groups (1024 points) per block
  size_t pbase = (size_t)g << 5;
  float s0 = 0.f, s1 = 0.f, s2 = 0.f, s3 = 0.f;
  float q0 = 0.f, q1 = 0.f, q2 = 0.f, q3 = 0.f;
  float mx0 = -3.4e38f, mn0 = 3.4e38f, mx1 = -3.4e38f, mn1 = 3.4e38f;
  float mx2 = -3.4e38f, mn2 = 3.4e38f, mx3 = -3.4e38f, mn3 = 3.4e38f;
#pragma unroll
  for (int k = 0; k < 32; k++) {
    uint2 d = *(const uint2*)(x + ((pbase + k) << 7) + cl * 4);
    float a0 = __uint_as_float(d.x << 16);
    float a1 = __uint_as_float(d.x & 0xFFFF0000u);
    float a2 = __uint_as_float(d.y << 16);
    float a3 = __uint_as_float(d.y & 0xFFFF0000u);
    s0 += a0; q0 = fmaf(a0, a0, q0);
    s1 += a1; q1 = fmaf(a1, a1, q1);
    s2 += a2; q2 = fmaf(a2, a2, q2);
    s3 += a3; q3 = fmaf(a3, a3, q3);
    mx0 = fmaxf(mx0, a0); mn0 = fminf(mn0, a0);
    mx1 = fmaxf(mx1, a1); mn1 = fminf(mn1, a1);
    mx2 = fmaxf(mx2, a2); mn2 = fminf(mn2, a2);
    mx3 = fmaxf(mx3, a3); mn3 = fminf(mn3, a3);
  }
  float4 vmx; vmx.x = mx0; vmx.y = mx1; vmx.z = mx2; vmx.w = mx3;
  float4 vmn; vmn.x = mn0; vmn.y = mn1; vmn.z = mn2; vmn.w = mn3;
  *(float4*)(g_mx + ((size_t)g << 7) + cl * 4) = vmx;
  *(float4*)(g_mn + ((size_t)g << 7) + cl * 4) = vmn;
  float4 vs; vs.x = s0; vs.y = s1; vs.z = s2; vs.w = s3;
  float4 vq; vq.x = q0; vq.y = q1; vq.z = q2; vq.w = q3;
  *(float4*)&sm[wv][cl * 4] = vs;
  *(float4*)&sq[wv][cl * 4] = vq;
  __syncthreads();
  if (t < 128) {
    float S = 0.f, Q = 0.f;
#pragma unroll
    for (int r = 0; r < 32; r++) { S += sm[r][t]; Q += sq[r][t]; }
    atomicAdd(part + t, S); atomicAdd(part + 128 + t, Q);
  }
}

// ---------------- epilogue: BN2+leaky on precomputed max/min, coalesced r/w ----------------
__global__ __launch_bounds__(256) void k_epi(const float* __restrict__ g2,
                                             const float* __restrict__ b2,
                                             float* __restrict__ out) {
  __shared__ float scA[128], shA[128];
  __shared__ float res[16][132];
  int t = threadIdx.x;
  if (t < 128) {
    float m = g_part2[t] / P_TOTF;
    float v = g_part2[128 + t] / P_TOTF - m * m;
    float sc = g2[t] / sqrtf(v + EPSV);
    scA[t] = sc; shA[t] = b2[t] - m * sc;
  }
  __syncthreads();
  int cp = t & 63, sl = t >> 6;        // channels 2cp,2cp+1 ; sl in 0..3
  int c0 = cp * 2, c1 = c0 + 1;
  float sc0 = scA[c0], sh0 = shA[c0];
  float sc1 = scA[c1], sh1 = shA[c1];
  int sg0 = blockIdx.x * 16;
  for (int it = 0; it < 4; it++) {
    int sgl = sl * 4 + it;             // 0..15, each once per block
    size_t off = ((size_t)(sg0 + sgl) << 7) + c0;
    float2 vmx = *(const float2*)(g_mx + off);
    float2 vmn = *(const float2*)(g_mn + off);
    float a0 = (sc0 >= 0.f ? vmx.x : vmn.x) * sc0 + sh0; a0 = fmaxf(a0, 0.1f * a0);
    float a1 = (sc1 >= 0.f ? vmx.y : vmn.y) * sc1 + sh1; a1 = fmaxf(a1, 0.1f * a1);
    res[sgl][c0] = a0; res[sgl][c1] = a1;
  }
  __syncthreads();
  int b = sg0 >> 12, s0 = sg0 & 4095;   // block never straddles b (4096 % 16 == 0)
#pragma unroll
  for (int w = 0; w < 2; w++) {
    int fidx = t * 2 + w;               // 0..511
    int c = fidx >> 2, qi = fidx & 3;
    float4 o;
    o.x = res[qi * 4 + 0][c];
    o.y = res[qi * 4 + 1][c];
    o.z = res[qi * 4 + 2][c];
    o.w = res[qi * 4 + 3][c];
    *(float4*)(out + 24576 + (((size_t)(b * 128 + c)) << 12) + s0 + qi * 4) = o;
  }
}

extern "C" void kernel_launch(void* const* d_in, const int* in_sizes, int n_in,
                              void* d_out, int out_size, void* d_ws, size_t ws_size,
                              hipStream_t stream) {
  (void)in_sizes; (void)n_in; (void)out_size; (void)d_ws; (void)ws_size;
  const float* xyz    = (const float*)d_in[0];
  const float* points = (const float*)d_in[1];
  const float* W0     = (const float*)d_in[2];
  const float* W1     = (const float*)d_in[3];
  const float* W2     = (const float*)d_in[4];
  const float* g0     = (const float*)d_in[5];
  const float* b0     = (const float*)d_in[6];
  const float* g1     = (const float*)d_in[7];
  const float* b1     = (const float*)d_in[8];
  const float* g2     = (const float*)d_in[9];
  const float* b2     = (const float*)d_in[10];
  float* out = (float*)d_out;

  short *x0b, *x1b, *x2b; float *part0, *part1, *part2;
  hipGetSymbolAddress((void**)&x0b,   HIP_SYMBOL(g_x0b));
  hipGetSymbolAddress((void**)&x1b,   HIP_SYMBOL(g_x1b));
  hipGetSymbolAddress((void**)&x2b,   HIP_SYMBOL(g_x2b));
  hipGetSymbolAddress((void**)&part0, HIP_SYMBOL(g_part0));
  hipGetSymbolAddress((void**)&part1, HIP_SYMBOL(g_part1));
  hipGetSymbolAddress((void**)&part2, HIP_SYMBOL(g_part2));

  hipLaunchKernelGGL(k_setup,    dim3(641),  dim3(256),  0, stream, xyz, points, W0, W1, W2, out);
  hipLaunchKernelGGL(k_knn,      dim3(2048), dim3(256),  0, stream);
  hipLaunchKernelGGL(k_l0,       dim3(1024), dim3(256),  0, stream, xyz);
  hipLaunchKernelGGL(k_red64,    dim3(256),  dim3(1024), 0, stream, x0b, part0);
  hipLaunchKernelGGL(k_l1,       dim3(1024), dim3(256),  0, stream, g0, b0);
  hipLaunchKernelGGL(k_red64,    dim3(256),  dim3(1024), 0, stream, x1b, part1);
  hipLaunchKernelGGL(k_l2,       dim3(2048), dim3(256),  0, stream, g1, b1);
  hipLaunchKernelGGL(k_red128mx, dim3(256),  dim3(1024), 0, stream, x2b, part2);
  hipLaunchKernelGGL(k_epi,      dim3(512),  dim3(256),  0, stream, g2, b2, out);
}

// Round 12
// 301.894 us; speedup vs baseline: 1.0341x; 1.0341x over previous
//
#include <hip/hip_runtime.h>
#include <hip/hip_bf16.h>
#include <stdint.h>

#define N_ALL   16384
#define NPOINT  4096
#define KNN_K   32
#define BATCH   2
#define P_TOT   (BATCH*NPOINT*KNN_K)   /* 262144 */
#define P_TOTF  262144.0f
#define EPSV    1e-5f

typedef __attribute__((ext_vector_type(8))) short bf16x8;
typedef __attribute__((ext_vector_type(4))) float f32x4;

// ---- all scratch in module-static device memory; d_ws untouched ----
__device__ unsigned short g_knn[P_TOT];                                   // 512 KB
__device__ __attribute__((aligned(16))) float g_pxyzn[BATCH*N_ALL*4];     // 512 KB (x,y,z,|x|^2)
__device__ __attribute__((aligned(16))) short g_ptb[BATCH*N_ALL*64];      // 4 MB  [b,n][64c] bf16
__device__ __attribute__((aligned(16))) short g_x0b[(size_t)P_TOT*64];    // 32 MB [p][64] bf16
__device__ __attribute__((aligned(16))) short g_x1b[(size_t)P_TOT*64];    // 32 MB
__device__ __attribute__((aligned(16))) short g_x2b[(size_t)P_TOT*128];   // 64 MB
__device__ __attribute__((aligned(16))) float g_mx[(size_t)BATCH*NPOINT*128];  // 4 MB
__device__ __attribute__((aligned(16))) float g_mn[(size_t)BATCH*NPOINT*128];  // 4 MB
__device__ __attribute__((aligned(16))) short g_Wb0[4*3*64*8];            // swizzled A-frags
__device__ __attribute__((aligned(16))) short g_Wb1[4*2*64*8];
__device__ __attribute__((aligned(16))) short g_Wb2[8*2*64*8];
__device__ float g_p0s[4][128];      // BN0 stats shadows (chain depth 256/addr)
__device__ float g_p1s[4][128];      // BN1 stats shadows
__device__ float g_part2[256];

__device__ __forceinline__ float b2f(short s) {
  union { unsigned u; float f; } v; v.u = ((unsigned)(unsigned short)s) << 16; return v.f;
}
__device__ __forceinline__ short f2b(float f) {
  union { float f; unsigned u; } v; v.f = f;
  unsigned u = v.u;
  u += 0x7FFFu + ((u >> 16) & 1u);
  return (short)(u >> 16);
}
// packed f32x2 -> bf16x2 (v_cvt_pk_bf16_f32, RNE — bit-identical to f2b pairs)
__device__ __forceinline__ unsigned pkbf(float a, float b) {
  union { __hip_bfloat162 h; unsigned u; } v;
  v.h = __float22bfloat162_rn(make_float2(a, b));
  return v.u;
}
__device__ __forceinline__ unsigned long long bperm64(unsigned long long v, int byteaddr) {
  int lo = __builtin_amdgcn_ds_bpermute(byteaddr, (int)(unsigned)(v & 0xFFFFFFFFULL));
  int hi = __builtin_amdgcn_ds_bpermute(byteaddr, (int)(unsigned)(v >> 32));
  return (((unsigned long long)(unsigned)hi) << 32) | (unsigned)lo;
}
__device__ __forceinline__ unsigned long long u64min(unsigned long long a, unsigned long long b) {
  return a < b ? a : b;
}
// bitonic compare-exchange step: keep min (mx=0) or max (mx=1) of (v, pv)
__device__ __forceinline__ unsigned long long selstage(unsigned long long v,
                                                       unsigned long long pv, bool mx) {
  bool lt = v < pv;
  return (lt != mx) ? v : pv;
}

// sort 32 buffered candidates (vB, one per lane within a 32-lane half) ascending,
// merge lowest-32 of (vL ∪ vB) back into vL (sorted), refresh worst_hi/wd.
__device__ __forceinline__ void knn_merge32(unsigned long long& vL,
                                            unsigned long long& worst,
                                            unsigned& worst_hi, float& wd,
                                            unsigned long long vB, int hl,
                                            int aX1, int aX2, int aX4, int aX8,
                                            int aX16, int aRev, int aW) {
  vB = selstage(vB, bperm64(vB, aX1),  ((hl & 1) != 0) != ((hl & 2) != 0));
  vB = selstage(vB, bperm64(vB, aX2),  ((hl & 2) != 0) != ((hl & 4) != 0));
  vB = selstage(vB, bperm64(vB, aX1),  ((hl & 1) != 0) != ((hl & 4) != 0));
  vB = selstage(vB, bperm64(vB, aX4),  ((hl & 4) != 0) != ((hl & 8) != 0));
  vB = selstage(vB, bperm64(vB, aX2),  ((hl & 2) != 0) != ((hl & 8) != 0));
  vB = selstage(vB, bperm64(vB, aX1),  ((hl & 1) != 0) != ((hl & 8) != 0));
  vB = selstage(vB, bperm64(vB, aX8),  ((hl & 8) != 0) != ((hl & 16) != 0));
  vB = selstage(vB, bperm64(vB, aX4),  ((hl & 4) != 0) != ((hl & 16) != 0));
  vB = selstage(vB, bperm64(vB, aX2),  ((hl & 2) != 0) != ((hl & 16) != 0));
  vB = selstage(vB, bperm64(vB, aX1),  ((hl & 1) != 0) != ((hl & 16) != 0));
  vB = selstage(vB, bperm64(vB, aX16), (hl & 16) != 0);
  vB = selstage(vB, bperm64(vB, aX8),  (hl & 8) != 0);
  vB = selstage(vB, bperm64(vB, aX4),  (hl & 4) != 0);
  vB = selstage(vB, bperm64(vB, aX2),  (hl & 2) != 0);
  vB = selstage(vB, bperm64(vB, aX1),  (hl & 1) != 0);
  // vL asc, vB asc: pair lane i with reversed buffer -> lowest 32 (bitonic), then cleanup
  vL = u64min(vL, bperm64(vB, aRev));
  vL = selstage(vL, bperm64(vL, aX16), (hl & 16) != 0);
  vL = selstage(vL, bperm64(vL, aX8),  (hl & 8) != 0);
  vL = selstage(vL, bperm64(vL, aX4),  (hl & 4) != 0);
  vL = selstage(vL, bperm64(vL, aX2),  (hl & 2) != 0);
  vL = selstage(vL, bperm64(vL, aX1),  (hl & 1) != 0);
  worst = bperm64(vL, aW);
  worst_hi = (unsigned)(worst >> 32);
  unsigned wh = worst_hi;
  unsigned ub = (wh & 0x80000000u) ? (wh ^ 0x80000000u) : ~wh;
  wd = (wh == 0xFFFFFFFFu) ? __builtin_inff() : __uint_as_float(ub);
}

// ---------------- setup: tpose (blk<512) | copy+pack (512..639) | wprep (640) ----------------
__global__ __launch_bounds__(256) void k_setup(const float* __restrict__ xyz,
                                               const float* __restrict__ points,
                                               const float* __restrict__ W0,
                                               const float* __restrict__ W1,
                                               const float* __restrict__ W2,
                                               float* __restrict__ out) {
#pragma clang fp contract(off)
  __shared__ float tile[64][65];
  int blk = blockIdx.x;
  int t = threadIdx.x;
  if (blk < 512) {
    int b  = blk >> 8;
    int n0 = (blk & 255) << 6;
#pragma unroll
    for (int r = 0; r < 16; r++) {
      int lin = r * 256 + t;
      int c = lin >> 6, nn = lin & 63;
      tile[c][nn] = points[((size_t)(b * 64 + c)) * N_ALL + n0 + nn];
    }
    __syncthreads();
#pragma unroll
    for (int r = 0; r < 16; r++) {
      int lin = r * 256 + t;
      int nn = lin >> 6, c = lin & 63;
      g_ptb[((size_t)(b * N_ALL + n0 + nn)) * 64 + c] = f2b(tile[c][nn]);
    }
  } else if (blk < 640) {
    int i = (blk - 512) * 256 + t;   // < 32768
    if (i < 24576) {
      int s = i & 4095;
      int c = (i >> 12) % 3;
      int b = i / 12288;
      out[i] = xyz[(b * 3 + c) * N_ALL + s];
    }
    int b = i >> 14, n = i & 16383;
    const float* xb = xyz + b * 3 * N_ALL;
    float x = xb[n], y = xb[N_ALL + n], z = xb[2 * N_ALL + n];
    float4 p; p.x = x; p.y = y; p.z = z; p.w = x * x + y * y + z * z;
    ((float4*)g_pxyzn)[i] = p;
  } else {
    for (int i = t; i < 4 * 3 * 64 * 8; i += 256) {
      int j = i & 7, lane = (i >> 3) & 63, rest = i >> 9;
      int kt = rest % 3, mt = rest / 3;
      int m = 16 * mt + (lane & 15);
      int k = 32 * kt + (lane >> 4) * 8 + j;
      float v = 0.f;
      if (k < 64) v = W0[m * 67 + 3 + k];
      else if (k < 67) v = W0[m * 67 + (k - 64)];
      g_Wb0[i] = f2b(v);
    }
    for (int i = t; i < 4 * 2 * 64 * 8; i += 256) {
      int j = i & 7, lane = (i >> 3) & 63;
      int kt = (i >> 9) & 1, mt = i >> 10;
      int m = 16 * mt + (lane & 15);
      int k = 32 * kt + (lane >> 4) * 8 + j;
      g_Wb1[i] = f2b(W1[m * 64 + k]);
    }
    for (int i = t; i < 8 * 2 * 64 * 8; i += 256) {
      int j = i & 7, lane = (i >> 3) & 63;
      int kt = (i >> 9) & 1, mt = i >> 10;
      int m = 16 * mt + (lane & 15);
      int k = 32 * kt + (lane >> 4) * 8 + j;
      g_Wb2[i] = f2b(W2[m * 64 + k]);
    }
    float* z0 = &g_p0s[0][0];
    float* z1 = &g_p1s[0][0];
    for (int i = t; i < 512; i += 256) { z0[i] = 0.f; z1[i] = 0.f; }
    g_part2[t] = 0.f;
  }
}

// ---------------- KNN: split-N 2-way, 2 queries/wave, float gate + survivor-only keys ----------------
__global__ __launch_bounds__(256, 8) void k_knn() {
#pragma clang fp contract(off)
  __shared__ unsigned long long buf[4][2][64];
  int wv = threadIdx.x >> 6;
  int lane = threadIdx.x & 63;
  int half = lane >> 5;            // 0: lanes 0..31 (query A), 1: lanes 32..63 (query B)
  int hl = lane & 31;
  int lanebase = lane & 32;
  unsigned long long* bufh = buf[wv][half];

  int qpair = wv >> 1;             // waves {0,1} share queries, {2,3} share queries
  int range = wv & 1;              // 0: points [0,8192), 1: [8192,16384)
  int q = blockIdx.x * 4 + qpair * 2 + half;   // 0..8191
  int b = q >> 12, s = q & 4095;
  const float4* pb = (const float4*)g_pxyzn + (b << 14);
  float4 qp = pb[s];
  float qx = qp.x, qy = qp.y, qz = qp.z, qn = qp.w;

  // hoisted cross-lane byte addresses (stay within own 32-lane half)
  int aX1  = (lanebase | (hl ^ 1))  << 2;
  int aX2  = (lanebase | (hl ^ 2))  << 2;
  int aX4  = (lanebase | (hl ^ 4))  << 2;
  int aX8  = (lanebase | (hl ^ 8))  << 2;
  int aX16 = (lanebase | (hl ^ 16)) << 2;
  int aRev = (lanebase | (31 - hl)) << 2;
  int aW   = (lanebase | 31)        << 2;

  unsigned long long vL = ~0ULL;      // per-half sorted top-32 (ascending by lane)
  unsigned long long worst = ~0ULL;   // per-lane copy of own half's vL[31]
  unsigned worst_hi = 0xFFFFFFFFu;
  float wd = __builtin_inff();        // worst distance as float (conservative gate)
  int F = 0;                          // buffered-candidate count (uniform within half)

  int base = range << 13;
  for (int n0 = base; n0 < base + 8192; n0 += 128) {
    float4 p0 = pb[n0 + hl];
    float4 p1 = pb[n0 + 32 + hl];
    float4 p2 = pb[n0 + 64 + hl];
    float4 p3 = pb[n0 + 96 + hl];
    float d[4];
    {
      float dt0 = (qx * p0.x + qy * p0.y) + qz * p0.z;   // contract off: exact ref order
      float dt1 = (qx * p1.x + qy * p1.y) + qz * p1.z;
      float dt2 = (qx * p2.x + qy * p2.y) + qz * p2.z;
      float dt3 = (qx * p3.x + qy * p3.y) + qz * p3.z;
      d[0] = __builtin_fmaf(-2.0f, dt0, qn + p0.w);      // == (qn+pn) - 2*dt exactly
      d[1] = __builtin_fmaf(-2.0f, dt1, qn + p1.w);
      d[2] = __builtin_fmaf(-2.0f, dt2, qn + p2.w);
      d[3] = __builtin_fmaf(-2.0f, dt3, qn + p3.w);
    }
    float md = fminf(fminf(d[0], d[1]), fminf(d[2], d[3]));
    if (__ballot(md <= wd)) {
#pragma unroll
      for (int t = 0; t < 4; t++) {
        bool sv = d[t] <= wd;           // float gate: conservative superset of exact u64 test
        unsigned long long bl = __ballot(sv);
        unsigned mb = half ? (unsigned)(bl >> 32) : (unsigned)bl;
        if (sv) {                       // survivors only: build exact u64 key (masked, no branch)
          unsigned u = __float_as_uint(d[t]);
          u ^= ((unsigned)(((int)u) >> 31)) | 0x80000000u;   // order-preserving map
          unsigned long long c = (((unsigned long long)u) << 32)
                               | (unsigned)(n0 + 32 * t + hl);
          bufh[F + __popc(mb & ((1u << hl) - 1u))] = c;
        }
        F += __popc(mb);
        if (__ballot(F >= 32)) {          // coherent: both halves merge together
          int take = F >= 32 ? 32 : F;    // partner half consumes its partial buffer
          unsigned long long vB = (hl < take) ? bufh[hl] : ~0ULL;
          knn_merge32(vL, worst, worst_hi, wd, vB, hl,
                      aX1, aX2, aX4, aX8, aX16, aRev, aW);
          int R = F - take;               // 0..31
          if (hl < R) bufh[hl] = bufh[32 + hl];   // reads 32..62, writes 0..30: disjoint
          F = R;
        }
      }
    }
  }
  if (__ballot(F > 0)) {   // flush remaining (<32) with +inf padding
    unsigned long long vB = (hl < F) ? bufh[hl] : ~0ULL;
    knn_merge32(vL, worst, worst_hi, wd, vB, hl, aX1, aX2, aX4, aX8, aX16, aRev, aW);
  }

  // cross-wave combine: waves (2k, 2k+1) hold lo/hi top-32 for the same queries
  bufh[hl] = vL;
  __syncthreads();
  unsigned long long vB = buf[wv ^ 1][half][hl];
  vL = u64min(vL, bperm64(vB, aRev));            // both sorted asc: reverse-pair min
  vL = selstage(vL, bperm64(vL, aX16), (hl & 16) != 0);
  vL = selstage(vL, bperm64(vL, aX8),  (hl & 8) != 0);
  vL = selstage(vL, bperm64(vL, aX4),  (hl & 4) != 0);
  vL = selstage(vL, bperm64(vL, aX2),  (hl & 2) != 0);
  vL = selstage(vL, bperm64(vL, aX1),  (hl & 1) != 0);
  if (range == 0)
    g_knn[((size_t)q << 5) | hl] = (unsigned short)(vL & 0xFFFF);
}

// ---------------- layer0: gather feats, MFMA K=96 -> x0 bf16 + fused BN0 stats ----------------
__global__ __launch_bounds__(256) void k_l0(const float* __restrict__ xyz) {
  __shared__ __attribute__((aligned(16))) short feats[256][104];   // 53 KB; reused as 36 KB f32 scratch
  int t = threadIdx.x;
  int p0 = blockIdx.x * 256;
  {
    int p = p0 + t;
    int idx = g_knn[p];
    int s = (p >> 5) & 4095;
    int b = p >> 17;
    const short* src = g_ptb + ((size_t)((b << 14) + idx) << 6);
#pragma unroll
    for (int i = 0; i < 8; i++)
      ((int4*)&feats[t][0])[i] = ((const int4*)src)[i];
    const float* xb = xyz + b * 3 * N_ALL;
    int4 z; z.x = 0; z.y = 0; z.z = 0; z.w = 0;      // vectorized zero-fill [64..95]
    *(int4*)&feats[t][64] = z;
    *(int4*)&feats[t][72] = z;
    *(int4*)&feats[t][80] = z;
    *(int4*)&feats[t][88] = z;
    short4 d3;
    d3.x = f2b(xb[idx] - xb[s]);
    d3.y = f2b(xb[N_ALL + idx] - xb[N_ALL + s]);
    d3.z = f2b(xb[2 * N_ALL + idx] - xb[2 * N_ALL + s]);
    d3.w = 0;
    *(short4*)&feats[t][64] = d3;                     // overwrites [64..67]
  }
  __syncthreads();
  int lane = t & 63, wv = t >> 6;
  int l15 = lane & 15, quad = lane >> 4;
  bf16x8 A[4][3];
#pragma unroll
  for (int mt = 0; mt < 4; mt++)
#pragma unroll
    for (int kt = 0; kt < 3; kt++)
      A[mt][kt] = *(const bf16x8*)(g_Wb0 + (((mt * 3 + kt) * 64 + lane) << 3));
  f32x4 C[4][4];
#pragma unroll
  for (int mt = 0; mt < 4; mt++)
#pragma unroll
    for (int nt = 0; nt < 4; nt++) C[mt][nt] = 0.f;
#pragma unroll
  for (int kt = 0; kt < 3; kt++)
#pragma unroll
    for (int nt = 0; nt < 4; nt++) {
      bf16x8 B = *(const bf16x8*)(&feats[wv * 64 + nt * 16 + l15][kt * 32 + quad * 8]);
#pragma unroll
      for (int mt = 0; mt < 4; mt++)
        C[mt][nt] = __builtin_amdgcn_mfma_f32_16x16x32_bf16(A[mt][kt], B, C[mt][nt], 0, 0, 0);
    }
  float sA[16], qA[16];
#pragma unroll
  for (int i = 0; i < 16; i++) { sA[i] = 0.f; qA[i] = 0.f; }
#pragma unroll
  for (int mt = 0; mt < 4; mt++)
#pragma unroll
    for (int nt = 0; nt < 4; nt++) {
      int p = p0 + wv * 64 + nt * 16 + l15;
      int c0 = mt * 16 + quad * 4;
      uint2 o;
      o.x = pkbf(C[mt][nt][0], C[mt][nt][1]);
      o.y = pkbf(C[mt][nt][2], C[mt][nt][3]);
      *(uint2*)(g_x0b + ((size_t)p << 6) + c0) = o;
      float v0 = __uint_as_float(o.x << 16);
      float v1 = __uint_as_float(o.x & 0xFFFF0000u);
      float v2 = __uint_as_float(o.y << 16);
      float v3 = __uint_as_float(o.y & 0xFFFF0000u);
      int ib = mt * 4;
      sA[ib+0] += v0; qA[ib+0] = fmaf(v0, v0, qA[ib+0]);
      sA[ib+1] += v1; qA[ib+1] = fmaf(v1, v1, qA[ib+1]);
      sA[ib+2] += v2; qA[ib+2] = fmaf(v2, v2, qA[ib+2]);
      sA[ib+3] += v3; qA[ib+3] = fmaf(v3, v3, qA[ib+3]);
    }
  // fused BN0 stats: reg-accum -> LDS (stride 36 rows) -> 64-thread reduce -> shadow atomics
  __syncthreads();                       // all waves done reading feats
  float* red = (float*)&feats[0][0];     // 256 rows x 36 floats = 36 KB
  int rb = t * 36;
#pragma unroll
  for (int w = 0; w < 4; w++) {
    float4 vs; vs.x = sA[w*4+0]; vs.y = sA[w*4+1]; vs.z = sA[w*4+2]; vs.w = sA[w*4+3];
    float4 vq; vq.x = qA[w*4+0]; vq.y = qA[w*4+1]; vq.z = qA[w*4+2]; vq.w = qA[w*4+3];
    *(float4*)&red[rb + w*4] = vs;
    *(float4*)&red[rb + 16 + w*4] = vq;
  }
  __syncthreads();
  if (t < 64) {
    int qd = (t >> 2) & 3;               // quad of channel t
    int i = ((t >> 4) << 2) | (t & 3);   // register index mt*4+j
    float S = 0.f, Q = 0.f;
#pragma unroll
    for (int w = 0; w < 4; w++)
#pragma unroll
      for (int l = 0; l < 16; l++) {
        int row = (w * 64 + qd * 16 + l) * 36;
        S += red[row + i];
        Q += red[row + 16 + i];
      }
    float* sh = &g_p0s[blockIdx.x & 3][0];
    atomicAdd(sh + t, S);
    atomicAdd(sh + 64 + t, Q);
  }
}

// ---------------- layer1: BN0+leaky on x0 frags, MFMA K=64 -> x1 bf16 + fused BN1 stats ----------------
__global__ __launch_bounds__(256) void k_l1(const float* __restrict__ g0,
                                            const float* __restrict__ b0) {
  __shared__ float scA[64], shA[64];
  __shared__ __attribute__((aligned(16))) float red[256 * 36];   // 36 KB stats scratch
  int t = threadIdx.x;
  if (t < 64) {
    float ps = g_p0s[0][t] + g_p0s[1][t] + g_p0s[2][t] + g_p0s[3][t];
    float pq = g_p0s[0][64+t] + g_p0s[1][64+t] + g_p0s[2][64+t] + g_p0s[3][64+t];
    float m = ps / P_TOTF;
    float v = pq / P_TOTF - m * m;
    float sc = g0[t] / sqrtf(v + EPSV);
    scA[t] = sc; shA[t] = b0[t] - m * sc;
  }
  __syncthreads();
  int lane = t & 63, wv = t >> 6;
  int l15 = lane & 15, quad = lane >> 4;
  int p0 = blockIdx.x * 256 + wv * 64;
  float scv[2][8], shv[2][8];
#pragma unroll
  for (int kt = 0; kt < 2; kt++)
#pragma unroll
    for (int j = 0; j < 8; j++) {
      int c = kt * 32 + quad * 8 + j;
      scv[kt][j] = scA[c]; shv[kt][j] = shA[c];
    }
  bf16x8 A[4][2];
#pragma unroll
  for (int mt = 0; mt < 4; mt++)
#pragma unroll
    for (int kt = 0; kt < 2; kt++)
      A[mt][kt] = *(const bf16x8*)(g_Wb1 + (((mt * 2 + kt) * 64 + lane) << 3));
  f32x4 C[4][4];
#pragma unroll
  for (int mt = 0; mt < 4; mt++)
#pragma unroll
    for (int nt = 0; nt < 4; nt++) C[mt][nt] = 0.f;
#pragma unroll
  for (int kt = 0; kt < 2; kt++)
#pragma unroll
    for (int nt = 0; nt < 4; nt++) {
      const short* src = g_x0b + (((size_t)(p0 + nt * 16 + l15)) << 6) + kt * 32 + quad * 8;
      uint4 raw = *(const uint4*)src;
      bf16x8 B;
      unsigned* Bu = (unsigned*)&B;
      unsigned ru[4] = {raw.x, raw.y, raw.z, raw.w};
#pragma unroll
      for (int jj = 0; jj < 4; jj++) {
        float lo = __uint_as_float(ru[jj] << 16);
        float hi = __uint_as_float(ru[jj] & 0xFFFF0000u);
        float a0 = lo * scv[kt][2*jj]   + shv[kt][2*jj];
        float a1 = hi * scv[kt][2*jj+1] + shv[kt][2*jj+1];
        a0 = fmaxf(a0, 0.1f * a0);
        a1 = fmaxf(a1, 0.1f * a1);
        Bu[jj] = pkbf(a0, a1);
      }
#pragma unroll
      for (int mt = 0; mt < 4; mt++)
        C[mt][nt] = __builtin_amdgcn_mfma_f32_16x16x32_bf16(A[mt][kt], B, C[mt][nt], 0, 0, 0);
    }
  float sA[16], qA[16];
#pragma unroll
  for (int i = 0; i < 16; i++) { sA[i] = 0.f; qA[i] = 0.f; }
#pragma unroll
  for (int mt = 0; mt < 4; mt++)
#pragma unroll
    for (int nt = 0; nt < 4; nt++) {
      int p = p0 + nt * 16 + l15;
      int c0 = mt * 16 + quad * 4;
      uint2 o;
      o.x = pkbf(C[mt][nt][0], C[mt][nt][1]);
      o.y = pkbf(C[mt][nt][2], C[mt][nt][3]);
      *(uint2*)(g_x1b + ((size_t)p << 6) + c0) = o;
      float v0 = __uint_as_float(o.x << 16);
      float v1 = __uint_as_float(o.x & 0xFFFF0000u);
      float v2 = __uint_as_float(o.y << 16);
      float v3 = __uint_as_float(o.y & 0xFFFF0000u);
      int ib = mt * 4;
      sA[ib+0] += v0; qA[ib+0] = fmaf(v0, v0, qA[ib+0]);
      sA[ib+1] += v1; qA[ib+1] = fmaf(v1, v1, qA[ib+1]);
      sA[ib+2] += v2; qA[ib+2] = fmaf(v2, v2, qA[ib+2]);
      sA[ib+3] += v3; qA[ib+3] = fmaf(v3, v3, qA[ib+3]);
    }
  int rb = t * 36;
#pragma unroll
  for (int w = 0; w < 4; w++) {
    float4 vs; vs.x = sA[w*4+0]; vs.y = sA[w*4+1]; vs.z = sA[w*4+2]; vs.w = sA[w*4+3];
    float4 vq; vq.x = qA[w*4+0]; vq.y = qA[w*4+1]; vq.z = qA[w*4+2]; vq.w = qA[w*4+3];
    *(float4*)&red[rb + w*4] = vs;
    *(float4*)&red[rb + 16 + w*4] = vq;
  }
  __syncthreads();
  if (t < 64) {
    int qd = (t >> 2) & 3;
    int i = ((t >> 4) << 2) | (t & 3);
    float S = 0.f, Q = 0.f;
#pragma unroll
    for (int w = 0; w < 4; w++)
#pragma unroll
      for (int l = 0; l < 16; l++) {
        int row = (w * 64 + qd * 16 + l) * 36;
        S += red[row + i];
        Q += red[row + 16 + i];
      }
    float* sh = &g_p1s[blockIdx.x & 3][0];
    atomicAdd(sh + t, S);
    atomicAdd(sh + 64 + t, Q);
  }
}

// ---------------- layer2: BN1+leaky on x1 frags, MFMA K=64 M=128 -> x2 bf16 ----------------
__global__ __launch_bounds__(256) void k_l2(const float* __restrict__ g1,
                                            const float* __restrict__ b1) {
  __shared__ float scA[64], shA[64];
  int t = threadIdx.x;
  if (t < 64) {
    float ps = g_p1s[0][t] + g_p1s[1][t] + g_p1s[2][t] + g_p1s[3][t];
    float pq = g_p1s[0][64+t] + g_p1s[1][64+t] + g_p1s[2][64+t] + g_p1s[3][64+t];
    float m = ps / P_TOTF;
    float v = pq / P_TOTF - m * m;
    float sc = g1[t] / sqrtf(v + EPSV);
    scA[t] = sc; shA[t] = b1[t] - m * sc;
  }
  __syncthreads();
  int lane = t & 63, wv = t >> 6;
  int l15 = lane & 15, quad = lane >> 4;
  int chh = wv & 1;                      // channel half
  int p0 = blockIdx.x * 128 + (wv >> 1) * 64;
  float scv[2][8], shv[2][8];
#pragma unroll
  for (int kt = 0; kt < 2; kt++)
#pragma unroll
    for (int j = 0; j < 8; j++) {
      int c = kt * 32 + quad * 8 + j;
      scv[kt][j] = scA[c]; shv[kt][j] = shA[c];
    }
  bf16x8 A[4][2];
#pragma unroll
  for (int mt = 0; mt < 4; mt++)
#pragma unroll
    for (int kt = 0; kt < 2; kt++)
      A[mt][kt] = *(const bf16x8*)(g_Wb2 + ((((4 * chh + mt) * 2 + kt) * 64 + lane) << 3));
  f32x4 C[4][4];
#pragma unroll
  for (int mt = 0; mt < 4; mt++)
#pragma unroll
    for (int nt = 0; nt < 4; nt++) C[mt][nt] = 0.f;
#pragma unroll
  for (int kt = 0; kt < 2; kt++)
#pragma unroll
    for (int nt = 0; nt < 4; nt++) {
      const short* src = g_x1b + (((size_t)(p0 + nt * 16 + l15)) << 6) + kt * 32 + quad * 8;
      uint4 raw = *(const uint4*)src;
      bf16x8 B;
      unsigned* Bu = (unsigned*)&B;
      unsigned ru[4] = {raw.x, raw.y, raw.z, raw.w};
#pragma unroll
      for (int jj = 0; jj < 4; jj++) {
        float lo = __uint_as_float(ru[jj] << 16);
        float hi = __uint_as_float(ru[jj] & 0xFFFF0000u);
        float a0 = lo * scv[kt][2*jj]   + shv[kt][2*jj];
        float a1 = hi * scv[kt][2*jj+1] + shv[kt][2*jj+1];
        a0 = fmaxf(a0, 0.1f * a0);
        a1 = fmaxf(a1, 0.1f * a1);
        Bu[jj] = pkbf(a0, a1);
      }
#pragma unroll
      for (int mt = 0; mt < 4; mt++)
        C[mt][nt] = __builtin_amdgcn_mfma_f32_16x16x32_bf16(A[mt][kt], B, C[mt][nt], 0, 0, 0);
    }
#pragma unroll
  for (int mt = 0; mt < 4; mt++)
#pragma unroll
    for (int nt = 0; nt < 4; nt++) {
      int p = p0 + nt * 16 + l15;
      int c0 = (4 * chh + mt) * 16 + quad * 4;
      uint2 o;
      o.x = pkbf(C[mt][nt][0], C[mt][nt][1]);
      o.y = pkbf(C[mt][nt][2], C[mt][nt][3]);
      *(uint2*)(g_x2b + ((size_t)p << 7) + c0) = o;
    }
}

// ---------------- stats + per-(s,c) max/min over bf16 [p][128] — 1024 thr, uint2 loads ----------------
__global__ __launch_bounds__(1024) void k_red128mx(const short* __restrict__ x,
                                                   float* __restrict__ part) {
  __shared__ float sm[32][132], sq[32][132];
  int t = threadIdx.x;
  int cl = t & 31, wv = t >> 5;        // cl: channel quad (4 ch), wv: group slice 0..31
  int g = blockIdx.x * 32 + wv;        // 32 k-groups (1024 points) per block
  size_t pbase = (size_t)g << 5;
  float s0 = 0.f, s1 = 0.f, s2 = 0.f, s3 = 0.f;
  float q0 = 0.f, q1 = 0.f, q2 = 0.f, q3 = 0.f;
  float mx0 = -3.4e38f, mn0 = 3.4e38f, mx1 = -3.4e38f, mn1 = 3.4e38f;
  float mx2 = -3.4e38f, mn2 = 3.4e38f, mx3 = -3.4e38f, mn3 = 3.4e38f;
#pragma unroll
  for (int k = 0; k < 32; k++) {
    uint2 d = *(const uint2*)(x + ((pbase + k) << 7) + cl * 4);
    float a0 = __uint_as_float(d.x << 16);
    float a1 = __uint_as_float(d.x & 0xFFFF0000u);
    float a2 = __uint_as_float(d.y << 16);
    float a3 = __uint_as_float(d.y & 0xFFFF0000u);
    s0 += a0; q0 = fmaf(a0, a0, q0);
    s1 += a1; q1 = fmaf(a1, a1, q1);
    s2 += a2; q2 = fmaf(a2, a2, q2);
    s3 += a3; q3 = fmaf(a3, a3, q3);
    mx0 = fmaxf(mx0, a0); mn0 = fminf(mn0, a0);
    mx1 = fmaxf(mx1, a1); mn1 = fminf(mn1, a1);
    mx2 = fmaxf(mx2, a2); mn2 = fminf(mn2, a2);
    mx3 = fmaxf(mx3, a3); mn3 = fminf(mn3, a3);
  }
  float4 vmx; vmx.x = mx0; vmx.y = mx1; vmx.z = mx2; vmx.w = mx3;
  float4 vmn; vmn.x = mn0; vmn.y = mn1; vmn.z = mn2; vmn.w = mn3;
  *(float4*)(g_mx + ((size_t)g << 7) + cl * 4) = vmx;
  *(float4*)(g_mn + ((size_t)g << 7) + cl * 4) = vmn;
  float4 vs; vs.x = s0; vs.y = s1; vs.z = s2; vs.w = s3;
  float4 vq; vq.x = q0; vq.y = q1; vq.z = q2; vq.w = q3;
  *(float4*)&sm[wv][cl * 4] = vs;
  *(float4*)&sq[wv][cl * 4] = vq;
  __syncthreads();
  if (t < 128) {
    float S = 0.f, Q = 0.f;
#pragma unroll
    for (int r = 0; r < 32; r++) { S += sm[r][t]; Q += sq[r][t]; }
    atomicAdd(part + t, S); atomicAdd(part + 128 + t, Q);
  }
}

// ---------------- epilogue: BN2+leaky on precomputed max/min, coalesced r/w ----------------
__global__ __launch_bounds__(256) void k_epi(const float* __restrict__ g2,
                                             const float* __restrict__ b2,
                                             float* __restrict__ out) {
  __shared__ float scA[128], shA[128];
  __shared__ float res[16][132];
  int t = threadIdx.x;
  if (t < 128) {
    float m = g_part2[t] / P_TOTF;
    float v = g_part2[128 + t] / P_TOTF - m * m;
    float sc = g2[t] / sqrtf(v + EPSV);
    scA[t] = sc; shA[t] = b2[t] - m * sc;
  }
  __syncthreads();
  int cp = t & 63, sl = t >> 6;        // channels 2cp,2cp+1 ; sl in 0..3
  int c0 = cp * 2, c1 = c0 + 1;
  float sc0 = scA[c0], sh0 = shA[c0];
  float sc1 = scA[c1], sh1 = shA[c1];
  int sg0 = blockIdx.x * 16;
  for (int it = 0; it < 4; it++) {
    int sgl = sl * 4 + it;             // 0..15, each once per block
    size_t off = ((size_t)(sg0 + sgl) << 7) + c0;
    float2 vmx = *(const float2*)(g_mx + off);
    float2 vmn = *(const float2*)(g_mn + off);
    float a0 = (sc0 >= 0.f ? vmx.x : vmn.x) * sc0 + sh0; a0 = fmaxf(a0, 0.1f * a0);
    float a1 = (sc1 >= 0.f ? vmx.y : vmn.y) * sc1 + sh1; a1 = fmaxf(a1, 0.1f * a1);
    res[sgl][c0] = a0; res[sgl][c1] = a1;
  }
  __syncthreads();
  int b = sg0 >> 12, s0 = sg0 & 4095;   // block never straddles b (4096 % 16 == 0)
#pragma unroll
  for (int w = 0; w < 2; w++) {
    int fidx = t * 2 + w;               // 0..511
    int c = fidx >> 2, qi = fidx & 3;
    float4 o;
    o.x = res[qi * 4 + 0][c];
    o.y = res[qi * 4 + 1][c];
    o.z = res[qi * 4 + 2][c];
    o.w = res[qi * 4 + 3][c];
    *(float4*)(out + 24576 + (((size_t)(b * 128 + c)) << 12) + s0 + qi * 4) = o;
  }
}

extern "C" void kernel_launch(void* const* d_in, const int* in_sizes, int n_in,
                              void* d_out, int out_size, void* d_ws, size_t ws_size,
                              hipStream_t stream) {
  (void)in_sizes; (void)n_in; (void)out_size; (void)d_ws; (void)ws_size;
  const float* xyz    = (const float*)d_in[0];
  const float* points = (const float*)d_in[1];
  const float* W0     = (const float*)d_in[2];
  const float* W1     = (const float*)d_in[3];
  const float* W2     = (const float*)d_in[4];
  const float* g0     = (const float*)d_in[5];
  const float* b0     = (const float*)d_in[6];
  const float* g1     = (const float*)d_in[7];
  const float* b1     = (const float*)d_in[8];
  const float* g2     = (const float*)d_in[9];
  const float* b2     = (const float*)d_in[10];
  float* out = (float*)d_out;

  short *x2b; float *part2;
  hipGetSymbolAddress((void**)&x2b,   HIP_SYMBOL(g_x2b));
  hipGetSymbolAddress((void**)&part2, HIP_SYMBOL(g_part2));

  hipLaunchKernelGGL(k_setup,    dim3(641),  dim3(256),  0, stream, xyz, points, W0, W1, W2, out);
  hipLaunchKernelGGL(k_knn,      dim3(2048), dim3(256),  0, stream);
  hipLaunchKernelGGL(k_l0,       dim3(1024), dim3(256),  0, stream, xyz);
  hipLaunchKernelGGL(k_l1,       dim3(1024), dim3(256),  0, stream, g0, b0);
  hipLaunchKernelGGL(k_l2,       dim3(2048), dim3(256),  0, stream, g1, b1);
  hipLaunchKernelGGL(k_red128mx, dim3(256),  dim3(1024), 0, stream, x2b, part2);
  hipLaunchKernelGGL(k_epi,      dim3(512),  dim3(256),  0, stream, g2, b2, out);
}

// Round 13
// 289.906 us; speedup vs baseline: 1.0769x; 1.0413x over previous
//
#include <hip/hip_runtime.h>
#include <hip/hip_bf16.h>
#include <stdint.h>

#define N_ALL   16384
#define NPOINT  4096
#define KNN_K   32
#define BATCH   2
#define P_TOT   (BATCH*NPOINT*KNN_K)   /* 262144 */
#define P_TOTF  262144.0f
#define EPSV    1e-5f

typedef __attribute__((ext_vector_type(8))) short bf16x8;
typedef __attribute__((ext_vector_type(4))) float f32x4;

// ---- all scratch in module-static device memory; d_ws untouched ----
__device__ unsigned short g_knn[P_TOT];                                   // 512 KB
__device__ __attribute__((aligned(16))) float g_pxyzn[BATCH*N_ALL*4];     // 512 KB (x,y,z,|x|^2)
__device__ __attribute__((aligned(16))) short g_ptb[BATCH*N_ALL*64];      // 4 MB  [b,n][64c] bf16
__device__ __attribute__((aligned(16))) short g_x0b[(size_t)P_TOT*64];    // 32 MB [p][64] bf16
__device__ __attribute__((aligned(16))) short g_x1b[(size_t)P_TOT*64];    // 32 MB
__device__ __attribute__((aligned(16))) float g_mx[(size_t)BATCH*NPOINT*128];  // 4 MB
__device__ __attribute__((aligned(16))) float g_mn[(size_t)BATCH*NPOINT*128];  // 4 MB
__device__ __attribute__((aligned(16))) short g_Wb0[4*3*64*8];            // swizzled A-frags
__device__ __attribute__((aligned(16))) short g_Wb1[4*2*64*8];
__device__ __attribute__((aligned(16))) short g_Wb2[8*2*64*8];
__device__ float g_p0s[4][128];      // BN0 stats shadows (chain depth 256/addr)
__device__ float g_p1s[4][128];      // BN1 stats shadows
__device__ float g_p2s[8][256];      // BN2 stats shadows (2048 blocks / 8 = 256/addr)

__device__ __forceinline__ float b2f(short s) {
  union { unsigned u; float f; } v; v.u = ((unsigned)(unsigned short)s) << 16; return v.f;
}
__device__ __forceinline__ short f2b(float f) {
  union { float f; unsigned u; } v; v.f = f;
  unsigned u = v.u;
  u += 0x7FFFu + ((u >> 16) & 1u);
  return (short)(u >> 16);
}
// packed f32x2 -> bf16x2 (v_cvt_pk_bf16_f32, RNE — bit-identical to f2b pairs)
__device__ __forceinline__ unsigned pkbf(float a, float b) {
  union { __hip_bfloat162 h; unsigned u; } v;
  v.h = __float22bfloat162_rn(make_float2(a, b));
  return v.u;
}
__device__ __forceinline__ unsigned long long bperm64(unsigned long long v, int byteaddr) {
  int lo = __builtin_amdgcn_ds_bpermute(byteaddr, (int)(unsigned)(v & 0xFFFFFFFFULL));
  int hi = __builtin_amdgcn_ds_bpermute(byteaddr, (int)(unsigned)(v >> 32));
  return (((unsigned long long)(unsigned)hi) << 32) | (unsigned)lo;
}
__device__ __forceinline__ unsigned long long u64min(unsigned long long a, unsigned long long b) {
  return a < b ? a : b;
}
// bitonic compare-exchange step: keep min (mx=0) or max (mx=1) of (v, pv)
__device__ __forceinline__ unsigned long long selstage(unsigned long long v,
                                                       unsigned long long pv, bool mx) {
  bool lt = v < pv;
  return (lt != mx) ? v : pv;
}

// sort 32 buffered candidates (vB, one per lane within a 32-lane half) ascending,
// merge lowest-32 of (vL ∪ vB) back into vL (sorted), refresh worst_hi/wd.
__device__ __forceinline__ void knn_merge32(unsigned long long& vL,
                                            unsigned long long& worst,
                                            unsigned& worst_hi, float& wd,
                                            unsigned long long vB, int hl,
                                            int aX1, int aX2, int aX4, int aX8,
                                            int aX16, int aRev, int aW) {
  vB = selstage(vB, bperm64(vB, aX1),  ((hl & 1) != 0) != ((hl & 2) != 0));
  vB = selstage(vB, bperm64(vB, aX2),  ((hl & 2) != 0) != ((hl & 4) != 0));
  vB = selstage(vB, bperm64(vB, aX1),  ((hl & 1) != 0) != ((hl & 4) != 0));
  vB = selstage(vB, bperm64(vB, aX4),  ((hl & 4) != 0) != ((hl & 8) != 0));
  vB = selstage(vB, bperm64(vB, aX2),  ((hl & 2) != 0) != ((hl & 8) != 0));
  vB = selstage(vB, bperm64(vB, aX1),  ((hl & 1) != 0) != ((hl & 8) != 0));
  vB = selstage(vB, bperm64(vB, aX8),  ((hl & 8) != 0) != ((hl & 16) != 0));
  vB = selstage(vB, bperm64(vB, aX4),  ((hl & 4) != 0) != ((hl & 16) != 0));
  vB = selstage(vB, bperm64(vB, aX2),  ((hl & 2) != 0) != ((hl & 16) != 0));
  vB = selstage(vB, bperm64(vB, aX1),  ((hl & 1) != 0) != ((hl & 16) != 0));
  vB = selstage(vB, bperm64(vB, aX16), (hl & 16) != 0);
  vB = selstage(vB, bperm64(vB, aX8),  (hl & 8) != 0);
  vB = selstage(vB, bperm64(vB, aX4),  (hl & 4) != 0);
  vB = selstage(vB, bperm64(vB, aX2),  (hl & 2) != 0);
  vB = selstage(vB, bperm64(vB, aX1),  (hl & 1) != 0);
  // vL asc, vB asc: pair lane i with reversed buffer -> lowest 32 (bitonic), then cleanup
  vL = u64min(vL, bperm64(vB, aRev));
  vL = selstage(vL, bperm64(vL, aX16), (hl & 16) != 0);
  vL = selstage(vL, bperm64(vL, aX8),  (hl & 8) != 0);
  vL = selstage(vL, bperm64(vL, aX4),  (hl & 4) != 0);
  vL = selstage(vL, bperm64(vL, aX2),  (hl & 2) != 0);
  vL = selstage(vL, bperm64(vL, aX1),  (hl & 1) != 0);
  worst = bperm64(vL, aW);
  worst_hi = (unsigned)(worst >> 32);
  unsigned wh = worst_hi;
  unsigned ub = (wh & 0x80000000u) ? (wh ^ 0x80000000u) : ~wh;
  wd = (wh == 0xFFFFFFFFu) ? __builtin_inff() : __uint_as_float(ub);
}

// ---------------- setup: tpose (blk<512) | copy+pack (512..639) | wprep (640) ----------------
__global__ __launch_bounds__(256) void k_setup(const float* __restrict__ xyz,
                                               const float* __restrict__ points,
                                               const float* __restrict__ W0,
                                               const float* __restrict__ W1,
                                               const float* __restrict__ W2,
                                               float* __restrict__ out) {
#pragma clang fp contract(off)
  __shared__ float tile[64][65];
  int blk = blockIdx.x;
  int t = threadIdx.x;
  if (blk < 512) {
    int b  = blk >> 8;
    int n0 = (blk & 255) << 6;
#pragma unroll
    for (int r = 0; r < 16; r++) {
      int lin = r * 256 + t;
      int c = lin >> 6, nn = lin & 63;
      tile[c][nn] = points[((size_t)(b * 64 + c)) * N_ALL + n0 + nn];
    }
    __syncthreads();
#pragma unroll
    for (int r = 0; r < 16; r++) {
      int lin = r * 256 + t;
      int nn = lin >> 6, c = lin & 63;
      g_ptb[((size_t)(b * N_ALL + n0 + nn)) * 64 + c] = f2b(tile[c][nn]);
    }
  } else if (blk < 640) {
    int i = (blk - 512) * 256 + t;   // < 32768
    if (i < 24576) {
      int s = i & 4095;
      int c = (i >> 12) % 3;
      int b = i / 12288;
      out[i] = xyz[(b * 3 + c) * N_ALL + s];
    }
    int b = i >> 14, n = i & 16383;
    const float* xb = xyz + b * 3 * N_ALL;
    float x = xb[n], y = xb[N_ALL + n], z = xb[2 * N_ALL + n];
    float4 p; p.x = x; p.y = y; p.z = z; p.w = x * x + y * y + z * z;
    ((float4*)g_pxyzn)[i] = p;
  } else {
    for (int i = t; i < 4 * 3 * 64 * 8; i += 256) {
      int j = i & 7, lane = (i >> 3) & 63, rest = i >> 9;
      int kt = rest % 3, mt = rest / 3;
      int m = 16 * mt + (lane & 15);
      int k = 32 * kt + (lane >> 4) * 8 + j;
      float v = 0.f;
      if (k < 64) v = W0[m * 67 + 3 + k];
      else if (k < 67) v = W0[m * 67 + (k - 64)];
      g_Wb0[i] = f2b(v);
    }
    for (int i = t; i < 4 * 2 * 64 * 8; i += 256) {
      int j = i & 7, lane = (i >> 3) & 63;
      int kt = (i >> 9) & 1, mt = i >> 10;
      int m = 16 * mt + (lane & 15);
      int k = 32 * kt + (lane >> 4) * 8 + j;
      g_Wb1[i] = f2b(W1[m * 64 + k]);
    }
    for (int i = t; i < 8 * 2 * 64 * 8; i += 256) {
      int j = i & 7, lane = (i >> 3) & 63;
      int kt = (i >> 9) & 1, mt = i >> 10;
      int m = 16 * mt + (lane & 15);
      int k = 32 * kt + (lane >> 4) * 8 + j;
      g_Wb2[i] = f2b(W2[m * 64 + k]);
    }
    float* z0 = &g_p0s[0][0];
    float* z1 = &g_p1s[0][0];
    float* z2 = &g_p2s[0][0];
    for (int i = t; i < 512; i += 256) { z0[i] = 0.f; z1[i] = 0.f; }
    for (int i = t; i < 2048; i += 256) z2[i] = 0.f;
  }
}

// ---------------- KNN: split-N 2-way, 2 queries/wave, float gate + survivor-only keys ----------------
__global__ __launch_bounds__(256, 8) void k_knn() {
#pragma clang fp contract(off)
  __shared__ unsigned long long buf[4][2][64];
  int wv = threadIdx.x >> 6;
  int lane = threadIdx.x & 63;
  int half = lane >> 5;            // 0: lanes 0..31 (query A), 1: lanes 32..63 (query B)
  int hl = lane & 31;
  int lanebase = lane & 32;
  unsigned long long* bufh = buf[wv][half];

  int qpair = wv >> 1;             // waves {0,1} share queries, {2,3} share queries
  int range = wv & 1;              // 0: points [0,8192), 1: [8192,16384)
  int q = blockIdx.x * 4 + qpair * 2 + half;   // 0..8191
  int b = q >> 12, s = q & 4095;
  const float4* pb = (const float4*)g_pxyzn + (b << 14);
  float4 qp = pb[s];
  float qx = qp.x, qy = qp.y, qz = qp.z, qn = qp.w;

  // hoisted cross-lane byte addresses (stay within own 32-lane half)
  int aX1  = (lanebase | (hl ^ 1))  << 2;
  int aX2  = (lanebase | (hl ^ 2))  << 2;
  int aX4  = (lanebase | (hl ^ 4))  << 2;
  int aX8  = (lanebase | (hl ^ 8))  << 2;
  int aX16 = (lanebase | (hl ^ 16)) << 2;
  int aRev = (lanebase | (31 - hl)) << 2;
  int aW   = (lanebase | 31)        << 2;

  unsigned long long vL = ~0ULL;      // per-half sorted top-32 (ascending by lane)
  unsigned long long worst = ~0ULL;   // per-lane copy of own half's vL[31]
  unsigned worst_hi = 0xFFFFFFFFu;
  float wd = __builtin_inff();        // worst distance as float (conservative gate)
  int F = 0;                          // buffered-candidate count (uniform within half)

  int base = range << 13;
  for (int n0 = base; n0 < base + 8192; n0 += 128) {
    float4 p0 = pb[n0 + hl];
    float4 p1 = pb[n0 + 32 + hl];
    float4 p2 = pb[n0 + 64 + hl];
    float4 p3 = pb[n0 + 96 + hl];
    float d[4];
    {
      float dt0 = (qx * p0.x + qy * p0.y) + qz * p0.z;   // contract off: exact ref order
      float dt1 = (qx * p1.x + qy * p1.y) + qz * p1.z;
      float dt2 = (qx * p2.x + qy * p2.y) + qz * p2.z;
      float dt3 = (qx * p3.x + qy * p3.y) + qz * p3.z;
      d[0] = __builtin_fmaf(-2.0f, dt0, qn + p0.w);      // == (qn+pn) - 2*dt exactly
      d[1] = __builtin_fmaf(-2.0f, dt1, qn + p1.w);
      d[2] = __builtin_fmaf(-2.0f, dt2, qn + p2.w);
      d[3] = __builtin_fmaf(-2.0f, dt3, qn + p3.w);
    }
    float md = fminf(fminf(d[0], d[1]), fminf(d[2], d[3]));
    if (__ballot(md <= wd)) {
#pragma unroll
      for (int t = 0; t < 4; t++) {
        bool sv = d[t] <= wd;           // float gate: conservative superset of exact u64 test
        unsigned long long bl = __ballot(sv);
        unsigned mb = half ? (unsigned)(bl >> 32) : (unsigned)bl;
        if (sv) {                       // survivors only: build exact u64 key (masked, no branch)
          unsigned u = __float_as_uint(d[t]);
          u ^= ((unsigned)(((int)u) >> 31)) | 0x80000000u;   // order-preserving map
          unsigned long long c = (((unsigned long long)u) << 32)
                               | (unsigned)(n0 + 32 * t + hl);
          bufh[F + __popc(mb & ((1u << hl) - 1u))] = c;
        }
        F += __popc(mb);
        if (__ballot(F >= 32)) {          // coherent: both halves merge together
          int take = F >= 32 ? 32 : F;    // partner half consumes its partial buffer
          unsigned long long vB = (hl < take) ? bufh[hl] : ~0ULL;
          knn_merge32(vL, worst, worst_hi, wd, vB, hl,
                      aX1, aX2, aX4, aX8, aX16, aRev, aW);
          int R = F - take;               // 0..31
          if (hl < R) bufh[hl] = bufh[32 + hl];   // reads 32..62, writes 0..30: disjoint
          F = R;
        }
      }
    }
  }
  if (__ballot(F > 0)) {   // flush remaining (<32) with +inf padding
    unsigned long long vB = (hl < F) ? bufh[hl] : ~0ULL;
    knn_merge32(vL, worst, worst_hi, wd, vB, hl, aX1, aX2, aX4, aX8, aX16, aRev, aW);
  }

  // cross-wave combine: waves (2k, 2k+1) hold lo/hi top-32 for the same queries
  bufh[hl] = vL;
  __syncthreads();
  unsigned long long vB = buf[wv ^ 1][half][hl];
  vL = u64min(vL, bperm64(vB, aRev));            // both sorted asc: reverse-pair min
  vL = selstage(vL, bperm64(vL, aX16), (hl & 16) != 0);
  vL = selstage(vL, bperm64(vL, aX8),  (hl & 8) != 0);
  vL = selstage(vL, bperm64(vL, aX4),  (hl & 4) != 0);
  vL = selstage(vL, bperm64(vL, aX2),  (hl & 2) != 0);
  vL = selstage(vL, bperm64(vL, aX1),  (hl & 1) != 0);
  if (range == 0)
    g_knn[((size_t)q << 5) | hl] = (unsigned short)(vL & 0xFFFF);
}

// ---------------- layer0: gather feats, MFMA K=96 -> x0 bf16 + fused BN0 stats ----------------
__global__ __launch_bounds__(256) void k_l0(const float* __restrict__ xyz) {
  __shared__ __attribute__((aligned(16))) short feats[256][104];   // 53 KB; reused as 36 KB f32 scratch
  int t = threadIdx.x;
  int p0 = blockIdx.x * 256;
  {
    int p = p0 + t;
    int idx = g_knn[p];
    int s = (p >> 5) & 4095;
    int b = p >> 17;
    const short* src = g_ptb + ((size_t)((b << 14) + idx) << 6);
#pragma unroll
    for (int i = 0; i < 8; i++)
      ((int4*)&feats[t][0])[i] = ((const int4*)src)[i];
    const float* xb = xyz + b * 3 * N_ALL;
    int4 z; z.x = 0; z.y = 0; z.z = 0; z.w = 0;      // vectorized zero-fill [64..95]
    *(int4*)&feats[t][64] = z;
    *(int4*)&feats[t][72] = z;
    *(int4*)&feats[t][80] = z;
    *(int4*)&feats[t][88] = z;
    short4 d3;
    d3.x = f2b(xb[idx] - xb[s]);
    d3.y = f2b(xb[N_ALL + idx] - xb[N_ALL + s]);
    d3.z = f2b(xb[2 * N_ALL + idx] - xb[2 * N_ALL + s]);
    d3.w = 0;
    *(short4*)&feats[t][64] = d3;                     // overwrites [64..67]
  }
  __syncthreads();
  int lane = t & 63, wv = t >> 6;
  int l15 = lane & 15, quad = lane >> 4;
  bf16x8 A[4][3];
#pragma unroll
  for (int mt = 0; mt < 4; mt++)
#pragma unroll
    for (int kt = 0; kt < 3; kt++)
      A[mt][kt] = *(const bf16x8*)(g_Wb0 + (((mt * 3 + kt) * 64 + lane) << 3));
  f32x4 C[4][4];
#pragma unroll
  for (int mt = 0; mt < 4; mt++)
#pragma unroll
    for (int nt = 0; nt < 4; nt++) C[mt][nt] = 0.f;
#pragma unroll
  for (int kt = 0; kt < 3; kt++)
#pragma unroll
    for (int nt = 0; nt < 4; nt++) {
      bf16x8 B = *(const bf16x8*)(&feats[wv * 64 + nt * 16 + l15][kt * 32 + quad * 8]);
#pragma unroll
      for (int mt = 0; mt < 4; mt++)
        C[mt][nt] = __builtin_amdgcn_mfma_f32_16x16x32_bf16(A[mt][kt], B, C[mt][nt], 0, 0, 0);
    }
  float sA[16], qA[16];
#pragma unroll
  for (int i = 0; i < 16; i++) { sA[i] = 0.f; qA[i] = 0.f; }
#pragma unroll
  for (int mt = 0; mt < 4; mt++)
#pragma unroll
    for (int nt = 0; nt < 4; nt++) {
      int p = p0 + wv * 64 + nt * 16 + l15;
      int c0 = mt * 16 + quad * 4;
      uint2 o;
      o.x = pkbf(C[mt][nt][0], C[mt][nt][1]);
      o.y = pkbf(C[mt][nt][2], C[mt][nt][3]);
      *(uint2*)(g_x0b + ((size_t)p << 6) + c0) = o;
      float v0 = __uint_as_float(o.x << 16);
      float v1 = __uint_as_float(o.x & 0xFFFF0000u);
      float v2 = __uint_as_float(o.y << 16);
      float v3 = __uint_as_float(o.y & 0xFFFF0000u);
      int ib = mt * 4;
      sA[ib+0] += v0; qA[ib+0] = fmaf(v0, v0, qA[ib+0]);
      sA[ib+1] += v1; qA[ib+1] = fmaf(v1, v1, qA[ib+1]);
      sA[ib+2] += v2; qA[ib+2] = fmaf(v2, v2, qA[ib+2]);
      sA[ib+3] += v3; qA[ib+3] = fmaf(v3, v3, qA[ib+3]);
    }
  // fused BN0 stats: reg-accum -> LDS (stride 36 rows) -> 64-thread reduce -> shadow atomics
  __syncthreads();                       // all waves done reading feats
  float* red = (float*)&feats[0][0];     // 256 rows x 36 floats = 36 KB
  int rb = t * 36;
#pragma unroll
  for (int w = 0; w < 4; w++) {
    float4 vs; vs.x = sA[w*4+0]; vs.y = sA[w*4+1]; vs.z = sA[w*4+2]; vs.w = sA[w*4+3];
    float4 vq; vq.x = qA[w*4+0]; vq.y = qA[w*4+1]; vq.z = qA[w*4+2]; vq.w = qA[w*4+3];
    *(float4*)&red[rb + w*4] = vs;
    *(float4*)&red[rb + 16 + w*4] = vq;
  }
  __syncthreads();
  if (t < 64) {
    int qd = (t >> 2) & 3;               // quad of channel t
    int i = ((t >> 4) << 2) | (t & 3);   // register index mt*4+j
    float S = 0.f, Q = 0.f;
#pragma unroll
    for (int w = 0; w < 4; w++)
#pragma unroll
      for (int l = 0; l < 16; l++) {
        int row = (w * 64 + qd * 16 + l) * 36;
        S += red[row + i];
        Q += red[row + 16 + i];
      }
    float* sh = &g_p0s[blockIdx.x & 3][0];
    atomicAdd(sh + t, S);
    atomicAdd(sh + 64 + t, Q);
  }
}

// ---------------- layer1: BN0+leaky on x0 frags, MFMA K=64 -> x1 bf16 + fused BN1 stats ----------------
__global__ __launch_bounds__(256) void k_l1(const float* __restrict__ g0,
                                            const float* __restrict__ b0) {
  __shared__ float scA[64], shA[64];
  __shared__ __attribute__((aligned(16))) float red[256 * 36];   // 36 KB stats scratch
  int t = threadIdx.x;
  if (t < 64) {
    float ps = g_p0s[0][t] + g_p0s[1][t] + g_p0s[2][t] + g_p0s[3][t];
    float pq = g_p0s[0][64+t] + g_p0s[1][64+t] + g_p0s[2][64+t] + g_p0s[3][64+t];
    float m = ps / P_TOTF;
    float v = pq / P_TOTF - m * m;
    float sc = g0[t] / sqrtf(v + EPSV);
    scA[t] = sc; shA[t] = b0[t] - m * sc;
  }
  __syncthreads();
  int lane = t & 63, wv = t >> 6;
  int l15 = lane & 15, quad = lane >> 4;
  int p0 = blockIdx.x * 256 + wv * 64;
  float scv[2][8], shv[2][8];
#pragma unroll
  for (int kt = 0; kt < 2; kt++)
#pragma unroll
    for (int j = 0; j < 8; j++) {
      int c = kt * 32 + quad * 8 + j;
      scv[kt][j] = scA[c]; shv[kt][j] = shA[c];
    }
  bf16x8 A[4][2];
#pragma unroll
  for (int mt = 0; mt < 4; mt++)
#pragma unroll
    for (int kt = 0; kt < 2; kt++)
      A[mt][kt] = *(const bf16x8*)(g_Wb1 + (((mt * 2 + kt) * 64 + lane) << 3));
  f32x4 C[4][4];
#pragma unroll
  for (int mt = 0; mt < 4; mt++)
#pragma unroll
    for (int nt = 0; nt < 4; nt++) C[mt][nt] = 0.f;
#pragma unroll
  for (int kt = 0; kt < 2; kt++)
#pragma unroll
    for (int nt = 0; nt < 4; nt++) {
      const short* src = g_x0b + (((size_t)(p0 + nt * 16 + l15)) << 6) + kt * 32 + quad * 8;
      uint4 raw = *(const uint4*)src;
      bf16x8 B;
      unsigned* Bu = (unsigned*)&B;
      unsigned ru[4] = {raw.x, raw.y, raw.z, raw.w};
#pragma unroll
      for (int jj = 0; jj < 4; jj++) {
        float lo = __uint_as_float(ru[jj] << 16);
        float hi = __uint_as_float(ru[jj] & 0xFFFF0000u);
        float a0 = lo * scv[kt][2*jj]   + shv[kt][2*jj];
        float a1 = hi * scv[kt][2*jj+1] + shv[kt][2*jj+1];
        a0 = fmaxf(a0, 0.1f * a0);
        a1 = fmaxf(a1, 0.1f * a1);
        Bu[jj] = pkbf(a0, a1);
      }
#pragma unroll
      for (int mt = 0; mt < 4; mt++)
        C[mt][nt] = __builtin_amdgcn_mfma_f32_16x16x32_bf16(A[mt][kt], B, C[mt][nt], 0, 0, 0);
    }
  float sA[16], qA[16];
#pragma unroll
  for (int i = 0; i < 16; i++) { sA[i] = 0.f; qA[i] = 0.f; }
#pragma unroll
  for (int mt = 0; mt < 4; mt++)
#pragma unroll
    for (int nt = 0; nt < 4; nt++) {
      int p = p0 + nt * 16 + l15;
      int c0 = mt * 16 + quad * 4;
      uint2 o;
      o.x = pkbf(C[mt][nt][0], C[mt][nt][1]);
      o.y = pkbf(C[mt][nt][2], C[mt][nt][3]);
      *(uint2*)(g_x1b + ((size_t)p << 6) + c0) = o;
      float v0 = __uint_as_float(o.x << 16);
      float v1 = __uint_as_float(o.x & 0xFFFF0000u);
      float v2 = __uint_as_float(o.y << 16);
      float v3 = __uint_as_float(o.y & 0xFFFF0000u);
      int ib = mt * 4;
      sA[ib+0] += v0; qA[ib+0] = fmaf(v0, v0, qA[ib+0]);
      sA[ib+1] += v1; qA[ib+1] = fmaf(v1, v1, qA[ib+1]);
      sA[ib+2] += v2; qA[ib+2] = fmaf(v2, v2, qA[ib+2]);
      sA[ib+3] += v3; qA[ib+3] = fmaf(v3, v3, qA[ib+3]);
    }
  int rb = t * 36;
#pragma unroll
  for (int w = 0; w < 4; w++) {
    float4 vs; vs.x = sA[w*4+0]; vs.y = sA[w*4+1]; vs.z = sA[w*4+2]; vs.w = sA[w*4+3];
    float4 vq; vq.x = qA[w*4+0]; vq.y = qA[w*4+1]; vq.z = qA[w*4+2]; vq.w = qA[w*4+3];
    *(float4*)&red[rb + w*4] = vs;
    *(float4*)&red[rb + 16 + w*4] = vq;
  }
  __syncthreads();
  if (t < 64) {
    int qd = (t >> 2) & 3;
    int i = ((t >> 4) << 2) | (t & 3);
    float S = 0.f, Q = 0.f;
#pragma unroll
    for (int w = 0; w < 4; w++)
#pragma unroll
      for (int l = 0; l < 16; l++) {
        int row = (w * 64 + qd * 16 + l) * 36;
        S += red[row + i];
        Q += red[row + 16 + i];
      }
    float* sh = &g_p1s[blockIdx.x & 3][0];
    atomicAdd(sh + t, S);
    atomicAdd(sh + 64 + t, Q);
  }
}

// ---------------- layer2: BN1+leaky, MFMA M=128; fused k-max/min + BN2 stats (x2 never hits HBM) ----------------
__global__ __launch_bounds__(256) void k_l2(const float* __restrict__ g1,
                                            const float* __restrict__ b1) {
  __shared__ float scA[64], shA[64];
  __shared__ __attribute__((aligned(16))) float red[9216];   // 36 KB scratch (phase A: bf16 mx/mn; phase B: stats)
  int t = threadIdx.x;
  if (t < 64) {
    float ps = g_p1s[0][t] + g_p1s[1][t] + g_p1s[2][t] + g_p1s[3][t];
    float pq = g_p1s[0][64+t] + g_p1s[1][64+t] + g_p1s[2][64+t] + g_p1s[3][64+t];
    float m = ps / P_TOTF;
    float v = pq / P_TOTF - m * m;
    float sc = g1[t] / sqrtf(v + EPSV);
    scA[t] = sc; shA[t] = b1[t] - m * sc;
  }
  __syncthreads();
  int lane = t & 63, wv = t >> 6;
  int l15 = lane & 15, quad = lane >> 4;
  int chh = wv & 1;                      // channel half
  int p0 = blockIdx.x * 128 + (wv >> 1) * 64;
  float scv[2][8], shv[2][8];
#pragma unroll
  for (int kt = 0; kt < 2; kt++)
#pragma unroll
    for (int j = 0; j < 8; j++) {
      int c = kt * 32 + quad * 8 + j;
      scv[kt][j] = scA[c]; shv[kt][j] = shA[c];
    }
  bf16x8 A[4][2];
#pragma unroll
  for (int mt = 0; mt < 4; mt++)
#pragma unroll
    for (int kt = 0; kt < 2; kt++)
      A[mt][kt] = *(const bf16x8*)(g_Wb2 + ((((4 * chh + mt) * 2 + kt) * 64 + lane) << 3));
  f32x4 C[4][4];
#pragma unroll
  for (int mt = 0; mt < 4; mt++)
#pragma unroll
    for (int nt = 0; nt < 4; nt++) C[mt][nt] = 0.f;
#pragma unroll
  for (int kt = 0; kt < 2; kt++)
#pragma unroll
    for (int nt = 0; nt < 4; nt++) {
      const short* src = g_x1b + (((size_t)(p0 + nt * 16 + l15)) << 6) + kt * 32 + quad * 8;
      uint4 raw = *(const uint4*)src;
      bf16x8 B;
      unsigned* Bu = (unsigned*)&B;
      unsigned ru[4] = {raw.x, raw.y, raw.z, raw.w};
#pragma unroll
      for (int jj = 0; jj < 4; jj++) {
        float lo = __uint_as_float(ru[jj] << 16);
        float hi = __uint_as_float(ru[jj] & 0xFFFF0000u);
        float a0 = lo * scv[kt][2*jj]   + shv[kt][2*jj];
        float a1 = hi * scv[kt][2*jj+1] + shv[kt][2*jj+1];
        a0 = fmaxf(a0, 0.1f * a0);
        a1 = fmaxf(a1, 0.1f * a1);
        Bu[jj] = pkbf(a0, a1);
      }
#pragma unroll
      for (int mt = 0; mt < 4; mt++)
        C[mt][nt] = __builtin_amdgcn_mfma_f32_16x16x32_bf16(A[mt][kt], B, C[mt][nt], 0, 0, 0);
    }
  // per-lane: bf16-rounded values -> stats accum + per-s-subgroup partial max/min
  float sA[16], qA[16];
  float mxP[2][16], mnP[2][16];
#pragma unroll
  for (int i = 0; i < 16; i++) {
    sA[i] = 0.f; qA[i] = 0.f;
    mxP[0][i] = -3.4e38f; mnP[0][i] = 3.4e38f;
    mxP[1][i] = -3.4e38f; mnP[1][i] = 3.4e38f;
  }
#pragma unroll
  for (int mt = 0; mt < 4; mt++)
#pragma unroll
    for (int nt = 0; nt < 4; nt++) {
      unsigned ox = pkbf(C[mt][nt][0], C[mt][nt][1]);
      unsigned oy = pkbf(C[mt][nt][2], C[mt][nt][3]);
      float v0 = __uint_as_float(ox << 16);
      float v1 = __uint_as_float(ox & 0xFFFF0000u);
      float v2 = __uint_as_float(oy << 16);
      float v3 = __uint_as_float(oy & 0xFFFF0000u);
      int ib = mt * 4, sp = nt >> 1;
      sA[ib+0] += v0; qA[ib+0] = fmaf(v0, v0, qA[ib+0]);
      sA[ib+1] += v1; qA[ib+1] = fmaf(v1, v1, qA[ib+1]);
      sA[ib+2] += v2; qA[ib+2] = fmaf(v2, v2, qA[ib+2]);
      sA[ib+3] += v3; qA[ib+3] = fmaf(v3, v3, qA[ib+3]);
      mxP[sp][ib+0] = fmaxf(mxP[sp][ib+0], v0); mnP[sp][ib+0] = fminf(mnP[sp][ib+0], v0);
      mxP[sp][ib+1] = fmaxf(mxP[sp][ib+1], v1); mnP[sp][ib+1] = fminf(mnP[sp][ib+1], v1);
      mxP[sp][ib+2] = fmaxf(mxP[sp][ib+2], v2); mnP[sp][ib+2] = fminf(mnP[sp][ib+2], v2);
      mxP[sp][ib+3] = fmaxf(mxP[sp][ib+3], v3); mnP[sp][ib+3] = fminf(mnP[sp][ib+3], v3);
    }
  // phase A: bf16 partial max/min -> LDS [4 sg][16 l15][132 c], reduce over l15 -> g_mx/g_mn
  short* mxs = (short*)red;              // 4*16*132 shorts = 16896 B
  short* mns = mxs + 8448;               // second 16896 B (total 33792 <= 36864)
  int sgl0 = (wv >> 1) * 2;
#pragma unroll
  for (int sp = 0; sp < 2; sp++)
#pragma unroll
    for (int mt = 0; mt < 4; mt++) {
      int c0 = (4 * chh + mt) * 16 + quad * 4;
      int base = ((sgl0 + sp) * 16 + l15) * 132 + c0;
      short4 m4;
      m4.x = f2b(mxP[sp][mt*4+0]); m4.y = f2b(mxP[sp][mt*4+1]);
      m4.z = f2b(mxP[sp][mt*4+2]); m4.w = f2b(mxP[sp][mt*4+3]);
      *(short4*)&mxs[base] = m4;
      short4 n4;
      n4.x = f2b(mnP[sp][mt*4+0]); n4.y = f2b(mnP[sp][mt*4+1]);
      n4.z = f2b(mnP[sp][mt*4+2]); n4.w = f2b(mnP[sp][mt*4+3]);
      *(short4*)&mns[base] = n4;
    }
  __syncthreads();
  {
    int sg = t >> 6, c0 = (t & 63) * 2;   // each thread: 1 s-group, 2 channels
    float m0 = -3.4e38f, m1 = -3.4e38f, n0 = 3.4e38f, n1 = 3.4e38f;
#pragma unroll
    for (int l = 0; l < 16; l++) {
      unsigned ux = *(const unsigned*)&mxs[(sg * 16 + l) * 132 + c0];
      m0 = fmaxf(m0, __uint_as_float(ux << 16));
      m1 = fmaxf(m1, __uint_as_float(ux & 0xFFFF0000u));
      unsigned un = *(const unsigned*)&mns[(sg * 16 + l) * 132 + c0];
      n0 = fminf(n0, __uint_as_float(un << 16));
      n1 = fminf(n1, __uint_as_float(un & 0xFFFF0000u));
    }
    int sgg = blockIdx.x * 4 + sg;
    float2 vmx; vmx.x = m0; vmx.y = m1;
    float2 vmn; vmn.x = n0; vmn.y = n1;
    *(float2*)(g_mx + ((size_t)sgg << 7) + c0) = vmx;
    *(float2*)(g_mn + ((size_t)sgg << 7) + c0) = vmn;
  }
  __syncthreads();
  // phase B: BN2 stats (r12 pattern), 128 channels from 2 waves each
  int rb = t * 36;
#pragma unroll
  for (int w = 0; w < 4; w++) {
    float4 vs; vs.x = sA[w*4+0]; vs.y = sA[w*4+1]; vs.z = sA[w*4+2]; vs.w = sA[w*4+3];
    float4 vq; vq.x = qA[w*4+0]; vq.y = qA[w*4+1]; vq.z = qA[w*4+2]; vq.w = qA[w*4+3];
    *(float4*)&red[rb + w*4] = vs;
    *(float4*)&red[rb + 16 + w*4] = vq;
  }
  __syncthreads();
  if (t < 128) {
    int c = t;
    int ch2 = c >> 6, mt = (c >> 4) & 3, qd = (c >> 2) & 3, j = c & 3;
    int i = mt * 4 + j;
    float S = 0.f, Q = 0.f;
#pragma unroll
    for (int w = 0; w < 2; w++) {
      int wvv = ch2 + w * 2;
#pragma unroll
      for (int l = 0; l < 16; l++) {
        int row = (wvv * 64 + qd * 16 + l) * 36;
        S += red[row + i];
        Q += red[row + 16 + i];
      }
    }
    float* sh = &g_p2s[blockIdx.x & 7][0];
    atomicAdd(sh + c, S);
    atomicAdd(sh + 128 + c, Q);
  }
}

// ---------------- epilogue: BN2+leaky on precomputed max/min, coalesced r/w ----------------
__global__ __launch_bounds__(256) void k_epi(const float* __restrict__ g2,
                                             const float* __restrict__ b2,
                                             float* __restrict__ out) {
  __shared__ float scA[128], shA[128];
  __shared__ float res[16][132];
  int t = threadIdx.x;
  if (t < 128) {
    float ps = 0.f, pq = 0.f;
#pragma unroll
    for (int s = 0; s < 8; s++) { ps += g_p2s[s][t]; pq += g_p2s[s][128 + t]; }
    float m = ps / P_TOTF;
    float v = pq / P_TOTF - m * m;
    float sc = g2[t] / sqrtf(v + EPSV);
    scA[t] = sc; shA[t] = b2[t] - m * sc;
  }
  __syncthreads();
  int cp = t & 63, sl = t >> 6;        // channels 2cp,2cp+1 ; sl in 0..3
  int c0 = cp * 2, c1 = c0 + 1;
  float sc0 = scA[c0], sh0 = shA[c0];
  float sc1 = scA[c1], sh1 = shA[c1];
  int sg0 = blockIdx.x * 16;
  for (int it = 0; it < 4; it++) {
    int sgl = sl * 4 + it;             // 0..15, each once per block
    size_t off = ((size_t)(sg0 + sgl) << 7) + c0;
    float2 vmx = *(const float2*)(g_mx + off);
    float2 vmn = *(const float2*)(g_mn + off);
    float a0 = (sc0 >= 0.f ? vmx.x : vmn.x) * sc0 + sh0; a0 = fmaxf(a0, 0.1f * a0);
    float a1 = (sc1 >= 0.f ? vmx.y : vmn.y) * sc1 + sh1; a1 = fmaxf(a1, 0.1f * a1);
    res[sgl][c0] = a0; res[sgl][c1] = a1;
  }
  __syncthreads();
  int b = sg0 >> 12, s0 = sg0 & 4095;   // block never straddles b (4096 % 16 == 0)
#pragma unroll
  for (int w = 0; w < 2; w++) {
    int fidx = t * 2 + w;               // 0..511
    int c = fidx >> 2, qi = fidx & 3;
    float4 o;
    o.x = res[qi * 4 + 0][c];
    o.y = res[qi * 4 + 1][c];
    o.z = res[qi * 4 + 2][c];
    o.w = res[qi * 4 + 3][c];
    *(float4*)(out + 24576 + (((size_t)(b * 128 + c)) << 12) + s0 + qi * 4) = o;
  }
}

extern "C" void kernel_launch(void* const* d_in, const int* in_sizes, int n_in,
                              void* d_out, int out_size, void* d_ws, size_t ws_size,
                              hipStream_t stream) {
  (void)in_sizes; (void)n_in; (void)out_size; (void)d_ws; (void)ws_size;
  const float* xyz    = (const float*)d_in[0];
  const float* points = (const float*)d_in[1];
  const float* W0     = (const float*)d_in[2];
  const float* W1     = (const float*)d_in[3];
  const float* W2     = (const float*)d_in[4];
  const float* g0     = (const float*)d_in[5];
  const float* b0     = (const float*)d_in[6];
  const float* g1     = (const float*)d_in[7];
  const float* b1     = (const float*)d_in[8];
  const float* g2     = (const float*)d_in[9];
  const float* b2     = (const float*)d_in[10];
  float* out = (float*)d_out;

  hipLaunchKernelGGL(k_setup, dim3(641),  dim3(256), 0, stream, xyz, points, W0, W1, W2, out);
  hipLaunchKernelGGL(k_knn,   dim3(2048), dim3(256), 0, stream);
  hipLaunchKernelGGL(k_l0,    dim3(1024), dim3(256), 0, stream, xyz);
  hipLaunchKernelGGL(k_l1,    dim3(1024), dim3(256), 0, stream, g0, b0);
  hipLaunchKernelGGL(k_l2,    dim3(2048), dim3(256), 0, stream, g1, b1);
  hipLaunchKernelGGL(k_epi,   dim3(512),  dim3(256), 0, stream, g2, b2, out);
}

// Round 14
// 284.574 us; speedup vs baseline: 1.0971x; 1.0187x over previous
//
#include <hip/hip_runtime.h>
#include <hip/hip_bf16.h>
#include <stdint.h>

#define N_ALL   16384
#define NPOINT  4096
#define KNN_K   32
#define BATCH   2
#define P_TOT   (BATCH*NPOINT*KNN_K)   /* 262144 */
#define P_TOTF  262144.0f
#define EPSV    1e-5f

typedef __attribute__((ext_vector_type(8))) short bf16x8;
typedef __attribute__((ext_vector_type(4))) float f32x4;

// ---- all scratch in module-static device memory; d_ws untouched ----
__device__ unsigned short g_knn[P_TOT];                                   // 512 KB
__device__ __attribute__((aligned(16))) float g_pxyzn[BATCH*N_ALL*4];     // 512 KB (x,y,z,|x|^2)
__device__ __attribute__((aligned(16))) short g_ptb[BATCH*N_ALL*64];      // 4 MB  [b,n][64c] bf16
__device__ __attribute__((aligned(16))) short g_x0b[(size_t)P_TOT*64];    // 32 MB [p][64] bf16
__device__ __attribute__((aligned(16))) short g_x1b[(size_t)P_TOT*64];    // 32 MB
__device__ __attribute__((aligned(16))) float g_mx[(size_t)BATCH*NPOINT*128];  // 4 MB
__device__ __attribute__((aligned(16))) float g_mn[(size_t)BATCH*NPOINT*128];  // 4 MB
__device__ __attribute__((aligned(16))) short g_Wb0[4*3*64*8];            // swizzled A-frags
__device__ __attribute__((aligned(16))) short g_Wb1[4*2*64*8];
__device__ __attribute__((aligned(16))) short g_Wb2[8*2*64*8];
__device__ float g_p0s[8][128];      // BN0 stats shadows (2048 blocks / 8 = 256/addr)
__device__ float g_p1s[4][128];      // BN1 stats shadows (1024 blocks / 4 = 256/addr)
__device__ float g_p2s[8][256];      // BN2 stats shadows (2048 blocks / 8 = 256/addr)

__device__ __forceinline__ float b2f(short s) {
  union { unsigned u; float f; } v; v.u = ((unsigned)(unsigned short)s) << 16; return v.f;
}
__device__ __forceinline__ short f2b(float f) {
  union { float f; unsigned u; } v; v.f = f;
  unsigned u = v.u;
  u += 0x7FFFu + ((u >> 16) & 1u);
  return (short)(u >> 16);
}
// packed f32x2 -> bf16x2 (v_cvt_pk_bf16_f32, RNE — bit-identical to f2b pairs)
__device__ __forceinline__ unsigned pkbf(float a, float b) {
  union { __hip_bfloat162 h; unsigned u; } v;
  v.h = __float22bfloat162_rn(make_float2(a, b));
  return v.u;
}
__device__ __forceinline__ unsigned long long bperm64(unsigned long long v, int byteaddr) {
  int lo = __builtin_amdgcn_ds_bpermute(byteaddr, (int)(unsigned)(v & 0xFFFFFFFFULL));
  int hi = __builtin_amdgcn_ds_bpermute(byteaddr, (int)(unsigned)(v >> 32));
  return (((unsigned long long)(unsigned)hi) << 32) | (unsigned)lo;
}
__device__ __forceinline__ unsigned long long u64min(unsigned long long a, unsigned long long b) {
  return a < b ? a : b;
}
// bitonic compare-exchange step: keep min (mx=0) or max (mx=1) of (v, pv)
__device__ __forceinline__ unsigned long long selstage(unsigned long long v,
                                                       unsigned long long pv, bool mx) {
  bool lt = v < pv;
  return (lt != mx) ? v : pv;
}

// sort 32 buffered candidates (vB, one per lane within a 32-lane half) ascending,
// merge lowest-32 of (vL ∪ vB) back into vL (sorted), refresh worst_hi/wd.
__device__ __forceinline__ void knn_merge32(unsigned long long& vL,
                                            unsigned long long& worst,
                                            unsigned& worst_hi, float& wd,
                                            unsigned long long vB, int hl,
                                            int aX1, int aX2, int aX4, int aX8,
                                            int aX16, int aRev, int aW) {
  vB = selstage(vB, bperm64(vB, aX1),  ((hl & 1) != 0) != ((hl & 2) != 0));
  vB = selstage(vB, bperm64(vB, aX2),  ((hl & 2) != 0) != ((hl & 4) != 0));
  vB = selstage(vB, bperm64(vB, aX1),  ((hl & 1) != 0) != ((hl & 4) != 0));
  vB = selstage(vB, bperm64(vB, aX4),  ((hl & 4) != 0) != ((hl & 8) != 0));
  vB = selstage(vB, bperm64(vB, aX2),  ((hl & 2) != 0) != ((hl & 8) != 0));
  vB = selstage(vB, bperm64(vB, aX1),  ((hl & 1) != 0) != ((hl & 8) != 0));
  vB = selstage(vB, bperm64(vB, aX8),  ((hl & 8) != 0) != ((hl & 16) != 0));
  vB = selstage(vB, bperm64(vB, aX4),  ((hl & 4) != 0) != ((hl & 16) != 0));
  vB = selstage(vB, bperm64(vB, aX2),  ((hl & 2) != 0) != ((hl & 16) != 0));
  vB = selstage(vB, bperm64(vB, aX1),  ((hl & 1) != 0) != ((hl & 16) != 0));
  vB = selstage(vB, bperm64(vB, aX16), (hl & 16) != 0);
  vB = selstage(vB, bperm64(vB, aX8),  (hl & 8) != 0);
  vB = selstage(vB, bperm64(vB, aX4),  (hl & 4) != 0);
  vB = selstage(vB, bperm64(vB, aX2),  (hl & 2) != 0);
  vB = selstage(vB, bperm64(vB, aX1),  (hl & 1) != 0);
  // vL asc, vB asc: pair lane i with reversed buffer -> lowest 32 (bitonic), then cleanup
  vL = u64min(vL, bperm64(vB, aRev));
  vL = selstage(vL, bperm64(vL, aX16), (hl & 16) != 0);
  vL = selstage(vL, bperm64(vL, aX8),  (hl & 8) != 0);
  vL = selstage(vL, bperm64(vL, aX4),  (hl & 4) != 0);
  vL = selstage(vL, bperm64(vL, aX2),  (hl & 2) != 0);
  vL = selstage(vL, bperm64(vL, aX1),  (hl & 1) != 0);
  worst = bperm64(vL, aW);
  worst_hi = (unsigned)(worst >> 32);
  unsigned wh = worst_hi;
  unsigned ub = (wh & 0x80000000u) ? (wh ^ 0x80000000u) : ~wh;
  wd = (wh == 0xFFFFFFFFu) ? __builtin_inff() : __uint_as_float(ub);
}

// ---------------- setup: tpose (blk<512) | copy+pack (512..639) | wprep (640) ----------------
__global__ __launch_bounds__(256) void k_setup(const float* __restrict__ xyz,
                                               const float* __restrict__ points,
                                               const float* __restrict__ W0,
                                               const float* __restrict__ W1,
                                               const float* __restrict__ W2,
                                               float* __restrict__ out) {
#pragma clang fp contract(off)
  __shared__ float tile[64][65];
  int blk = blockIdx.x;
  int t = threadIdx.x;
  if (blk < 512) {
    int b  = blk >> 8;
    int n0 = (blk & 255) << 6;
#pragma unroll
    for (int r = 0; r < 16; r++) {
      int lin = r * 256 + t;
      int c = lin >> 6, nn = lin & 63;
      tile[c][nn] = points[((size_t)(b * 64 + c)) * N_ALL + n0 + nn];
    }
    __syncthreads();
#pragma unroll
    for (int r = 0; r < 16; r++) {
      int lin = r * 256 + t;
      int nn = lin >> 6, c = lin & 63;
      g_ptb[((size_t)(b * N_ALL + n0 + nn)) * 64 + c] = f2b(tile[c][nn]);
    }
  } else if (blk < 640) {
    int i = (blk - 512) * 256 + t;   // < 32768
    if (i < 24576) {
      int s = i & 4095;
      int c = (i >> 12) % 3;
      int b = i / 12288;
      out[i] = xyz[(b * 3 + c) * N_ALL + s];
    }
    int b = i >> 14, n = i & 16383;
    const float* xb = xyz + b * 3 * N_ALL;
    float x = xb[n], y = xb[N_ALL + n], z = xb[2 * N_ALL + n];
    float4 p; p.x = x; p.y = y; p.z = z; p.w = x * x + y * y + z * z;
    ((float4*)g_pxyzn)[i] = p;
  } else {
    for (int i = t; i < 4 * 3 * 64 * 8; i += 256) {
      int j = i & 7, lane = (i >> 3) & 63, rest = i >> 9;
      int kt = rest % 3, mt = rest / 3;
      int m = 16 * mt + (lane & 15);
      int k = 32 * kt + (lane >> 4) * 8 + j;
      float v = 0.f;
      if (k < 64) v = W0[m * 67 + 3 + k];
      else if (k < 67) v = W0[m * 67 + (k - 64)];
      g_Wb0[i] = f2b(v);
    }
    for (int i = t; i < 4 * 2 * 64 * 8; i += 256) {
      int j = i & 7, lane = (i >> 3) & 63;
      int kt = (i >> 9) & 1, mt = i >> 10;
      int m = 16 * mt + (lane & 15);
      int k = 32 * kt + (lane >> 4) * 8 + j;
      g_Wb1[i] = f2b(W1[m * 64 + k]);
    }
    for (int i = t; i < 8 * 2 * 64 * 8; i += 256) {
      int j = i & 7, lane = (i >> 3) & 63;
      int kt = (i >> 9) & 1, mt = i >> 10;
      int m = 16 * mt + (lane & 15);
      int k = 32 * kt + (lane >> 4) * 8 + j;
      g_Wb2[i] = f2b(W2[m * 64 + k]);
    }
    float* z0 = &g_p0s[0][0];
    float* z1 = &g_p1s[0][0];
    float* z2 = &g_p2s[0][0];
    for (int i = t; i < 1024; i += 256) z0[i] = 0.f;
    for (int i = t; i < 512; i += 256) z1[i] = 0.f;
    for (int i = t; i < 2048; i += 256) z2[i] = 0.f;
  }
}

// ---------------- KNN: split-N 2-way, 2 queries/wave, float gate + survivor-only keys ----------------
__global__ __launch_bounds__(256, 8) void k_knn() {
#pragma clang fp contract(off)
  __shared__ unsigned long long buf[4][2][64];
  int wv = threadIdx.x >> 6;
  int lane = threadIdx.x & 63;
  int half = lane >> 5;            // 0: lanes 0..31 (query A), 1: lanes 32..63 (query B)
  int hl = lane & 31;
  int lanebase = lane & 32;
  unsigned long long* bufh = buf[wv][half];

  int qpair = wv >> 1;             // waves {0,1} share queries, {2,3} share queries
  int range = wv & 1;              // 0: points [0,8192), 1: [8192,16384)
  int q = blockIdx.x * 4 + qpair * 2 + half;   // 0..8191
  int b = q >> 12, s = q & 4095;
  const float4* pb = (const float4*)g_pxyzn + (b << 14);
  float4 qp = pb[s];
  float qx = qp.x, qy = qp.y, qz = qp.z, qn = qp.w;

  // hoisted cross-lane byte addresses (stay within own 32-lane half)
  int aX1  = (lanebase | (hl ^ 1))  << 2;
  int aX2  = (lanebase | (hl ^ 2))  << 2;
  int aX4  = (lanebase | (hl ^ 4))  << 2;
  int aX8  = (lanebase | (hl ^ 8))  << 2;
  int aX16 = (lanebase | (hl ^ 16)) << 2;
  int aRev = (lanebase | (31 - hl)) << 2;
  int aW   = (lanebase | 31)        << 2;

  unsigned long long vL = ~0ULL;      // per-half sorted top-32 (ascending by lane)
  unsigned long long worst = ~0ULL;   // per-lane copy of own half's vL[31]
  unsigned worst_hi = 0xFFFFFFFFu;
  float wd = __builtin_inff();        // worst distance as float (conservative gate)
  int F = 0;                          // buffered-candidate count (uniform within half)

  int base = range << 13;
  for (int n0 = base; n0 < base + 8192; n0 += 128) {
    float4 p0 = pb[n0 + hl];
    float4 p1 = pb[n0 + 32 + hl];
    float4 p2 = pb[n0 + 64 + hl];
    float4 p3 = pb[n0 + 96 + hl];
    float d[4];
    {
      float dt0 = (qx * p0.x + qy * p0.y) + qz * p0.z;   // contract off: exact ref order
      float dt1 = (qx * p1.x + qy * p1.y) + qz * p1.z;
      float dt2 = (qx * p2.x + qy * p2.y) + qz * p2.z;
      float dt3 = (qx * p3.x + qy * p3.y) + qz * p3.z;
      d[0] = __builtin_fmaf(-2.0f, dt0, qn + p0.w);      // == (qn+pn) - 2*dt exactly
      d[1] = __builtin_fmaf(-2.0f, dt1, qn + p1.w);
      d[2] = __builtin_fmaf(-2.0f, dt2, qn + p2.w);
      d[3] = __builtin_fmaf(-2.0f, dt3, qn + p3.w);
    }
    float md = fminf(fminf(d[0], d[1]), fminf(d[2], d[3]));
    if (__ballot(md <= wd)) {
#pragma unroll
      for (int t = 0; t < 4; t++) {
        bool sv = d[t] <= wd;           // float gate: conservative superset of exact u64 test
        unsigned long long bl = __ballot(sv);
        unsigned mb = half ? (unsigned)(bl >> 32) : (unsigned)bl;
        if (sv) {                       // survivors only: build exact u64 key (masked, no branch)
          unsigned u = __float_as_uint(d[t]);
          u ^= ((unsigned)(((int)u) >> 31)) | 0x80000000u;   // order-preserving map
          unsigned long long c = (((unsigned long long)u) << 32)
                               | (unsigned)(n0 + 32 * t + hl);
          bufh[F + __popc(mb & ((1u << hl) - 1u))] = c;
        }
        F += __popc(mb);
        if (__ballot(F >= 32)) {          // coherent: both halves merge together
          int take = F >= 32 ? 32 : F;    // partner half consumes its partial buffer
          unsigned long long vB = (hl < take) ? bufh[hl] : ~0ULL;
          knn_merge32(vL, worst, worst_hi, wd, vB, hl,
                      aX1, aX2, aX4, aX8, aX16, aRev, aW);
          int R = F - take;               // 0..31
          if (hl < R) bufh[hl] = bufh[32 + hl];   // reads 32..62, writes 0..30: disjoint
          F = R;
        }
      }
    }
  }
  if (__ballot(F > 0)) {   // flush remaining (<32) with +inf padding
    unsigned long long vB = (hl < F) ? bufh[hl] : ~0ULL;
    knn_merge32(vL, worst, worst_hi, wd, vB, hl, aX1, aX2, aX4, aX8, aX16, aRev, aW);
  }

  // cross-wave combine: waves (2k, 2k+1) hold lo/hi top-32 for the same queries
  bufh[hl] = vL;
  __syncthreads();
  unsigned long long vB = buf[wv ^ 1][half][hl];
  vL = u64min(vL, bperm64(vB, aRev));            // both sorted asc: reverse-pair min
  vL = selstage(vL, bperm64(vL, aX16), (hl & 16) != 0);
  vL = selstage(vL, bperm64(vL, aX8),  (hl & 8) != 0);
  vL = selstage(vL, bperm64(vL, aX4),  (hl & 4) != 0);
  vL = selstage(vL, bperm64(vL, aX2),  (hl & 2) != 0);
  vL = selstage(vL, bperm64(vL, aX1),  (hl & 1) != 0);
  if (range == 0)
    g_knn[((size_t)q << 5) | hl] = (unsigned short)(vL & 0xFFFF);
}

// ---------------- layer0: 128 pts/block (26.6 KB LDS, 6 blk/CU), pxyzn diffs, fused BN0 stats ----------------
__global__ __launch_bounds__(256) void k_l0() {
  __shared__ __attribute__((aligned(16))) short feats[128][104];   // 26.6 KB; reused as 20.5 KB f32 scratch
  int t = threadIdx.x;
  int p0 = blockIdx.x * 128;
  {
    int pt = t >> 1, h = t & 1;       // 2 threads per point
    int p = p0 + pt;
    int idx = g_knn[p];
    int s = (p >> 5) & 4095;
    int b = p >> 17;
    const short* src = g_ptb + ((size_t)((b << 14) + idx) << 6) + h * 32;
#pragma unroll
    for (int i = 0; i < 4; i++)
      ((int4*)&feats[pt][h * 32])[i] = ((const int4*)src)[i];
    if (h == 0) {
      const float4* pb4 = (const float4*)g_pxyzn + (b << 14);
      float4 a = pb4[idx], q = pb4[s];      // exact copies of xyz -> bit-identical diffs
      short4 d3;
      d3.x = f2b(a.x - q.x);
      d3.y = f2b(a.y - q.y);
      d3.z = f2b(a.z - q.z);
      d3.w = 0;
      *(short4*)&feats[pt][64] = d3;
      short4 z4; z4.x = 0; z4.y = 0; z4.z = 0; z4.w = 0;
      *(short4*)&feats[pt][68] = z4;
    } else {
      int4 z; z.x = 0; z.y = 0; z.z = 0; z.w = 0;
      *(int4*)&feats[pt][72] = z;
      *(int4*)&feats[pt][80] = z;
      *(int4*)&feats[pt][88] = z;
    }
  }
  __syncthreads();
  int lane = t & 63, wv = t >> 6;
  int l15 = lane & 15, quad = lane >> 4;
  bf16x8 A[4][3];
#pragma unroll
  for (int mt = 0; mt < 4; mt++)
#pragma unroll
    for (int kt = 0; kt < 3; kt++)
      A[mt][kt] = *(const bf16x8*)(g_Wb0 + (((mt * 3 + kt) * 64 + lane) << 3));
  f32x4 C[4][2];
#pragma unroll
  for (int mt = 0; mt < 4; mt++)
#pragma unroll
    for (int nt = 0; nt < 2; nt++) C[mt][nt] = 0.f;
#pragma unroll
  for (int kt = 0; kt < 3; kt++)
#pragma unroll
    for (int nt = 0; nt < 2; nt++) {
      bf16x8 B = *(const bf16x8*)(&feats[wv * 32 + nt * 16 + l15][kt * 32 + quad * 8]);
#pragma unroll
      for (int mt = 0; mt < 4; mt++)
        C[mt][nt] = __builtin_amdgcn_mfma_f32_16x16x32_bf16(A[mt][kt], B, C[mt][nt], 0, 0, 0);
    }
  float sA[16], qA[16];
#pragma unroll
  for (int i = 0; i < 16; i++) { sA[i] = 0.f; qA[i] = 0.f; }
#pragma unroll
  for (int mt = 0; mt < 4; mt++)
#pragma unroll
    for (int nt = 0; nt < 2; nt++) {
      int p = p0 + wv * 32 + nt * 16 + l15;
      int c0 = mt * 16 + quad * 4;
      uint2 o;
      o.x = pkbf(C[mt][nt][0], C[mt][nt][1]);
      o.y = pkbf(C[mt][nt][2], C[mt][nt][3]);
      *(uint2*)(g_x0b + ((size_t)p << 6) + c0) = o;
      float v0 = __uint_as_float(o.x << 16);
      float v1 = __uint_as_float(o.x & 0xFFFF0000u);
      float v2 = __uint_as_float(o.y << 16);
      float v3 = __uint_as_float(o.y & 0xFFFF0000u);
      int ib = mt * 4;
      sA[ib+0] += v0; qA[ib+0] = fmaf(v0, v0, qA[ib+0]);
      sA[ib+1] += v1; qA[ib+1] = fmaf(v1, v1, qA[ib+1]);
      sA[ib+2] += v2; qA[ib+2] = fmaf(v2, v2, qA[ib+2]);
      sA[ib+3] += v3; qA[ib+3] = fmaf(v3, v3, qA[ib+3]);
    }
  // fused BN0 stats, two-pass (S then Q) through 256x20 f32 scratch (20.5 KB)
  __syncthreads();                       // all waves done reading feats
  float* red = (float*)&feats[0][0];
  int rb = t * 20;
#pragma unroll
  for (int w = 0; w < 4; w++) {
    float4 vs; vs.x = sA[w*4+0]; vs.y = sA[w*4+1]; vs.z = sA[w*4+2]; vs.w = sA[w*4+3];
    *(float4*)&red[rb + w*4] = vs;
  }
  __syncthreads();
  float* sh = &g_p0s[blockIdx.x & 7][0];
  if (t < 64) {
    int qd = (t >> 2) & 3;               // quad of channel t
    int i = ((t >> 4) << 2) | (t & 3);   // register index mt*4+j
    float S = 0.f;
#pragma unroll
    for (int w = 0; w < 4; w++)
#pragma unroll
      for (int l = 0; l < 16; l++)
        S += red[(w * 64 + qd * 16 + l) * 20 + i];
    atomicAdd(sh + t, S);
  }
  __syncthreads();
#pragma unroll
  for (int w = 0; w < 4; w++) {
    float4 vq; vq.x = qA[w*4+0]; vq.y = qA[w*4+1]; vq.z = qA[w*4+2]; vq.w = qA[w*4+3];
    *(float4*)&red[rb + w*4] = vq;
  }
  __syncthreads();
  if (t < 64) {
    int qd = (t >> 2) & 3;
    int i = ((t >> 4) << 2) | (t & 3);
    float Q = 0.f;
#pragma unroll
    for (int w = 0; w < 4; w++)
#pragma unroll
      for (int l = 0; l < 16; l++)
        Q += red[(w * 64 + qd * 16 + l) * 20 + i];
    atomicAdd(sh + 64 + t, Q);
  }
}

// ---------------- layer1: BN0+leaky on x0 frags, MFMA K=64 -> x1 bf16 + fused BN1 stats ----------------
__global__ __launch_bounds__(256) void k_l1(const float* __restrict__ g0,
                                            const float* __restrict__ b0) {
  __shared__ float scA[64], shA[64];
  __shared__ __attribute__((aligned(16))) float red[256 * 36];   // 36 KB stats scratch
  int t = threadIdx.x;
  if (t < 64) {
    float ps = 0.f, pq = 0.f;
#pragma unroll
    for (int s = 0; s < 8; s++) { ps += g_p0s[s][t]; pq += g_p0s[s][64 + t]; }
    float m = ps / P_TOTF;
    float v = pq / P_TOTF - m * m;
    float sc = g0[t] / sqrtf(v + EPSV);
    scA[t] = sc; shA[t] = b0[t] - m * sc;
  }
  __syncthreads();
  int lane = t & 63, wv = t >> 6;
  int l15 = lane & 15, quad = lane >> 4;
  int p0 = blockIdx.x * 256 + wv * 64;
  float scv[2][8], shv[2][8];
#pragma unroll
  for (int kt = 0; kt < 2; kt++)
#pragma unroll
    for (int j = 0; j < 8; j++) {
      int c = kt * 32 + quad * 8 + j;
      scv[kt][j] = scA[c]; shv[kt][j] = shA[c];
    }
  bf16x8 A[4][2];
#pragma unroll
  for (int mt = 0; mt < 4; mt++)
#pragma unroll
    for (int kt = 0; kt < 2; kt++)
      A[mt][kt] = *(const bf16x8*)(g_Wb1 + (((mt * 2 + kt) * 64 + lane) << 3));
  f32x4 C[4][4];
#pragma unroll
  for (int mt = 0; mt < 4; mt++)
#pragma unroll
    for (int nt = 0; nt < 4; nt++) C[mt][nt] = 0.f;
#pragma unroll
  for (int kt = 0; kt < 2; kt++)
#pragma unroll
    for (int nt = 0; nt < 4; nt++) {
      const short* src = g_x0b + (((size_t)(p0 + nt * 16 + l15)) << 6) + kt * 32 + quad * 8;
      uint4 raw = *(const uint4*)src;
      bf16x8 B;
      unsigned* Bu = (unsigned*)&B;
      unsigned ru[4] = {raw.x, raw.y, raw.z, raw.w};
#pragma unroll
      for (int jj = 0; jj < 4; jj++) {
        float lo = __uint_as_float(ru[jj] << 16);
        float hi = __uint_as_float(ru[jj] & 0xFFFF0000u);
        float a0 = lo * scv[kt][2*jj]   + shv[kt][2*jj];
        float a1 = hi * scv[kt][2*jj+1] + shv[kt][2*jj+1];
        a0 = fmaxf(a0, 0.1f * a0);
        a1 = fmaxf(a1, 0.1f * a1);
        Bu[jj] = pkbf(a0, a1);
      }
#pragma unroll
      for (int mt = 0; mt < 4; mt++)
        C[mt][nt] = __builtin_amdgcn_mfma_f32_16x16x32_bf16(A[mt][kt], B, C[mt][nt], 0, 0, 0);
    }
  float sA[16], qA[16];
#pragma unroll
  for (int i = 0; i < 16; i++) { sA[i] = 0.f; qA[i] = 0.f; }
#pragma unroll
  for (int mt = 0; mt < 4; mt++)
#pragma unroll
    for (int nt = 0; nt < 4; nt++) {
      int p = p0 + nt * 16 + l15;
      int c0 = mt * 16 + quad * 4;
      uint2 o;
      o.x = pkbf(C[mt][nt][0], C[mt][nt][1]);
      o.y = pkbf(C[mt][nt][2], C[mt][nt][3]);
      *(uint2*)(g_x1b + ((size_t)p << 6) + c0) = o;
      float v0 = __uint_as_float(o.x << 16);
      float v1 = __uint_as_float(o.x & 0xFFFF0000u);
      float v2 = __uint_as_float(o.y << 16);
      float v3 = __uint_as_float(o.y & 0xFFFF0000u);
      int ib = mt * 4;
      sA[ib+0] += v0; qA[ib+0] = fmaf(v0, v0, qA[ib+0]);
      sA[ib+1] += v1; qA[ib+1] = fmaf(v1, v1, qA[ib+1]);
      sA[ib+2] += v2; qA[ib+2] = fmaf(v2, v2, qA[ib+2]);
      sA[ib+3] += v3; qA[ib+3] = fmaf(v3, v3, qA[ib+3]);
    }
  int rb = t * 36;
#pragma unroll
  for (int w = 0; w < 4; w++) {
    float4 vs; vs.x = sA[w*4+0]; vs.y = sA[w*4+1]; vs.z = sA[w*4+2]; vs.w = sA[w*4+3];
    float4 vq; vq.x = qA[w*4+0]; vq.y = qA[w*4+1]; vq.z = qA[w*4+2]; vq.w = qA[w*4+3];
    *(float4*)&red[rb + w*4] = vs;
    *(float4*)&red[rb + 16 + w*4] = vq;
  }
  __syncthreads();
  if (t < 64) {
    int qd = (t >> 2) & 3;
    int i = ((t >> 4) << 2) | (t & 3);
    float S = 0.f, Q = 0.f;
#pragma unroll
    for (int w = 0; w < 4; w++)
#pragma unroll
      for (int l = 0; l < 16; l++) {
        int row = (w * 64 + qd * 16 + l) * 36;
        S += red[row + i];
        Q += red[row + 16 + i];
      }
    float* sh = &g_p1s[blockIdx.x & 3][0];
    atomicAdd(sh + t, S);
    atomicAdd(sh + 64 + t, Q);
  }
}

// ---------------- layer2: BN1+leaky, MFMA M=128; fused k-max/min + BN2 stats (x2 never hits HBM) ----------------
__global__ __launch_bounds__(256) void k_l2(const float* __restrict__ g1,
                                            const float* __restrict__ b1) {
  __shared__ float scA[64], shA[64];
  __shared__ __attribute__((aligned(16))) float red[9216];   // 36 KB scratch (phase A: bf16 mx/mn; phase B: stats)
  int t = threadIdx.x;
  if (t < 64) {
    float ps = g_p1s[0][t] + g_p1s[1][t] + g_p1s[2][t] + g_p1s[3][t];
    float pq = g_p1s[0][64+t] + g_p1s[1][64+t] + g_p1s[2][64+t] + g_p1s[3][64+t];
    float m = ps / P_TOTF;
    float v = pq / P_TOTF - m * m;
    float sc = g1[t] / sqrtf(v + EPSV);
    scA[t] = sc; shA[t] = b1[t] - m * sc;
  }
  __syncthreads();
  int lane = t & 63, wv = t >> 6;
  int l15 = lane & 15, quad = lane >> 4;
  int chh = wv & 1;                      // channel half
  int p0 = blockIdx.x * 128 + (wv >> 1) * 64;
  float scv[2][8], shv[2][8];
#pragma unroll
  for (int kt = 0; kt < 2; kt++)
#pragma unroll
    for (int j = 0; j < 8; j++) {
      int c = kt * 32 + quad * 8 + j;
      scv[kt][j] = scA[c]; shv[kt][j] = shA[c];
    }
  bf16x8 A[4][2];
#pragma unroll
  for (int mt = 0; mt < 4; mt++)
#pragma unroll
    for (int kt = 0; kt < 2; kt++)
      A[mt][kt] = *(const bf16x8*)(g_Wb2 + ((((4 * chh + mt) * 2 + kt) * 64 + lane) << 3));
  f32x4 C[4][4];
#pragma unroll
  for (int mt = 0; mt < 4; mt++)
#pragma unroll
    for (int nt = 0; nt < 4; nt++) C[mt][nt] = 0.f;
#pragma unroll
  for (int kt = 0; kt < 2; kt++)
#pragma unroll
    for (int nt = 0; nt < 4; nt++) {
      const short* src = g_x1b + (((size_t)(p0 + nt * 16 + l15)) << 6) + kt * 32 + quad * 8;
      uint4 raw = *(const uint4*)src;
      bf16x8 B;
      unsigned* Bu = (unsigned*)&B;
      unsigned ru[4] = {raw.x, raw.y, raw.z, raw.w};
#pragma unroll
      for (int jj = 0; jj < 4; jj++) {
        float lo = __uint_as_float(ru[jj] << 16);
        float hi = __uint_as_float(ru[jj] & 0xFFFF0000u);
        float a0 = lo * scv[kt][2*jj]   + shv[kt][2*jj];
        float a1 = hi * scv[kt][2*jj+1] + shv[kt][2*jj+1];
        a0 = fmaxf(a0, 0.1f * a0);
        a1 = fmaxf(a1, 0.1f * a1);
        Bu[jj] = pkbf(a0, a1);
      }
#pragma unroll
      for (int mt = 0; mt < 4; mt++)
        C[mt][nt] = __builtin_amdgcn_mfma_f32_16x16x32_bf16(A[mt][kt], B, C[mt][nt], 0, 0, 0);
    }
  // per-lane: bf16-rounded values -> stats accum + per-s-subgroup partial max/min
  float sA[16], qA[16];
  float mxP[2][16], mnP[2][16];
#pragma unroll
  for (int i = 0; i < 16; i++) {
    sA[i] = 0.f; qA[i] = 0.f;
    mxP[0][i] = -3.4e38f; mnP[0][i] = 3.4e38f;
    mxP[1][i] = -3.4e38f; mnP[1][i] = 3.4e38f;
  }
#pragma unroll
  for (int mt = 0; mt < 4; mt++)
#pragma unroll
    for (int nt = 0; nt < 4; nt++) {
      unsigned ox = pkbf(C[mt][nt][0], C[mt][nt][1]);
      unsigned oy = pkbf(C[mt][nt][2], C[mt][nt][3]);
      float v0 = __uint_as_float(ox << 16);
      float v1 = __uint_as_float(ox & 0xFFFF0000u);
      float v2 = __uint_as_float(oy << 16);
      float v3 = __uint_as_float(oy & 0xFFFF0000u);
      int ib = mt * 4, sp = nt >> 1;
      sA[ib+0] += v0; qA[ib+0] = fmaf(v0, v0, qA[ib+0]);
      sA[ib+1] += v1; qA[ib+1] = fmaf(v1, v1, qA[ib+1]);
      sA[ib+2] += v2; qA[ib+2] = fmaf(v2, v2, qA[ib+2]);
      sA[ib+3] += v3; qA[ib+3] = fmaf(v3, v3, qA[ib+3]);
      mxP[sp][ib+0] = fmaxf(mxP[sp][ib+0], v0); mnP[sp][ib+0] = fminf(mnP[sp][ib+0], v0);
      mxP[sp][ib+1] = fmaxf(mxP[sp][ib+1], v1); mnP[sp][ib+1] = fminf(mnP[sp][ib+1], v1);
      mxP[sp][ib+2] = fmaxf(mxP[sp][ib+2], v2); mnP[sp][ib+2] = fminf(mnP[sp][ib+2], v2);
      mxP[sp][ib+3] = fmaxf(mxP[sp][ib+3], v3); mnP[sp][ib+3] = fminf(mnP[sp][ib+3], v3);
    }
  // phase A: bf16 partial max/min -> LDS [4 sg][16 l15][132 c], reduce over l15 -> g_mx/g_mn
  short* mxs = (short*)red;              // 4*16*132 shorts = 16896 B
  short* mns = mxs + 8448;               // second 16896 B (total 33792 <= 36864)
  int sgl0 = (wv >> 1) * 2;
#pragma unroll
  for (int sp = 0; sp < 2; sp++)
#pragma unroll
    for (int mt = 0; mt < 4; mt++) {
      int c0 = (4 * chh + mt) * 16 + quad * 4;
      int base = ((sgl0 + sp) * 16 + l15) * 132 + c0;
      short4 m4;
      m4.x = f2b(mxP[sp][mt*4+0]); m4.y = f2b(mxP[sp][mt*4+1]);
      m4.z = f2b(mxP[sp][mt*4+2]); m4.w = f2b(mxP[sp][mt*4+3]);
      *(short4*)&mxs[base] = m4;
      short4 n4;
      n4.x = f2b(mnP[sp][mt*4+0]); n4.y = f2b(mnP[sp][mt*4+1]);
      n4.z = f2b(mnP[sp][mt*4+2]); n4.w = f2b(mnP[sp][mt*4+3]);
      *(short4*)&mns[base] = n4;
    }
  __syncthreads();
  {
    int sg = t >> 6, c0 = (t & 63) * 2;   // each thread: 1 s-group, 2 channels
    float m0 = -3.4e38f, m1 = -3.4e38f, n0 = 3.4e38f, n1 = 3.4e38f;
#pragma unroll
    for (int l = 0; l < 16; l++) {
      unsigned ux = *(const unsigned*)&mxs[(sg * 16 + l) * 132 + c0];
      m0 = fmaxf(m0, __uint_as_float(ux << 16));
      m1 = fmaxf(m1, __uint_as_float(ux & 0xFFFF0000u));
      unsigned un = *(const unsigned*)&mns[(sg * 16 + l) * 132 + c0];
      n0 = fminf(n0, __uint_as_float(un << 16));
      n1 = fminf(n1, __uint_as_float(un & 0xFFFF0000u));
    }
    int sgg = blockIdx.x * 4 + sg;
    float2 vmx; vmx.x = m0; vmx.y = m1;
    float2 vmn; vmn.x = n0; vmn.y = n1;
    *(float2*)(g_mx + ((size_t)sgg << 7) + c0) = vmx;
    *(float2*)(g_mn + ((size_t)sgg << 7) + c0) = vmn;
  }
  __syncthreads();
  // phase B: BN2 stats (r12 pattern), 128 channels from 2 waves each
  int rb = t * 36;
#pragma unroll
  for (int w = 0; w < 4; w++) {
    float4 vs; vs.x = sA[w*4+0]; vs.y = sA[w*4+1]; vs.z = sA[w*4+2]; vs.w = sA[w*4+3];
    float4 vq; vq.x = qA[w*4+0]; vq.y = qA[w*4+1]; vq.z = qA[w*4+2]; vq.w = qA[w*4+3];
    *(float4*)&red[rb + w*4] = vs;
    *(float4*)&red[rb + 16 + w*4] = vq;
  }
  __syncthreads();
  if (t < 128) {
    int c = t;
    int ch2 = c >> 6, mt = (c >> 4) & 3, qd = (c >> 2) & 3, j = c & 3;
    int i = mt * 4 + j;
    float S = 0.f, Q = 0.f;
#pragma unroll
    for (int w = 0; w < 2; w++) {
      int wvv = ch2 + w * 2;
#pragma unroll
      for (int l = 0; l < 16; l++) {
        int row = (wvv * 64 + qd * 16 + l) * 36;
        S += red[row + i];
        Q += red[row + 16 + i];
      }
    }
    float* sh = &g_p2s[blockIdx.x & 7][0];
    atomicAdd(sh + c, S);
    atomicAdd(sh + 128 + c, Q);
  }
}

// ---------------- epilogue: BN2+leaky on precomputed max/min, coalesced r/w ----------------
__global__ __launch_bounds__(256) void k_epi(const float* __restrict__ g2,
                                             const float* __restrict__ b2,
                                             float* __restrict__ out) {
  __shared__ float scA[128], shA[128];
  __shared__ float res[16][132];
  int t = threadIdx.x;
  if (t < 128) {
    float ps = 0.f, pq = 0.f;
#pragma unroll
    for (int s = 0; s < 8; s++) { ps += g_p2s[s][t]; pq += g_p2s[s][128 + t]; }
    float m = ps / P_TOTF;
    float v = pq / P_TOTF - m * m;
    float sc = g2[t] / sqrtf(v + EPSV);
    scA[t] = sc; shA[t] = b2[t] - m * sc;
  }
  __syncthreads();
  int cp = t & 63, sl = t >> 6;        // channels 2cp,2cp+1 ; sl in 0..3
  int c0 = cp * 2, c1 = c0 + 1;
  float sc0 = scA[c0], sh0 = shA[c0];
  float sc1 = scA[c1], sh1 = shA[c1];
  int sg0 = blockIdx.x * 16;
  for (int it = 0; it < 4; it++) {
    int sgl = sl * 4 + it;             // 0..15, each once per block
    size_t off = ((size_t)(sg0 + sgl) << 7) + c0;
    float2 vmx = *(const float2*)(g_mx + off);
    float2 vmn = *(const float2*)(g_mn + off);
    float a0 = (sc0 >= 0.f ? vmx.x : vmn.x) * sc0 + sh0; a0 = fmaxf(a0, 0.1f * a0);
    float a1 = (sc1 >= 0.f ? vmx.y : vmn.y) * sc1 + sh1; a1 = fmaxf(a1, 0.1f * a1);
    res[sgl][c0] = a0; res[sgl][c1] = a1;
  }
  __syncthreads();
  int b = sg0 >> 12, s0 = sg0 & 4095;   // block never straddles b (4096 % 16 == 0)
#pragma unroll
  for (int w = 0; w < 2; w++) {
    int fidx = t * 2 + w;               // 0..511
    int c = fidx >> 2, qi = fidx & 3;
    float4 o;
    o.x = res[qi * 4 + 0][c];
    o.y = res[qi * 4 + 1][c];
    o.z = res[qi * 4 + 2][c];
    o.w = res[qi * 4 + 3][c];
    *(float4*)(out + 24576 + (((size_t)(b * 128 + c)) << 12) + s0 + qi * 4) = o;
  }
}

extern "C" void kernel_launch(void* const* d_in, const int* in_sizes, int n_in,
                              void* d_out, int out_size, void* d_ws, size_t ws_size,
                              hipStream_t stream) {
  (void)in_sizes; (void)n_in; (void)out_size; (void)d_ws; (void)ws_size;
  const float* xyz    = (const float*)d_in[0];
  const float* points = (const float*)d_in[1];
  const float* W0     = (const float*)d_in[2];
  const float* W1     = (const float*)d_in[3];
  const float* W2     = (const float*)d_in[4];
  const float* g0     = (const float*)d_in[5];
  const float* b0     = (const float*)d_in[6];
  const float* g1     = (const float*)d_in[7];
  const float* b1     = (const float*)d_in[8];
  const float* g2     = (const float*)d_in[9];
  const float* b2     = (const float*)d_in[10];
  float* out = (float*)d_out;

  hipLaunchKernelGGL(k_setup, dim3(641),  dim3(256), 0, stream, xyz, points, W0, W1, W2, out);
  hipLaunchKernelGGL(k_knn,   dim3(2048), dim3(256), 0, stream);
  hipLaunchKernelGGL(k_l0,    dim3(2048), dim3(256), 0, stream);
  hipLaunchKernelGGL(k_l1,    dim3(1024), dim3(256), 0, stream, g0, b0);
  hipLaunchKernelGGL(k_l2,    dim3(2048), dim3(256), 0, stream, g1, b1);
  hipLaunchKernelGGL(k_epi,   dim3(512),  dim3(256), 0, stream, g2, b2, out);
}

// Round 15
// 283.055 us; speedup vs baseline: 1.1030x; 1.0054x over previous
//
#include <hip/hip_runtime.h>
#include <hip/hip_bf16.h>
#include <stdint.h>

#define N_ALL   16384
#define NPOINT  4096
#define KNN_K   32
#define BATCH   2
#define P_TOT   (BATCH*NPOINT*KNN_K)   /* 262144 */
#define P_TOTF  262144.0f
#define EPSV    1e-5f

typedef __attribute__((ext_vector_type(8))) short bf16x8;
typedef __attribute__((ext_vector_type(4))) float f32x4;

// ---- all scratch in module-static device memory; d_ws untouched ----
__device__ unsigned short g_knn[P_TOT];                                   // 512 KB
__device__ __attribute__((aligned(16))) float g_pxyzn[BATCH*N_ALL*4];     // 512 KB (x,y,z,|x|^2)
__device__ __attribute__((aligned(16))) short g_ptb[BATCH*N_ALL*64];      // 4 MB  [b,n][64c] bf16
__device__ __attribute__((aligned(16))) short g_x0b[(size_t)P_TOT*64];    // 32 MB [p][64] bf16
__device__ __attribute__((aligned(16))) short g_x1b[(size_t)P_TOT*64];    // 32 MB
__device__ __attribute__((aligned(16))) float g_mx[(size_t)BATCH*NPOINT*128];  // 4 MB
__device__ __attribute__((aligned(16))) float g_mn[(size_t)BATCH*NPOINT*128];  // 4 MB
__device__ __attribute__((aligned(16))) short g_Wb0[4*3*64*8];            // swizzled A-frags
__device__ __attribute__((aligned(16))) short g_Wb1[4*2*64*8];
__device__ __attribute__((aligned(16))) short g_Wb2[8*2*64*8];
__device__ float g_p0s[8][128];      // BN0 stats shadows (2048 blocks / 8 = 256/addr)
__device__ float g_p1s[8][128];      // BN1 stats shadows (2048 blocks / 8 = 256/addr)
__device__ float g_p2s[8][256];      // BN2 stats shadows (2048 blocks / 8 = 256/addr)

__device__ __forceinline__ float b2f(short s) {
  union { unsigned u; float f; } v; v.u = ((unsigned)(unsigned short)s) << 16; return v.f;
}
__device__ __forceinline__ short f2b(float f) {
  union { float f; unsigned u; } v; v.f = f;
  unsigned u = v.u;
  u += 0x7FFFu + ((u >> 16) & 1u);
  return (short)(u >> 16);
}
// packed f32x2 -> bf16x2 (v_cvt_pk_bf16_f32, RNE — bit-identical to f2b pairs)
__device__ __forceinline__ unsigned pkbf(float a, float b) {
  union { __hip_bfloat162 h; unsigned u; } v;
  v.h = __float22bfloat162_rn(make_float2(a, b));
  return v.u;
}
__device__ __forceinline__ unsigned long long bperm64(unsigned long long v, int byteaddr) {
  int lo = __builtin_amdgcn_ds_bpermute(byteaddr, (int)(unsigned)(v & 0xFFFFFFFFULL));
  int hi = __builtin_amdgcn_ds_bpermute(byteaddr, (int)(unsigned)(v >> 32));
  return (((unsigned long long)(unsigned)hi) << 32) | (unsigned)lo;
}
__device__ __forceinline__ unsigned long long u64min(unsigned long long a, unsigned long long b) {
  return a < b ? a : b;
}
// bitonic compare-exchange step: keep min (mx=0) or max (mx=1) of (v, pv)
__device__ __forceinline__ unsigned long long selstage(unsigned long long v,
                                                       unsigned long long pv, bool mx) {
  bool lt = v < pv;
  return (lt != mx) ? v : pv;
}

// sort 32 buffered candidates (vB, one per lane within a 32-lane half) ascending,
// merge lowest-32 of (vL ∪ vB) back into vL (sorted), refresh worst_hi/wd.
__device__ __forceinline__ void knn_merge32(unsigned long long& vL,
                                            unsigned long long& worst,
                                            unsigned& worst_hi, float& wd,
                                            unsigned long long vB, int hl,
                                            int aX1, int aX2, int aX4, int aX8,
                                            int aX16, int aRev, int aW) {
  vB = selstage(vB, bperm64(vB, aX1),  ((hl & 1) != 0) != ((hl & 2) != 0));
  vB = selstage(vB, bperm64(vB, aX2),  ((hl & 2) != 0) != ((hl & 4) != 0));
  vB = selstage(vB, bperm64(vB, aX1),  ((hl & 1) != 0) != ((hl & 4) != 0));
  vB = selstage(vB, bperm64(vB, aX4),  ((hl & 4) != 0) != ((hl & 8) != 0));
  vB = selstage(vB, bperm64(vB, aX2),  ((hl & 2) != 0) != ((hl & 8) != 0));
  vB = selstage(vB, bperm64(vB, aX1),  ((hl & 1) != 0) != ((hl & 8) != 0));
  vB = selstage(vB, bperm64(vB, aX8),  ((hl & 8) != 0) != ((hl & 16) != 0));
  vB = selstage(vB, bperm64(vB, aX4),  ((hl & 4) != 0) != ((hl & 16) != 0));
  vB = selstage(vB, bperm64(vB, aX2),  ((hl & 2) != 0) != ((hl & 16) != 0));
  vB = selstage(vB, bperm64(vB, aX1),  ((hl & 1) != 0) != ((hl & 16) != 0));
  vB = selstage(vB, bperm64(vB, aX16), (hl & 16) != 0);
  vB = selstage(vB, bperm64(vB, aX8),  (hl & 8) != 0);
  vB = selstage(vB, bperm64(vB, aX4),  (hl & 4) != 0);
  vB = selstage(vB, bperm64(vB, aX2),  (hl & 2) != 0);
  vB = selstage(vB, bperm64(vB, aX1),  (hl & 1) != 0);
  // vL asc, vB asc: pair lane i with reversed buffer -> lowest 32 (bitonic), then cleanup
  vL = u64min(vL, bperm64(vB, aRev));
  vL = selstage(vL, bperm64(vL, aX16), (hl & 16) != 0);
  vL = selstage(vL, bperm64(vL, aX8),  (hl & 8) != 0);
  vL = selstage(vL, bperm64(vL, aX4),  (hl & 4) != 0);
  vL = selstage(vL, bperm64(vL, aX2),  (hl & 2) != 0);
  vL = selstage(vL, bperm64(vL, aX1),  (hl & 1) != 0);
  worst = bperm64(vL, aW);
  worst_hi = (unsigned)(worst >> 32);
  unsigned wh = worst_hi;
  unsigned ub = (wh & 0x80000000u) ? (wh ^ 0x80000000u) : ~wh;
  wd = (wh == 0xFFFFFFFFu) ? __builtin_inff() : __uint_as_float(ub);
}

// ---------------- setup: tpose (blk<512) | copy+pack (512..639) | wprep (640) ----------------
__global__ __launch_bounds__(256) void k_setup(const float* __restrict__ xyz,
                                               const float* __restrict__ points,
                                               const float* __restrict__ W0,
                                               const float* __restrict__ W1,
                                               const float* __restrict__ W2,
                                               float* __restrict__ out) {
#pragma clang fp contract(off)
  __shared__ float tile[64][65];
  int blk = blockIdx.x;
  int t = threadIdx.x;
  if (blk < 512) {
    int b  = blk >> 8;
    int n0 = (blk & 255) << 6;
#pragma unroll
    for (int r = 0; r < 16; r++) {
      int lin = r * 256 + t;
      int c = lin >> 6, nn = lin & 63;
      tile[c][nn] = points[((size_t)(b * 64 + c)) * N_ALL + n0 + nn];
    }
    __syncthreads();
#pragma unroll
    for (int r = 0; r < 16; r++) {
      int lin = r * 256 + t;
      int nn = lin >> 6, c = lin & 63;
      g_ptb[((size_t)(b * N_ALL + n0 + nn)) * 64 + c] = f2b(tile[c][nn]);
    }
  } else if (blk < 640) {
    int i = (blk - 512) * 256 + t;   // < 32768
    if (i < 24576) {
      int s = i & 4095;
      int c = (i >> 12) % 3;
      int b = i / 12288;
      out[i] = xyz[(b * 3 + c) * N_ALL + s];
    }
    int b = i >> 14, n = i & 16383;
    const float* xb = xyz + b * 3 * N_ALL;
    float x = xb[n], y = xb[N_ALL + n], z = xb[2 * N_ALL + n];
    float4 p; p.x = x; p.y = y; p.z = z; p.w = x * x + y * y + z * z;
    ((float4*)g_pxyzn)[i] = p;
  } else {
    for (int i = t; i < 4 * 3 * 64 * 8; i += 256) {
      int j = i & 7, lane = (i >> 3) & 63, rest = i >> 9;
      int kt = rest % 3, mt = rest / 3;
      int m = 16 * mt + (lane & 15);
      int k = 32 * kt + (lane >> 4) * 8 + j;
      float v = 0.f;
      if (k < 64) v = W0[m * 67 + 3 + k];
      else if (k < 67) v = W0[m * 67 + (k - 64)];
      g_Wb0[i] = f2b(v);
    }
    for (int i = t; i < 4 * 2 * 64 * 8; i += 256) {
      int j = i & 7, lane = (i >> 3) & 63;
      int kt = (i >> 9) & 1, mt = i >> 10;
      int m = 16 * mt + (lane & 15);
      int k = 32 * kt + (lane >> 4) * 8 + j;
      g_Wb1[i] = f2b(W1[m * 64 + k]);
    }
    for (int i = t; i < 8 * 2 * 64 * 8; i += 256) {
      int j = i & 7, lane = (i >> 3) & 63;
      int kt = (i >> 9) & 1, mt = i >> 10;
      int m = 16 * mt + (lane & 15);
      int k = 32 * kt + (lane >> 4) * 8 + j;
      g_Wb2[i] = f2b(W2[m * 64 + k]);
    }
    float* z0 = &g_p0s[0][0];
    float* z1 = &g_p1s[0][0];
    float* z2 = &g_p2s[0][0];
    for (int i = t; i < 1024; i += 256) { z0[i] = 0.f; z1[i] = 0.f; }
    for (int i = t; i < 2048; i += 256) z2[i] = 0.f;
  }
}

// ---------------- KNN: split-N 2-way, 2 queries/wave, float gate + survivor-only keys ----------------
__global__ __launch_bounds__(256, 8) void k_knn() {
#pragma clang fp contract(off)
  __shared__ unsigned long long buf[4][2][64];
  int wv = threadIdx.x >> 6;
  int lane = threadIdx.x & 63;
  int half = lane >> 5;            // 0: lanes 0..31 (query A), 1: lanes 32..63 (query B)
  int hl = lane & 31;
  int lanebase = lane & 32;
  unsigned long long* bufh = buf[wv][half];

  int qpair = wv >> 1;             // waves {0,1} share queries, {2,3} share queries
  int range = wv & 1;              // 0: points [0,8192), 1: [8192,16384)
  int q = blockIdx.x * 4 + qpair * 2 + half;   // 0..8191
  int b = q >> 12, s = q & 4095;
  const float4* pb = (const float4*)g_pxyzn + (b << 14);
  float4 qp = pb[s];
  float qx = qp.x, qy = qp.y, qz = qp.z, qn = qp.w;

  // hoisted cross-lane byte addresses (stay within own 32-lane half)
  int aX1  = (lanebase | (hl ^ 1))  << 2;
  int aX2  = (lanebase | (hl ^ 2))  << 2;
  int aX4  = (lanebase | (hl ^ 4))  << 2;
  int aX8  = (lanebase | (hl ^ 8))  << 2;
  int aX16 = (lanebase | (hl ^ 16)) << 2;
  int aRev = (lanebase | (31 - hl)) << 2;
  int aW   = (lanebase | 31)        << 2;

  unsigned long long vL = ~0ULL;      // per-half sorted top-32 (ascending by lane)
  unsigned long long worst = ~0ULL;   // per-lane copy of own half's vL[31]
  unsigned worst_hi = 0xFFFFFFFFu;
  float wd = __builtin_inff();        // worst distance as float (conservative gate)
  int F = 0;                          // buffered-candidate count (uniform within half)

  int base = range << 13;
  for (int n0 = base; n0 < base + 8192; n0 += 128) {
    float4 p0 = pb[n0 + hl];
    float4 p1 = pb[n0 + 32 + hl];
    float4 p2 = pb[n0 + 64 + hl];
    float4 p3 = pb[n0 + 96 + hl];
    float d[4];
    {
      float dt0 = (qx * p0.x + qy * p0.y) + qz * p0.z;   // contract off: exact ref order
      float dt1 = (qx * p1.x + qy * p1.y) + qz * p1.z;
      float dt2 = (qx * p2.x + qy * p2.y) + qz * p2.z;
      float dt3 = (qx * p3.x + qy * p3.y) + qz * p3.z;
      d[0] = __builtin_fmaf(-2.0f, dt0, qn + p0.w);      // == (qn+pn) - 2*dt exactly
      d[1] = __builtin_fmaf(-2.0f, dt1, qn + p1.w);
      d[2] = __builtin_fmaf(-2.0f, dt2, qn + p2.w);
      d[3] = __builtin_fmaf(-2.0f, dt3, qn + p3.w);
    }
    float md = fminf(fminf(d[0], d[1]), fminf(d[2], d[3]));
    if (__ballot(md <= wd)) {
#pragma unroll
      for (int t = 0; t < 4; t++) {
        bool sv = d[t] <= wd;           // float gate: conservative superset of exact u64 test
        unsigned long long bl = __ballot(sv);
        unsigned mb = half ? (unsigned)(bl >> 32) : (unsigned)bl;
        if (sv) {                       // survivors only: build exact u64 key (masked, no branch)
          unsigned u = __float_as_uint(d[t]);
          u ^= ((unsigned)(((int)u) >> 31)) | 0x80000000u;   // order-preserving map
          unsigned long long c = (((unsigned long long)u) << 32)
                               | (unsigned)(n0 + 32 * t + hl);
          bufh[F + __popc(mb & ((1u << hl) - 1u))] = c;
        }
        F += __popc(mb);
        if (__ballot(F >= 32)) {          // coherent: both halves merge together
          int take = F >= 32 ? 32 : F;    // partner half consumes its partial buffer
          unsigned long long vB = (hl < take) ? bufh[hl] : ~0ULL;
          knn_merge32(vL, worst, worst_hi, wd, vB, hl,
                      aX1, aX2, aX4, aX8, aX16, aRev, aW);
          int R = F - take;               // 0..31
          if (hl < R) bufh[hl] = bufh[32 + hl];   // reads 32..62, writes 0..30: disjoint
          F = R;
        }
      }
    }
  }
  if (__ballot(F > 0)) {   // flush remaining (<32) with +inf padding
    unsigned long long vB = (hl < F) ? bufh[hl] : ~0ULL;
    knn_merge32(vL, worst, worst_hi, wd, vB, hl, aX1, aX2, aX4, aX8, aX16, aRev, aW);
  }

  // cross-wave combine: waves (2k, 2k+1) hold lo/hi top-32 for the same queries
  bufh[hl] = vL;
  __syncthreads();
  unsigned long long vB = buf[wv ^ 1][half][hl];
  vL = u64min(vL, bperm64(vB, aRev));            // both sorted asc: reverse-pair min
  vL = selstage(vL, bperm64(vL, aX16), (hl & 16) != 0);
  vL = selstage(vL, bperm64(vL, aX8),  (hl & 8) != 0);
  vL = selstage(vL, bperm64(vL, aX4),  (hl & 4) != 0);
  vL = selstage(vL, bperm64(vL, aX2),  (hl & 2) != 0);
  vL = selstage(vL, bperm64(vL, aX1),  (hl & 1) != 0);
  if (range == 0)
    g_knn[((size_t)q << 5) | hl] = (unsigned short)(vL & 0xFFFF);
}

// ---------------- layer0: 128 pts/block (26.6 KB LDS, 6 blk/CU), pxyzn diffs, fused BN0 stats ----------------
__global__ __launch_bounds__(256) void k_l0() {
  __shared__ __attribute__((aligned(16))) short feats[128][104];   // 26.6 KB; reused as 20.5 KB f32 scratch
  int t = threadIdx.x;
  int p0 = blockIdx.x * 128;
  {
    int pt = t >> 1, h = t & 1;       // 2 threads per point
    int p = p0 + pt;
    int idx = g_knn[p];
    int s = (p >> 5) & 4095;
    int b = p >> 17;
    const short* src = g_ptb + ((size_t)((b << 14) + idx) << 6) + h * 32;
#pragma unroll
    for (int i = 0; i < 4; i++)
      ((int4*)&feats[pt][h * 32])[i] = ((const int4*)src)[i];
    if (h == 0) {
      const float4* pb4 = (const float4*)g_pxyzn + (b << 14);
      float4 a = pb4[idx], q = pb4[s];      // exact copies of xyz -> bit-identical diffs
      short4 d3;
      d3.x = f2b(a.x - q.x);
      d3.y = f2b(a.y - q.y);
      d3.z = f2b(a.z - q.z);
      d3.w = 0;
      *(short4*)&feats[pt][64] = d3;
      short4 z4; z4.x = 0; z4.y = 0; z4.z = 0; z4.w = 0;
      *(short4*)&feats[pt][68] = z4;
    } else {
      int4 z; z.x = 0; z.y = 0; z.z = 0; z.w = 0;
      *(int4*)&feats[pt][72] = z;
      *(int4*)&feats[pt][80] = z;
      *(int4*)&feats[pt][88] = z;
    }
  }
  __syncthreads();
  int lane = t & 63, wv = t >> 6;
  int l15 = lane & 15, quad = lane >> 4;
  bf16x8 A[4][3];
#pragma unroll
  for (int mt = 0; mt < 4; mt++)
#pragma unroll
    for (int kt = 0; kt < 3; kt++)
      A[mt][kt] = *(const bf16x8*)(g_Wb0 + (((mt * 3 + kt) * 64 + lane) << 3));
  f32x4 C[4][2];
#pragma unroll
  for (int mt = 0; mt < 4; mt++)
#pragma unroll
    for (int nt = 0; nt < 2; nt++) C[mt][nt] = 0.f;
#pragma unroll
  for (int kt = 0; kt < 3; kt++)
#pragma unroll
    for (int nt = 0; nt < 2; nt++) {
      bf16x8 B = *(const bf16x8*)(&feats[wv * 32 + nt * 16 + l15][kt * 32 + quad * 8]);
#pragma unroll
      for (int mt = 0; mt < 4; mt++)
        C[mt][nt] = __builtin_amdgcn_mfma_f32_16x16x32_bf16(A[mt][kt], B, C[mt][nt], 0, 0, 0);
    }
  float sA[16], qA[16];
#pragma unroll
  for (int i = 0; i < 16; i++) { sA[i] = 0.f; qA[i] = 0.f; }
#pragma unroll
  for (int mt = 0; mt < 4; mt++)
#pragma unroll
    for (int nt = 0; nt < 2; nt++) {
      int p = p0 + wv * 32 + nt * 16 + l15;
      int c0 = mt * 16 + quad * 4;
      uint2 o;
      o.x = pkbf(C[mt][nt][0], C[mt][nt][1]);
      o.y = pkbf(C[mt][nt][2], C[mt][nt][3]);
      *(uint2*)(g_x0b + ((size_t)p << 6) + c0) = o;
      float v0 = __uint_as_float(o.x << 16);
      float v1 = __uint_as_float(o.x & 0xFFFF0000u);
      float v2 = __uint_as_float(o.y << 16);
      float v3 = __uint_as_float(o.y & 0xFFFF0000u);
      int ib = mt * 4;
      sA[ib+0] += v0; qA[ib+0] = fmaf(v0, v0, qA[ib+0]);
      sA[ib+1] += v1; qA[ib+1] = fmaf(v1, v1, qA[ib+1]);
      sA[ib+2] += v2; qA[ib+2] = fmaf(v2, v2, qA[ib+2]);
      sA[ib+3] += v3; qA[ib+3] = fmaf(v3, v3, qA[ib+3]);
    }
  // fused BN0 stats, two-pass (S then Q) through 256x20 f32 scratch (20.5 KB)
  __syncthreads();                       // all waves done reading feats
  float* red = (float*)&feats[0][0];
  int rb = t * 20;
#pragma unroll
  for (int w = 0; w < 4; w++) {
    float4 vs; vs.x = sA[w*4+0]; vs.y = sA[w*4+1]; vs.z = sA[w*4+2]; vs.w = sA[w*4+3];
    *(float4*)&red[rb + w*4] = vs;
  }
  __syncthreads();
  float* sh = &g_p0s[blockIdx.x & 7][0];
  if (t < 64) {
    int qd = (t >> 2) & 3;               // quad of channel t
    int i = ((t >> 4) << 2) | (t & 3);   // register index mt*4+j
    float S = 0.f;
#pragma unroll
    for (int w = 0; w < 4; w++)
#pragma unroll
      for (int l = 0; l < 16; l++)
        S += red[(w * 64 + qd * 16 + l) * 20 + i];
    atomicAdd(sh + t, S);
  }
  __syncthreads();
#pragma unroll
  for (int w = 0; w < 4; w++) {
    float4 vq; vq.x = qA[w*4+0]; vq.y = qA[w*4+1]; vq.z = qA[w*4+2]; vq.w = qA[w*4+3];
    *(float4*)&red[rb + w*4] = vq;
  }
  __syncthreads();
  if (t < 64) {
    int qd = (t >> 2) & 3;
    int i = ((t >> 4) << 2) | (t & 3);
    float Q = 0.f;
#pragma unroll
    for (int w = 0; w < 4; w++)
#pragma unroll
      for (int l = 0; l < 16; l++)
        Q += red[(w * 64 + qd * 16 + l) * 20 + i];
    atomicAdd(sh + 64 + t, Q);
  }
}

// ---------------- layer1: 128 pts/block, C[4][2] (VGPR diet), fused BN1 stats ----------------
__global__ __launch_bounds__(256) void k_l1(const float* __restrict__ g0,
                                            const float* __restrict__ b0) {
  __shared__ float scA[64], shA[64];
  __shared__ __attribute__((aligned(16))) float red[256 * 20];   // 20.5 KB stats scratch
  int t = threadIdx.x;
  if (t < 64) {
    float ps = 0.f, pq = 0.f;
#pragma unroll
    for (int s = 0; s < 8; s++) { ps += g_p0s[s][t]; pq += g_p0s[s][64 + t]; }
    float m = ps / P_TOTF;
    float v = pq / P_TOTF - m * m;
    float sc = g0[t] / sqrtf(v + EPSV);
    scA[t] = sc; shA[t] = b0[t] - m * sc;
  }
  __syncthreads();
  int lane = t & 63, wv = t >> 6;
  int l15 = lane & 15, quad = lane >> 4;
  int p0 = blockIdx.x * 128 + wv * 32;
  float scv[2][8], shv[2][8];
#pragma unroll
  for (int kt = 0; kt < 2; kt++)
#pragma unroll
    for (int j = 0; j < 8; j++) {
      int c = kt * 32 + quad * 8 + j;
      scv[kt][j] = scA[c]; shv[kt][j] = shA[c];
    }
  bf16x8 A[4][2];
#pragma unroll
  for (int mt = 0; mt < 4; mt++)
#pragma unroll
    for (int kt = 0; kt < 2; kt++)
      A[mt][kt] = *(const bf16x8*)(g_Wb1 + (((mt * 2 + kt) * 64 + lane) << 3));
  f32x4 C[4][2];
#pragma unroll
  for (int mt = 0; mt < 4; mt++)
#pragma unroll
    for (int nt = 0; nt < 2; nt++) C[mt][nt] = 0.f;
#pragma unroll
  for (int kt = 0; kt < 2; kt++)
#pragma unroll
    for (int nt = 0; nt < 2; nt++) {
      const short* src = g_x0b + (((size_t)(p0 + nt * 16 + l15)) << 6) + kt * 32 + quad * 8;
      uint4 raw = *(const uint4*)src;
      bf16x8 B;
      unsigned* Bu = (unsigned*)&B;
      unsigned ru[4] = {raw.x, raw.y, raw.z, raw.w};
#pragma unroll
      for (int jj = 0; jj < 4; jj++) {
        float lo = __uint_as_float(ru[jj] << 16);
        float hi = __uint_as_float(ru[jj] & 0xFFFF0000u);
        float a0 = lo * scv[kt][2*jj]   + shv[kt][2*jj];
        float a1 = hi * scv[kt][2*jj+1] + shv[kt][2*jj+1];
        a0 = fmaxf(a0, 0.1f * a0);
        a1 = fmaxf(a1, 0.1f * a1);
        Bu[jj] = pkbf(a0, a1);
      }
#pragma unroll
      for (int mt = 0; mt < 4; mt++)
        C[mt][nt] = __builtin_amdgcn_mfma_f32_16x16x32_bf16(A[mt][kt], B, C[mt][nt], 0, 0, 0);
    }
  float sA[16], qA[16];
#pragma unroll
  for (int i = 0; i < 16; i++) { sA[i] = 0.f; qA[i] = 0.f; }
#pragma unroll
  for (int mt = 0; mt < 4; mt++)
#pragma unroll
    for (int nt = 0; nt < 2; nt++) {
      int p = p0 + nt * 16 + l15;
      int c0 = mt * 16 + quad * 4;
      uint2 o;
      o.x = pkbf(C[mt][nt][0], C[mt][nt][1]);
      o.y = pkbf(C[mt][nt][2], C[mt][nt][3]);
      *(uint2*)(g_x1b + ((size_t)p << 6) + c0) = o;
      float v0 = __uint_as_float(o.x << 16);
      float v1 = __uint_as_float(o.x & 0xFFFF0000u);
      float v2 = __uint_as_float(o.y << 16);
      float v3 = __uint_as_float(o.y & 0xFFFF0000u);
      int ib = mt * 4;
      sA[ib+0] += v0; qA[ib+0] = fmaf(v0, v0, qA[ib+0]);
      sA[ib+1] += v1; qA[ib+1] = fmaf(v1, v1, qA[ib+1]);
      sA[ib+2] += v2; qA[ib+2] = fmaf(v2, v2, qA[ib+2]);
      sA[ib+3] += v3; qA[ib+3] = fmaf(v3, v3, qA[ib+3]);
    }
  // fused BN1 stats, two-pass (S then Q) through 256x20 f32 scratch
  int rb = t * 20;
#pragma unroll
  for (int w = 0; w < 4; w++) {
    float4 vs; vs.x = sA[w*4+0]; vs.y = sA[w*4+1]; vs.z = sA[w*4+2]; vs.w = sA[w*4+3];
    *(float4*)&red[rb + w*4] = vs;
  }
  __syncthreads();
  float* sh = &g_p1s[blockIdx.x & 7][0];
  if (t < 64) {
    int qd = (t >> 2) & 3;
    int i = ((t >> 4) << 2) | (t & 3);
    float S = 0.f;
#pragma unroll
    for (int w = 0; w < 4; w++)
#pragma unroll
      for (int l = 0; l < 16; l++)
        S += red[(w * 64 + qd * 16 + l) * 20 + i];
    atomicAdd(sh + t, S);
  }
  __syncthreads();
#pragma unroll
  for (int w = 0; w < 4; w++) {
    float4 vq; vq.x = qA[w*4+0]; vq.y = qA[w*4+1]; vq.z = qA[w*4+2]; vq.w = qA[w*4+3];
    *(float4*)&red[rb + w*4] = vq;
  }
  __syncthreads();
  if (t < 64) {
    int qd = (t >> 2) & 3;
    int i = ((t >> 4) << 2) | (t & 3);
    float Q = 0.f;
#pragma unroll
    for (int w = 0; w < 4; w++)
#pragma unroll
      for (int l = 0; l < 16; l++)
        Q += red[(w * 64 + qd * 16 + l) * 20 + i];
    atomicAdd(sh + 64 + t, Q);
  }
}

// ---------------- layer2: BN1+leaky, MFMA M=128; fused k-max/min + BN2 stats (x2 never hits HBM) ----------------
__global__ __launch_bounds__(256) void k_l2(const float* __restrict__ g1,
                                            const float* __restrict__ b1) {
  __shared__ float scA[64], shA[64];
  __shared__ __attribute__((aligned(16))) float red[9216];   // 36 KB scratch (phase A: bf16 mx/mn; phase B: stats)
  int t = threadIdx.x;
  if (t < 64) {
    float ps = 0.f, pq = 0.f;
#pragma unroll
    for (int s = 0; s < 8; s++) { ps += g_p1s[s][t]; pq += g_p1s[s][64 + t]; }
    float m = ps / P_TOTF;
    float v = pq / P_TOTF - m * m;
    float sc = g1[t] / sqrtf(v + EPSV);
    scA[t] = sc; shA[t] = b1[t] - m * sc;
  }
  __syncthreads();
  int lane = t & 63, wv = t >> 6;
  int l15 = lane & 15, quad = lane >> 4;
  int chh = wv & 1;                      // channel half
  int p0 = blockIdx.x * 128 + (wv >> 1) * 64;
  float scv[2][8], shv[2][8];
#pragma unroll
  for (int kt = 0; kt < 2; kt++)
#pragma unroll
    for (int j = 0; j < 8; j++) {
      int c = kt * 32 + quad * 8 + j;
      scv[kt][j] = scA[c]; shv[kt][j] = shA[c];
    }
  bf16x8 A[4][2];
#pragma unroll
  for (int mt = 0; mt < 4; mt++)
#pragma unroll
    for (int kt = 0; kt < 2; kt++)
      A[mt][kt] = *(const bf16x8*)(g_Wb2 + ((((4 * chh + mt) * 2 + kt) * 64 + lane) << 3));
  f32x4 C[4][4];
#pragma unroll
  for (int mt = 0; mt < 4; mt++)
#pragma unroll
    for (int nt = 0; nt < 4; nt++) C[mt][nt] = 0.f;
#pragma unroll
  for (int kt = 0; kt < 2; kt++)
#pragma unroll
    for (int nt = 0; nt < 4; nt++) {
      const short* src = g_x1b + (((size_t)(p0 + nt * 16 + l15)) << 6) + kt * 32 + quad * 8;
      uint4 raw = *(const uint4*)src;
      bf16x8 B;
      unsigned* Bu = (unsigned*)&B;
      unsigned ru[4] = {raw.x, raw.y, raw.z, raw.w};
#pragma unroll
      for (int jj = 0; jj < 4; jj++) {
        float lo = __uint_as_float(ru[jj] << 16);
        float hi = __uint_as_float(ru[jj] & 0xFFFF0000u);
        float a0 = lo * scv[kt][2*jj]   + shv[kt][2*jj];
        float a1 = hi * scv[kt][2*jj+1] + shv[kt][2*jj+1];
        a0 = fmaxf(a0, 0.1f * a0);
        a1 = fmaxf(a1, 0.1f * a1);
        Bu[jj] = pkbf(a0, a1);
      }
#pragma unroll
      for (int mt = 0; mt < 4; mt++)
        C[mt][nt] = __builtin_amdgcn_mfma_f32_16x16x32_bf16(A[mt][kt], B, C[mt][nt], 0, 0, 0);
    }
  // per-lane: bf16-rounded values -> stats accum + per-s-subgroup partial max/min
  float sA[16], qA[16];
  float mxP[2][16], mnP[2][16];
#pragma unroll
  for (int i = 0; i < 16; i++) {
    sA[i] = 0.f; qA[i] = 0.f;
    mxP[0][i] = -3.4e38f; mnP[0][i] = 3.4e38f;
    mxP[1][i] = -3.4e38f; mnP[1][i] = 3.4e38f;
  }
#pragma unroll
  for (int mt = 0; mt < 4; mt++)
#pragma unroll
    for (int nt = 0; nt < 4; nt++) {
      unsigned ox = pkbf(C[mt][nt][0], C[mt][nt][1]);
      unsigned oy = pkbf(C[mt][nt][2], C[mt][nt][3]);
      float v0 = __uint_as_float(ox << 16);
      float v1 = __uint_as_float(ox & 0xFFFF0000u);
      float v2 = __uint_as_float(oy << 16);
      float v3 = __uint_as_float(oy & 0xFFFF0000u);
      int ib = mt * 4, sp = nt >> 1;
      sA[ib+0] += v0; qA[ib+0] = fmaf(v0, v0, qA[ib+0]);
      sA[ib+1] += v1; qA[ib+1] = fmaf(v1, v1, qA[ib+1]);
      sA[ib+2] += v2; qA[ib+2] = fmaf(v2, v2, qA[ib+2]);
      sA[ib+3] += v3; qA[ib+3] = fmaf(v3, v3, qA[ib+3]);
      mxP[sp][ib+0] = fmaxf(mxP[sp][ib+0], v0); mnP[sp][ib+0] = fminf(mnP[sp][ib+0], v0);
      mxP[sp][ib+1] = fmaxf(mxP[sp][ib+1], v1); mnP[sp][ib+1] = fminf(mnP[sp][ib+1], v1);
      mxP[sp][ib+2] = fmaxf(mxP[sp][ib+2], v2); mnP[sp][ib+2] = fminf(mnP[sp][ib+2], v2);
      mxP[sp][ib+3] = fmaxf(mxP[sp][ib+3], v3); mnP[sp][ib+3] = fminf(mnP[sp][ib+3], v3);
    }
  // phase A: bf16 partial max/min -> LDS [4 sg][16 l15][132 c], reduce over l15 -> g_mx/g_mn
  short* mxs = (short*)red;              // 4*16*132 shorts = 16896 B
  short* mns = mxs + 8448;               // second 16896 B (total 33792 <= 36864)
  int sgl0 = (wv >> 1) * 2;
#pragma unroll
  for (int sp = 0; sp < 2; sp++)
#pragma unroll
    for (int mt = 0; mt < 4; mt++) {
      int c0 = (4 * chh + mt) * 16 + quad * 4;
      int base = ((sgl0 + sp) * 16 + l15) * 132 + c0;
      short4 m4;
      m4.x = f2b(mxP[sp][mt*4+0]); m4.y = f2b(mxP[sp][mt*4+1]);
      m4.z = f2b(mxP[sp][mt*4+2]); m4.w = f2b(mxP[sp][mt*4+3]);
      *(short4*)&mxs[base] = m4;
      short4 n4;
      n4.x = f2b(mnP[sp][mt*4+0]); n4.y = f2b(mnP[sp][mt*4+1]);
      n4.z = f2b(mnP[sp][mt*4+2]); n4.w = f2b(mnP[sp][mt*4+3]);
      *(short4*)&mns[base] = n4;
    }
  __syncthreads();
  {
    int sg = t >> 6, c0 = (t & 63) * 2;   // each thread: 1 s-group, 2 channels
    float m0 = -3.4e38f, m1 = -3.4e38f, n0 = 3.4e38f, n1 = 3.4e38f;
#pragma unroll
    for (int l = 0; l < 16; l++) {
      unsigned ux = *(const unsigned*)&mxs[(sg * 16 + l) * 132 + c0];
      m0 = fmaxf(m0, __uint_as_float(ux << 16));
      m1 = fmaxf(m1, __uint_as_float(ux & 0xFFFF0000u));
      unsigned un = *(const unsigned*)&mns[(sg * 16 + l) * 132 + c0];
      n0 = fminf(n0, __uint_as_float(un << 16));
      n1 = fminf(n1, __uint_as_float(un & 0xFFFF0000u));
    }
    int sgg = blockIdx.x * 4 + sg;
    float2 vmx; vmx.x = m0; vmx.y = m1;
    float2 vmn; vmn.x = n0; vmn.y = n1;
    *(float2*)(g_mx + ((size_t)sgg << 7) + c0) = vmx;
    *(float2*)(g_mn + ((size_t)sgg << 7) + c0) = vmn;
  }
  __syncthreads();
  // phase B: BN2 stats (r12 pattern), 128 channels from 2 waves each
  int rb = t * 36;
#pragma unroll
  for (int w = 0; w < 4; w++) {
    float4 vs; vs.x = sA[w*4+0]; vs.y = sA[w*4+1]; vs.z = sA[w*4+2]; vs.w = sA[w*4+3];
    float4 vq; vq.x = qA[w*4+0]; vq.y = qA[w*4+1]; vq.z = qA[w*4+2]; vq.w = qA[w*4+3];
    *(float4*)&red[rb + w*4] = vs;
    *(float4*)&red[rb + 16 + w*4] = vq;
  }
  __syncthreads();
  if (t < 128) {
    int c = t;
    int ch2 = c >> 6, mt = (c >> 4) & 3, qd = (c >> 2) & 3, j = c & 3;
    int i = mt * 4 + j;
    float S = 0.f, Q = 0.f;
#pragma unroll
    for (int w = 0; w < 2; w++) {
      int wvv = ch2 + w * 2;
#pragma unroll
      for (int l = 0; l < 16; l++) {
        int row = (wvv * 64 + qd * 16 + l) * 36;
        S += red[row + i];
        Q += red[row + 16 + i];
      }
    }
    float* sh = &g_p2s[blockIdx.x & 7][0];
    atomicAdd(sh + c, S);
    atomicAdd(sh + 128 + c, Q);
  }
}

// ---------------- epilogue: BN2+leaky on precomputed max/min, coalesced r/w ----------------
__global__ __launch_bounds__(256) void k_epi(const float* __restrict__ g2,
                                             const float* __restrict__ b2,
                                             float* __restrict__ out) {
  __shared__ float scA[128], shA[128];
  __shared__ float res[16][132];
  int t = threadIdx.x;
  if (t < 128) {
    float ps = 0.f, pq = 0.f;
#pragma unroll
    for (int s = 0; s < 8; s++) { ps += g_p2s[s][t]; pq += g_p2s[s][128 + t]; }
    float m = ps / P_TOTF;
    float v = pq / P_TOTF - m * m;
    float sc = g2[t] / sqrtf(v + EPSV);
    scA[t] = sc; shA[t] = b2[t] - m * sc;
  }
  __syncthreads();
  int cp = t & 63, sl = t >> 6;        // channels 2cp,2cp+1 ; sl in 0..3
  int c0 = cp * 2, c1 = c0 + 1;
  float sc0 = scA[c0], sh0 = shA[c0];
  float sc1 = scA[c1], sh1 = shA[c1];
  int sg0 = blockIdx.x * 16;
  for (int it = 0; it < 4; it++) {
    int sgl = sl * 4 + it;             // 0..15, each once per block
    size_t off = ((size_t)(sg0 + sgl) << 7) + c0;
    float2 vmx = *(const float2*)(g_mx + off);
    float2 vmn = *(const float2*)(g_mn + off);
    float a0 = (sc0 >= 0.f ? vmx.x : vmn.x) * sc0 + sh0; a0 = fmaxf(a0, 0.1f * a0);
    float a1 = (sc1 >= 0.f ? vmx.y : vmn.y) * sc1 + sh1; a1 = fmaxf(a1, 0.1f * a1);
    res[sgl][c0] = a0; res[sgl][c1] = a1;
  }
  __syncthreads();
  int b = sg0 >> 12, s0 = sg0 & 4095;   // block never straddles b (4096 % 16 == 0)
#pragma unroll
  for (int w = 0; w < 2; w++) {
    int fidx = t * 2 + w;               // 0..511
    int c = fidx >> 2, qi = fidx & 3;
    float4 o;
    o.x = res[qi * 4 + 0][c];
    o.y = res[qi * 4 + 1][c];
    o.z = res[qi * 4 + 2][c];
    o.w = res[qi * 4 + 3][c];
    *(float4*)(out + 24576 + (((size_t)(b * 128 + c)) << 12) + s0 + qi * 4) = o;
  }
}

extern "C" void kernel_launch(void* const* d_in, const int* in_sizes, int n_in,
                              void* d_out, int out_size, void* d_ws, size_t ws_size,
                              hipStream_t stream) {
  (void)in_sizes; (void)n_in; (void)out_size; (void)d_ws; (void)ws_size;
  const float* xyz    = (const float*)d_in[0];
  const float* points = (const float*)d_in[1];
  const float* W0     = (const float*)d_in[2];
  const float* W1     = (const float*)d_in[3];
  const float* W2     = (const float*)d_in[4];
  const float* g0     = (const float*)d_in[5];
  const float* b0     = (const float*)d_in[6];
  const float* g1     = (const float*)d_in[7];
  const float* b1     = (const float*)d_in[8];
  const float* g2     = (const float*)d_in[9];
  const float* b2     = (const float*)d_in[10];
  float* out = (float*)d_out;

  hipLaunchKernelGGL(k_setup, dim3(641),  dim3(256), 0, stream, xyz, points, W0, W1, W2, out);
  hipLaunchKernelGGL(k_knn,   dim3(2048), dim3(256), 0, stream);
  hipLaunchKernelGGL(k_l0,    dim3(2048), dim3(256), 0, stream);
  hipLaunchKernelGGL(k_l1,    dim3(2048), dim3(256), 0, stream, g0, b0);
  hipLaunchKernelGGL(k_l2,    dim3(2048), dim3(256), 0, stream, g1, b1);
  hipLaunchKernelGGL(k_epi,   dim3(512),  dim3(256), 0, stream, g2, b2, out);
}

// Round 16
// 259.633 us; speedup vs baseline: 1.2025x; 1.0902x over previous
//
#include <hip/hip_runtime.h>
#include <hip/hip_bf16.h>
#include <stdint.h>

#define N_ALL   16384
#define NPOINT  4096
#define KNN_K   32
#define BATCH   2
#define P_TOT   (BATCH*NPOINT*KNN_K)   /* 262144 */
#define P_TOTF  262144.0f
#define EPSV    1e-5f

typedef __attribute__((ext_vector_type(8))) short bf16x8;
typedef __attribute__((ext_vector_type(4))) float f32x4;

// ---- all scratch in module-static device memory; d_ws untouched ----
__device__ unsigned short g_knn[P_TOT];                                   // 512 KB
__device__ __attribute__((aligned(16))) float g_pxyzn[BATCH*N_ALL*4];     // 512 KB (x,y,z,|x|^2)
__device__ __attribute__((aligned(16))) short g_ptb[BATCH*N_ALL*64];      // 4 MB  [b,n][64c] bf16
__device__ __attribute__((aligned(16))) short g_x0b[(size_t)P_TOT*64];    // 32 MB [p][64] bf16
__device__ __attribute__((aligned(16))) short g_x1b[(size_t)P_TOT*64];    // 32 MB
__device__ __attribute__((aligned(16))) float g_mx[(size_t)BATCH*NPOINT*128];  // 4 MB
__device__ __attribute__((aligned(16))) float g_mn[(size_t)BATCH*NPOINT*128];  // 4 MB
__device__ __attribute__((aligned(16))) short g_Wb0[4*3*64*8];            // swizzled A-frags
__device__ __attribute__((aligned(16))) short g_Wb1[4*2*64*8];
__device__ __attribute__((aligned(16))) short g_Wb2[8*2*64*8];
__device__ float g_p0s[8][128];      // BN0 stats shadows (2048 blocks / 8 = 256/addr)
__device__ float g_p1s[8][128];      // BN1 stats shadows (2048 blocks / 8 = 256/addr)
__device__ float g_p2s[8][256];      // BN2 stats shadows (2048 blocks / 8 = 256/addr)

__device__ __forceinline__ float b2f(short s) {
  union { unsigned u; float f; } v; v.u = ((unsigned)(unsigned short)s) << 16; return v.f;
}
__device__ __forceinline__ short f2b(float f) {
  union { float f; unsigned u; } v; v.f = f;
  unsigned u = v.u;
  u += 0x7FFFu + ((u >> 16) & 1u);
  return (short)(u >> 16);
}
// packed f32x2 -> bf16x2 (v_cvt_pk_bf16_f32, RNE — bit-identical to f2b pairs)
__device__ __forceinline__ unsigned pkbf(float a, float b) {
  union { __hip_bfloat162 h; unsigned u; } v;
  v.h = __float22bfloat162_rn(make_float2(a, b));
  return v.u;
}
__device__ __forceinline__ unsigned long long bperm64(unsigned long long v, int byteaddr) {
  int lo = __builtin_amdgcn_ds_bpermute(byteaddr, (int)(unsigned)(v & 0xFFFFFFFFULL));
  int hi = __builtin_amdgcn_ds_bpermute(byteaddr, (int)(unsigned)(v >> 32));
  return (((unsigned long long)(unsigned)hi) << 32) | (unsigned)lo;
}
__device__ __forceinline__ unsigned long long u64min(unsigned long long a, unsigned long long b) {
  return a < b ? a : b;
}
// bitonic compare-exchange step: keep min (mx=0) or max (mx=1) of (v, pv)
__device__ __forceinline__ unsigned long long selstage(unsigned long long v,
                                                       unsigned long long pv, bool mx) {
  bool lt = v < pv;
  return (lt != mx) ? v : pv;
}

// sort 32 buffered candidates (vB, one per lane within a 32-lane half) ascending,
// merge lowest-32 of (vL ∪ vB) back into vL (sorted), refresh worst_hi/wd.
__device__ __forceinline__ void knn_merge32(unsigned long long& vL,
                                            unsigned long long& worst,
                                            unsigned& worst_hi, float& wd,
                                            unsigned long long vB, int hl,
                                            int aX1, int aX2, int aX4, int aX8,
                                            int aX16, int aRev, int aW) {
  vB = selstage(vB, bperm64(vB, aX1),  ((hl & 1) != 0) != ((hl & 2) != 0));
  vB = selstage(vB, bperm64(vB, aX2),  ((hl & 2) != 0) != ((hl & 4) != 0));
  vB = selstage(vB, bperm64(vB, aX1),  ((hl & 1) != 0) != ((hl & 4) != 0));
  vB = selstage(vB, bperm64(vB, aX4),  ((hl & 4) != 0) != ((hl & 8) != 0));
  vB = selstage(vB, bperm64(vB, aX2),  ((hl & 2) != 0) != ((hl & 8) != 0));
  vB = selstage(vB, bperm64(vB, aX1),  ((hl & 1) != 0) != ((hl & 8) != 0));
  vB = selstage(vB, bperm64(vB, aX8),  ((hl & 8) != 0) != ((hl & 16) != 0));
  vB = selstage(vB, bperm64(vB, aX4),  ((hl & 4) != 0) != ((hl & 16) != 0));
  vB = selstage(vB, bperm64(vB, aX2),  ((hl & 2) != 0) != ((hl & 16) != 0));
  vB = selstage(vB, bperm64(vB, aX1),  ((hl & 1) != 0) != ((hl & 16) != 0));
  vB = selstage(vB, bperm64(vB, aX16), (hl & 16) != 0);
  vB = selstage(vB, bperm64(vB, aX8),  (hl & 8) != 0);
  vB = selstage(vB, bperm64(vB, aX4),  (hl & 4) != 0);
  vB = selstage(vB, bperm64(vB, aX2),  (hl & 2) != 0);
  vB = selstage(vB, bperm64(vB, aX1),  (hl & 1) != 0);
  // vL asc, vB asc: pair lane i with reversed buffer -> lowest 32 (bitonic), then cleanup
  vL = u64min(vL, bperm64(vB, aRev));
  vL = selstage(vL, bperm64(vL, aX16), (hl & 16) != 0);
  vL = selstage(vL, bperm64(vL, aX8),  (hl & 8) != 0);
  vL = selstage(vL, bperm64(vL, aX4),  (hl & 4) != 0);
  vL = selstage(vL, bperm64(vL, aX2),  (hl & 2) != 0);
  vL = selstage(vL, bperm64(vL, aX1),  (hl & 1) != 0);
  worst = bperm64(vL, aW);
  worst_hi = (unsigned)(worst >> 32);
  unsigned wh = worst_hi;
  unsigned ub = (wh & 0x80000000u) ? (wh ^ 0x80000000u) : ~wh;
  wd = (wh == 0xFFFFFFFFu) ? __builtin_inff() : __uint_as_float(ub);
}

// ---------------- pre: pxyzn pack + out xyz-copy (the only knn dependencies) ----------------
__global__ __launch_bounds__(256) void k_pre(const float* __restrict__ xyz,
                                             float* __restrict__ out) {
#pragma clang fp contract(off)
  int i = blockIdx.x * 256 + threadIdx.x;   // < 32768
  if (i < 24576) {
    int s = i & 4095;
    int c = (i >> 12) % 3;
    int b = i / 12288;
    out[i] = xyz[(b * 3 + c) * N_ALL + s];
  }
  int b = i >> 14, n = i & 16383;
  const float* xb = xyz + b * 3 * N_ALL;
  float x = xb[n], y = xb[N_ALL + n], z = xb[2 * N_ALL + n];
  float4 p; p.x = x; p.y = y; p.z = z; p.w = x * x + y * y + z * z;
  ((float4*)g_pxyzn)[i] = p;
}

// ---------------- knn+setup: blocks 0-511 tpose | 512 wprep | 513+ knn ----------------
__global__ __launch_bounds__(256, 8) void k_knn(const float* __restrict__ points,
                                                const float* __restrict__ W0,
                                                const float* __restrict__ W1,
                                                const float* __restrict__ W2) {
#pragma clang fp contract(off)
  __shared__ __attribute__((aligned(16))) char smem[64 * 65 * 4];   // 16.6 KB arena
  int blk = blockIdx.x;
  int t = threadIdx.x;
  if (blk < 512) {
    // ------- transpose points -> g_ptb (bf16 [b,n][64c]) -------
    float (*tile)[65] = (float(*)[65])smem;
    int b  = blk >> 8;
    int n0 = (blk & 255) << 6;
#pragma unroll
    for (int r = 0; r < 16; r++) {
      int lin = r * 256 + t;
      int c = lin >> 6, nn = lin & 63;
      tile[c][nn] = points[((size_t)(b * 64 + c)) * N_ALL + n0 + nn];
    }
    __syncthreads();
#pragma unroll
    for (int r = 0; r < 16; r++) {
      int lin = r * 256 + t;
      int nn = lin >> 6, c = lin & 63;
      g_ptb[((size_t)(b * N_ALL + n0 + nn)) * 64 + c] = f2b(tile[c][nn]);
    }
    return;
  }
  if (blk == 512) {
    // ------- W-prep + stats-shadow zeroing -------
    for (int i = t; i < 4 * 3 * 64 * 8; i += 256) {
      int j = i & 7, lane = (i >> 3) & 63, rest = i >> 9;
      int kt = rest % 3, mt = rest / 3;
      int m = 16 * mt + (lane & 15);
      int k = 32 * kt + (lane >> 4) * 8 + j;
      float v = 0.f;
      if (k < 64) v = W0[m * 67 + 3 + k];
      else if (k < 67) v = W0[m * 67 + (k - 64)];
      g_Wb0[i] = f2b(v);
    }
    for (int i = t; i < 4 * 2 * 64 * 8; i += 256) {
      int j = i & 7, lane = (i >> 3) & 63;
      int kt = (i >> 9) & 1, mt = i >> 10;
      int m = 16 * mt + (lane & 15);
      int k = 32 * kt + (lane >> 4) * 8 + j;
      g_Wb1[i] = f2b(W1[m * 64 + k]);
    }
    for (int i = t; i < 8 * 2 * 64 * 8; i += 256) {
      int j = i & 7, lane = (i >> 3) & 63;
      int kt = (i >> 9) & 1, mt = i >> 10;
      int m = 16 * mt + (lane & 15);
      int k = 32 * kt + (lane >> 4) * 8 + j;
      g_Wb2[i] = f2b(W2[m * 64 + k]);
    }
    float* z0 = &g_p0s[0][0];
    float* z1 = &g_p1s[0][0];
    float* z2 = &g_p2s[0][0];
    for (int i = t; i < 1024; i += 256) { z0[i] = 0.f; z1[i] = 0.f; }
    for (int i = t; i < 2048; i += 256) z2[i] = 0.f;
    return;
  }
  // ------- KNN: split-N 2-way, 2 queries/wave, float gate + survivor-only keys -------
  int kb = blk - 513;                // 0..2047
  int wv = t >> 6;
  int lane = t & 63;
  int half = lane >> 5;            // 0: lanes 0..31 (query A), 1: lanes 32..63 (query B)
  int hl = lane & 31;
  int lanebase = lane & 32;
  unsigned long long* bufh = (unsigned long long*)smem + (wv * 2 + half) * 64;

  int qpair = wv >> 1;             // waves {0,1} share queries, {2,3} share queries
  int range = wv & 1;              // 0: points [0,8192), 1: [8192,16384)
  int q = kb * 4 + qpair * 2 + half;   // 0..8191
  int b = q >> 12, s = q & 4095;
  const float4* pb = (const float4*)g_pxyzn + (b << 14);
  float4 qp = pb[s];
  float qx = qp.x, qy = qp.y, qz = qp.z, qn = qp.w;

  // hoisted cross-lane byte addresses (stay within own 32-lane half)
  int aX1  = (lanebase | (hl ^ 1))  << 2;
  int aX2  = (lanebase | (hl ^ 2))  << 2;
  int aX4  = (lanebase | (hl ^ 4))  << 2;
  int aX8  = (lanebase | (hl ^ 8))  << 2;
  int aX16 = (lanebase | (hl ^ 16)) << 2;
  int aRev = (lanebase | (31 - hl)) << 2;
  int aW   = (lanebase | 31)        << 2;

  unsigned long long vL = ~0ULL;      // per-half sorted top-32 (ascending by lane)
  unsigned long long worst = ~0ULL;   // per-lane copy of own half's vL[31]
  unsigned worst_hi = 0xFFFFFFFFu;
  float wd = __builtin_inff();        // worst distance as float (conservative gate)
  int F = 0;                          // buffered-candidate count (uniform within half)

  int base = range << 13;
  for (int n0 = base; n0 < base + 8192; n0 += 128) {
    float4 p0 = pb[n0 + hl];
    float4 p1 = pb[n0 + 32 + hl];
    float4 p2 = pb[n0 + 64 + hl];
    float4 p3 = pb[n0 + 96 + hl];
    float d[4];
    {
      float dt0 = (qx * p0.x + qy * p0.y) + qz * p0.z;   // contract off: exact ref order
      float dt1 = (qx * p1.x + qy * p1.y) + qz * p1.z;
      float dt2 = (qx * p2.x + qy * p2.y) + qz * p2.z;
      float dt3 = (qx * p3.x + qy * p3.y) + qz * p3.z;
      d[0] = __builtin_fmaf(-2.0f, dt0, qn + p0.w);      // == (qn+pn) - 2*dt exactly
      d[1] = __builtin_fmaf(-2.0f, dt1, qn + p1.w);
      d[2] = __builtin_fmaf(-2.0f, dt2, qn + p2.w);
      d[3] = __builtin_fmaf(-2.0f, dt3, qn + p3.w);
    }
    float md = fminf(fminf(d[0], d[1]), fminf(d[2], d[3]));
    if (__ballot(md <= wd)) {
#pragma unroll
      for (int u4 = 0; u4 < 4; u4++) {
        bool sv = d[u4] <= wd;          // float gate: conservative superset of exact u64 test
        unsigned long long bl = __ballot(sv);
        unsigned mb = half ? (unsigned)(bl >> 32) : (unsigned)bl;
        if (sv) {                       // survivors only: build exact u64 key (masked, no branch)
          unsigned u = __float_as_uint(d[u4]);
          u ^= ((unsigned)(((int)u) >> 31)) | 0x80000000u;   // order-preserving map
          unsigned long long c = (((unsigned long long)u) << 32)
                               | (unsigned)(n0 + 32 * u4 + hl);
          bufh[F + __popc(mb & ((1u << hl) - 1u))] = c;
        }
        F += __popc(mb);
        if (__ballot(F >= 32)) {          // coherent: both halves merge together
          int take = F >= 32 ? 32 : F;    // partner half consumes its partial buffer
          unsigned long long vB = (hl < take) ? bufh[hl] : ~0ULL;
          knn_merge32(vL, worst, worst_hi, wd, vB, hl,
                      aX1, aX2, aX4, aX8, aX16, aRev, aW);
          int R = F - take;               // 0..31
          if (hl < R) bufh[hl] = bufh[32 + hl];   // reads 32..62, writes 0..30: disjoint
          F = R;
        }
      }
    }
  }
  if (__ballot(F > 0)) {   // flush remaining (<32) with +inf padding
    unsigned long long vB = (hl < F) ? bufh[hl] : ~0ULL;
    knn_merge32(vL, worst, worst_hi, wd, vB, hl, aX1, aX2, aX4, aX8, aX16, aRev, aW);
  }

  // cross-wave combine: waves (2k, 2k+1) hold lo/hi top-32 for the same queries
  bufh[hl] = vL;
  __syncthreads();
  unsigned long long vB = *((unsigned long long*)smem + ((wv ^ 1) * 2 + half) * 64 + hl);
  vL = u64min(vL, bperm64(vB, aRev));            // both sorted asc: reverse-pair min
  vL = selstage(vL, bperm64(vL, aX16), (hl & 16) != 0);
  vL = selstage(vL, bperm64(vL, aX8),  (hl & 8) != 0);
  vL = selstage(vL, bperm64(vL, aX4),  (hl & 4) != 0);
  vL = selstage(vL, bperm64(vL, aX2),  (hl & 2) != 0);
  vL = selstage(vL, bperm64(vL, aX1),  (hl & 1) != 0);
  if (range == 0)
    g_knn[((size_t)q << 5) | hl] = (unsigned short)(vL & 0xFFFF);
}

// ---------------- layer0: 128 pts/block (26.6 KB LDS, 6 blk/CU), pxyzn diffs, fused BN0 stats ----------------
__global__ __launch_bounds__(256) void k_l0() {
  __shared__ __attribute__((aligned(16))) short feats[128][104];   // 26.6 KB; reused as 20.5 KB f32 scratch
  int t = threadIdx.x;
  int p0 = blockIdx.x * 128;
  {
    int pt = t >> 1, h = t & 1;       // 2 threads per point
    int p = p0 + pt;
    int idx = g_knn[p];
    int s = (p >> 5) & 4095;
    int b = p >> 17;
    const short* src = g_ptb + ((size_t)((b << 14) + idx) << 6) + h * 32;
#pragma unroll
    for (int i = 0; i < 4; i++)
      ((int4*)&feats[pt][h * 32])[i] = ((const int4*)src)[i];
    if (h == 0) {
      const float4* pb4 = (const float4*)g_pxyzn + (b << 14);
      float4 a = pb4[idx], q = pb4[s];      // exact copies of xyz -> bit-identical diffs
      short4 d3;
      d3.x = f2b(a.x - q.x);
      d3.y = f2b(a.y - q.y);
      d3.z = f2b(a.z - q.z);
      d3.w = 0;
      *(short4*)&feats[pt][64] = d3;
      short4 z4; z4.x = 0; z4.y = 0; z4.z = 0; z4.w = 0;
      *(short4*)&feats[pt][68] = z4;
    } else {
      int4 z; z.x = 0; z.y = 0; z.z = 0; z.w = 0;
      *(int4*)&feats[pt][72] = z;
      *(int4*)&feats[pt][80] = z;
      *(int4*)&feats[pt][88] = z;
    }
  }
  __syncthreads();
  int lane = t & 63, wv = t >> 6;
  int l15 = lane & 15, quad = lane >> 4;
  bf16x8 A[4][3];
#pragma unroll
  for (int mt = 0; mt < 4; mt++)
#pragma unroll
    for (int kt = 0; kt < 3; kt++)
      A[mt][kt] = *(const bf16x8*)(g_Wb0 + (((mt * 3 + kt) * 64 + lane) << 3));
  f32x4 C[4][2];
#pragma unroll
  for (int mt = 0; mt < 4; mt++)
#pragma unroll
    for (int nt = 0; nt < 2; nt++) C[mt][nt] = 0.f;
#pragma unroll
  for (int kt = 0; kt < 3; kt++)
#pragma unroll
    for (int nt = 0; nt < 2; nt++) {
      bf16x8 B = *(const bf16x8*)(&feats[wv * 32 + nt * 16 + l15][kt * 32 + quad * 8]);
#pragma unroll
      for (int mt = 0; mt < 4; mt++)
        C[mt][nt] = __builtin_amdgcn_mfma_f32_16x16x32_bf16(A[mt][kt], B, C[mt][nt], 0, 0, 0);
    }
  float sA[16], qA[16];
#pragma unroll
  for (int i = 0; i < 16; i++) { sA[i] = 0.f; qA[i] = 0.f; }
#pragma unroll
  for (int mt = 0; mt < 4; mt++)
#pragma unroll
    for (int nt = 0; nt < 2; nt++) {
      int p = p0 + wv * 32 + nt * 16 + l15;
      int c0 = mt * 16 + quad * 4;
      uint2 o;
      o.x = pkbf(C[mt][nt][0], C[mt][nt][1]);
      o.y = pkbf(C[mt][nt][2], C[mt][nt][3]);
      *(uint2*)(g_x0b + ((size_t)p << 6) + c0) = o;
      float v0 = __uint_as_float(o.x << 16);
      float v1 = __uint_as_float(o.x & 0xFFFF0000u);
      float v2 = __uint_as_float(o.y << 16);
      float v3 = __uint_as_float(o.y & 0xFFFF0000u);
      int ib = mt * 4;
      sA[ib+0] += v0; qA[ib+0] = fmaf(v0, v0, qA[ib+0]);
      sA[ib+1] += v1; qA[ib+1] = fmaf(v1, v1, qA[ib+1]);
      sA[ib+2] += v2; qA[ib+2] = fmaf(v2, v2, qA[ib+2]);
      sA[ib+3] += v3; qA[ib+3] = fmaf(v3, v3, qA[ib+3]);
    }
  // fused BN0 stats, two-pass (S then Q) through 256x20 f32 scratch (20.5 KB)
  __syncthreads();                       // all waves done reading feats
  float* red = (float*)&feats[0][0];
  int rb = t * 20;
#pragma unroll
  for (int w = 0; w < 4; w++) {
    float4 vs; vs.x = sA[w*4+0]; vs.y = sA[w*4+1]; vs.z = sA[w*4+2]; vs.w = sA[w*4+3];
    *(float4*)&red[rb + w*4] = vs;
  }
  __syncthreads();
  float* sh = &g_p0s[blockIdx.x & 7][0];
  if (t < 64) {
    int qd = (t >> 2) & 3;               // quad of channel t
    int i = ((t >> 4) << 2) | (t & 3);   // register index mt*4+j
    float S = 0.f;
#pragma unroll
    for (int w = 0; w < 4; w++)
#pragma unroll
      for (int l = 0; l < 16; l++)
        S += red[(w * 64 + qd * 16 + l) * 20 + i];
    atomicAdd(sh + t, S);
  }
  __syncthreads();
#pragma unroll
  for (int w = 0; w < 4; w++) {
    float4 vq; vq.x = qA[w*4+0]; vq.y = qA[w*4+1]; vq.z = qA[w*4+2]; vq.w = qA[w*4+3];
    *(float4*)&red[rb + w*4] = vq;
  }
  __syncthreads();
  if (t < 64) {
    int qd = (t >> 2) & 3;
    int i = ((t >> 4) << 2) | (t & 3);
    float Q = 0.f;
#pragma unroll
    for (int w = 0; w < 4; w++)
#pragma unroll
      for (int l = 0; l < 16; l++)
        Q += red[(w * 64 + qd * 16 + l) * 20 + i];
    atomicAdd(sh + 64 + t, Q);
  }
}

// ---------------- layer1: 128 pts/block, C[4][2] (VGPR diet), fused BN1 stats ----------------
__global__ __launch_bounds__(256) void k_l1(const float* __restrict__ g0,
                                            const float* __restrict__ b0) {
  __shared__ float scA[64], shA[64];
  __shared__ __attribute__((aligned(16))) float red[256 * 20];   // 20.5 KB stats scratch
  int t = threadIdx.x;
  if (t < 64) {
    float ps = 0.f, pq = 0.f;
#pragma unroll
    for (int s = 0; s < 8; s++) { ps += g_p0s[s][t]; pq += g_p0s[s][64 + t]; }
    float m = ps / P_TOTF;
    float v = pq / P_TOTF - m * m;
    float sc = g0[t] / sqrtf(v + EPSV);
    scA[t] = sc; shA[t] = b0[t] - m * sc;
  }
  __syncthreads();
  int lane = t & 63, wv = t >> 6;
  int l15 = lane & 15, quad = lane >> 4;
  int p0 = blockIdx.x * 128 + wv * 32;
  float scv[2][8], shv[2][8];
#pragma unroll
  for (int kt = 0; kt < 2; kt++)
#pragma unroll
    for (int j = 0; j < 8; j++) {
      int c = kt * 32 + quad * 8 + j;
      scv[kt][j] = scA[c]; shv[kt][j] = shA[c];
    }
  bf16x8 A[4][2];
#pragma unroll
  for (int mt = 0; mt < 4; mt++)
#pragma unroll
    for (int kt = 0; kt < 2; kt++)
      A[mt][kt] = *(const bf16x8*)(g_Wb1 + (((mt * 2 + kt) * 64 + lane) << 3));
  f32x4 C[4][2];
#pragma unroll
  for (int mt = 0; mt < 4; mt++)
#pragma unroll
    for (int nt = 0; nt < 2; nt++) C[mt][nt] = 0.f;
#pragma unroll
  for (int kt = 0; kt < 2; kt++)
#pragma unroll
    for (int nt = 0; nt < 2; nt++) {
      const short* src = g_x0b + (((size_t)(p0 + nt * 16 + l15)) << 6) + kt * 32 + quad * 8;
      uint4 raw = *(const uint4*)src;
      bf16x8 B;
      unsigned* Bu = (unsigned*)&B;
      unsigned ru[4] = {raw.x, raw.y, raw.z, raw.w};
#pragma unroll
      for (int jj = 0; jj < 4; jj++) {
        float lo = __uint_as_float(ru[jj] << 16);
        float hi = __uint_as_float(ru[jj] & 0xFFFF0000u);
        float a0 = lo * scv[kt][2*jj]   + shv[kt][2*jj];
        float a1 = hi * scv[kt][2*jj+1] + shv[kt][2*jj+1];
        a0 = fmaxf(a0, 0.1f * a0);
        a1 = fmaxf(a1, 0.1f * a1);
        Bu[jj] = pkbf(a0, a1);
      }
#pragma unroll
      for (int mt = 0; mt < 4; mt++)
        C[mt][nt] = __builtin_amdgcn_mfma_f32_16x16x32_bf16(A[mt][kt], B, C[mt][nt], 0, 0, 0);
    }
  float sA[16], qA[16];
#pragma unroll
  for (int i = 0; i < 16; i++) { sA[i] = 0.f; qA[i] = 0.f; }
#pragma unroll
  for (int mt = 0; mt < 4; mt++)
#pragma unroll
    for (int nt = 0; nt < 2; nt++) {
      int p = p0 + nt * 16 + l15;
      int c0 = mt * 16 + quad * 4;
      uint2 o;
      o.x = pkbf(C[mt][nt][0], C[mt][nt][1]);
      o.y = pkbf(C[mt][nt][2], C[mt][nt][3]);
      *(uint2*)(g_x1b + ((size_t)p << 6) + c0) = o;
      float v0 = __uint_as_float(o.x << 16);
      float v1 = __uint_as_float(o.x & 0xFFFF0000u);
      float v2 = __uint_as_float(o.y << 16);
      float v3 = __uint_as_float(o.y & 0xFFFF0000u);
      int ib = mt * 4;
      sA[ib+0] += v0; qA[ib+0] = fmaf(v0, v0, qA[ib+0]);
      sA[ib+1] += v1; qA[ib+1] = fmaf(v1, v1, qA[ib+1]);
      sA[ib+2] += v2; qA[ib+2] = fmaf(v2, v2, qA[ib+2]);
      sA[ib+3] += v3; qA[ib+3] = fmaf(v3, v3, qA[ib+3]);
    }
  // fused BN1 stats, two-pass (S then Q) through 256x20 f32 scratch
  int rb = t * 20;
#pragma unroll
  for (int w = 0; w < 4; w++) {
    float4 vs; vs.x = sA[w*4+0]; vs.y = sA[w*4+1]; vs.z = sA[w*4+2]; vs.w = sA[w*4+3];
    *(float4*)&red[rb + w*4] = vs;
  }
  __syncthreads();
  float* sh = &g_p1s[blockIdx.x & 7][0];
  if (t < 64) {
    int qd = (t >> 2) & 3;
    int i = ((t >> 4) << 2) | (t & 3);
    float S = 0.f;
#pragma unroll
    for (int w = 0; w < 4; w++)
#pragma unroll
      for (int l = 0; l < 16; l++)
        S += red[(w * 64 + qd * 16 + l) * 20 + i];
    atomicAdd(sh + t, S);
  }
  __syncthreads();
#pragma unroll
  for (int w = 0; w < 4; w++) {
    float4 vq; vq.x = qA[w*4+0]; vq.y = qA[w*4+1]; vq.z = qA[w*4+2]; vq.w = qA[w*4+3];
    *(float4*)&red[rb + w*4] = vq;
  }
  __syncthreads();
  if (t < 64) {
    int qd = (t >> 2) & 3;
    int i = ((t >> 4) << 2) | (t & 3);
    float Q = 0.f;
#pragma unroll
    for (int w = 0; w < 4; w++)
#pragma unroll
      for (int l = 0; l < 16; l++)
        Q += red[(w * 64 + qd * 16 + l) * 20 + i];
    atomicAdd(sh + 64 + t, Q);
  }
}

// ---------------- layer2: BN1+leaky, MFMA M=128; fused k-max/min + BN2 stats (x2 never hits HBM) ----------------
__global__ __launch_bounds__(256) void k_l2(const float* __restrict__ g1,
                                            const float* __restrict__ b1) {
  __shared__ float scA[64], shA[64];
  __shared__ __attribute__((aligned(16))) float red[9216];   // 36 KB scratch (phase A: bf16 mx/mn; phase B: stats)
  int t = threadIdx.x;
  if (t < 64) {
    float ps = 0.f, pq = 0.f;
#pragma unroll
    for (int s = 0; s < 8; s++) { ps += g_p1s[s][t]; pq += g_p1s[s][64 + t]; }
    float m = ps / P_TOTF;
    float v = pq / P_TOTF - m * m;
    float sc = g1[t] / sqrtf(v + EPSV);
    scA[t] = sc; shA[t] = b1[t] - m * sc;
  }
  __syncthreads();
  int lane = t & 63, wv = t >> 6;
  int l15 = lane & 15, quad = lane >> 4;
  int chh = wv & 1;                      // channel half
  int p0 = blockIdx.x * 128 + (wv >> 1) * 64;
  float scv[2][8], shv[2][8];
#pragma unroll
  for (int kt = 0; kt < 2; kt++)
#pragma unroll
    for (int j = 0; j < 8; j++) {
      int c = kt * 32 + quad * 8 + j;
      scv[kt][j] = scA[c]; shv[kt][j] = shA[c];
    }
  bf16x8 A[4][2];
#pragma unroll
  for (int mt = 0; mt < 4; mt++)
#pragma unroll
    for (int kt = 0; kt < 2; kt++)
      A[mt][kt] = *(const bf16x8*)(g_Wb2 + ((((4 * chh + mt) * 2 + kt) * 64 + lane) << 3));
  f32x4 C[4][4];
#pragma unroll
  for (int mt = 0; mt < 4; mt++)
#pragma unroll
    for (int nt = 0; nt < 4; nt++) C[mt][nt] = 0.f;
#pragma unroll
  for (int kt = 0; kt < 2; kt++)
#pragma unroll
    for (int nt = 0; nt < 4; nt++) {
      const short* src = g_x1b + (((size_t)(p0 + nt * 16 + l15)) << 6) + kt * 32 + quad * 8;
      uint4 raw = *(const uint4*)src;
      bf16x8 B;
      unsigned* Bu = (unsigned*)&B;
      unsigned ru[4] = {raw.x, raw.y, raw.z, raw.w};
#pragma unroll
      for (int jj = 0; jj < 4; jj++) {
        float lo = __uint_as_float(ru[jj] << 16);
        float hi = __uint_as_float(ru[jj] & 0xFFFF0000u);
        float a0 = lo * scv[kt][2*jj]   + shv[kt][2*jj];
        float a1 = hi * scv[kt][2*jj+1] + shv[kt][2*jj+1];
        a0 = fmaxf(a0, 0.1f * a0);
        a1 = fmaxf(a1, 0.1f * a1);
        Bu[jj] = pkbf(a0, a1);
      }
#pragma unroll
      for (int mt = 0; mt < 4; mt++)
        C[mt][nt] = __builtin_amdgcn_mfma_f32_16x16x32_bf16(A[mt][kt], B, C[mt][nt], 0, 0, 0);
    }
  // per-lane: bf16-rounded values -> stats accum + per-s-subgroup partial max/min
  float sA[16], qA[16];
  float mxP[2][16], mnP[2][16];
#pragma unroll
  for (int i = 0; i < 16; i++) {
    sA[i] = 0.f; qA[i] = 0.f;
    mxP[0][i] = -3.4e38f; mnP[0][i] = 3.4e38f;
    mxP[1][i] = -3.4e38f; mnP[1][i] = 3.4e38f;
  }
#pragma unroll
  for (int mt = 0; mt < 4; mt++)
#pragma unroll
    for (int nt = 0; nt < 4; nt++) {
      unsigned ox = pkbf(C[mt][nt][0], C[mt][nt][1]);
      unsigned oy = pkbf(C[mt][nt][2], C[mt][nt][3]);
      float v0 = __uint_as_float(ox << 16);
      float v1 = __uint_as_float(ox & 0xFFFF0000u);
      float v2 = __uint_as_float(oy << 16);
      float v3 = __uint_as_float(oy & 0xFFFF0000u);
      int ib = mt * 4, sp = nt >> 1;
      sA[ib+0] += v0; qA[ib+0] = fmaf(v0, v0, qA[ib+0]);
      sA[ib+1] += v1; qA[ib+1] = fmaf(v1, v1, qA[ib+1]);
      sA[ib+2] += v2; qA[ib+2] = fmaf(v2, v2, qA[ib+2]);
      sA[ib+3] += v3; qA[ib+3] = fmaf(v3, v3, qA[ib+3]);
      mxP[sp][ib+0] = fmaxf(mxP[sp][ib+0], v0); mnP[sp][ib+0] = fminf(mnP[sp][ib+0], v0);
      mxP[sp][ib+1] = fmaxf(mxP[sp][ib+1], v1); mnP[sp][ib+1] = fminf(mnP[sp][ib+1], v1);
      mxP[sp][ib+2] = fmaxf(mxP[sp][ib+2], v2); mnP[sp][ib+2] = fminf(mnP[sp][ib+2], v2);
      mxP[sp][ib+3] = fmaxf(mxP[sp][ib+3], v3); mnP[sp][ib+3] = fminf(mnP[sp][ib+3], v3);
    }
  // phase A: bf16 partial max/min -> LDS [4 sg][16 l15][132 c], reduce over l15 -> g_mx/g_mn
  short* mxs = (short*)red;              // 4*16*132 shorts = 16896 B
  short* mns = mxs + 8448;               // second 16896 B (total 33792 <= 36864)
  int sgl0 = (wv >> 1) * 2;
#pragma unroll
  for (int sp = 0; sp < 2; sp++)
#pragma unroll
    for (int mt = 0; mt < 4; mt++) {
      int c0 = (4 * chh + mt) * 16 + quad * 4;
      int base = ((sgl0 + sp) * 16 + l15) * 132 + c0;
      short4 m4;
      m4.x = f2b(mxP[sp][mt*4+0]); m4.y = f2b(mxP[sp][mt*4+1]);
      m4.z = f2b(mxP[sp][mt*4+2]); m4.w = f2b(mxP[sp][mt*4+3]);
      *(short4*)&mxs[base] = m4;
      short4 n4;
      n4.x = f2b(mnP[sp][mt*4+0]); n4.y = f2b(mnP[sp][mt*4+1]);
      n4.z = f2b(mnP[sp][mt*4+2]); n4.w = f2b(mnP[sp][mt*4+3]);
      *(short4*)&mns[base] = n4;
    }
  __syncthreads();
  {
    int sg = t >> 6, c0 = (t & 63) * 2;   // each thread: 1 s-group, 2 channels
    float m0 = -3.4e38f, m1 = -3.4e38f, n0 = 3.4e38f, n1 = 3.4e38f;
#pragma unroll
    for (int l = 0; l < 16; l++) {
      unsigned ux = *(const unsigned*)&mxs[(sg * 16 + l) * 132 + c0];
      m0 = fmaxf(m0, __uint_as_float(ux << 16));
      m1 = fmaxf(m1, __uint_as_float(ux & 0xFFFF0000u));
      unsigned un = *(const unsigned*)&mns[(sg * 16 + l) * 132 + c0];
      n0 = fminf(n0, __uint_as_float(un << 16));
      n1 = fminf(n1, __uint_as_float(un & 0xFFFF0000u));
    }
    int sgg = blockIdx.x * 4 + sg;
    float2 vmx; vmx.x = m0; vmx.y = m1;
    float2 vmn; vmn.x = n0; vmn.y = n1;
    *(float2*)(g_mx + ((size_t)sgg << 7) + c0) = vmx;
    *(float2*)(g_mn + ((size_t)sgg << 7) + c0) = vmn;
  }
  __syncthreads();
  // phase B: BN2 stats (r12 pattern), 128 channels from 2 waves each
  int rb = t * 36;
#pragma unroll
  for (int w = 0; w < 4; w++) {
    float4 vs; vs.x = sA[w*4+0]; vs.y = sA[w*4+1]; vs.z = sA[w*4+2]; vs.w = sA[w*4+3];
    float4 vq; vq.x = qA[w*4+0]; vq.y = qA[w*4+1]; vq.z = qA[w*4+2]; vq.w = qA[w*4+3];
    *(float4*)&red[rb + w*4] = vs;
    *(float4*)&red[rb + 16 + w*4] = vq;
  }
  __syncthreads();
  if (t < 128) {
    int c = t;
    int ch2 = c >> 6, mt = (c >> 4) & 3, qd = (c >> 2) & 3, j = c & 3;
    int i = mt * 4 + j;
    float S = 0.f, Q = 0.f;
#pragma unroll
    for (int w = 0; w < 2; w++) {
      int wvv = ch2 + w * 2;
#pragma unroll
      for (int l = 0; l < 16; l++) {
        int row = (wvv * 64 + qd * 16 + l) * 36;
        S += red[row + i];
        Q += red[row + 16 + i];
      }
    }
    float* sh = &g_p2s[blockIdx.x & 7][0];
    atomicAdd(sh + c, S);
    atomicAdd(sh + 128 + c, Q);
  }
}

// ---------------- epilogue: BN2+leaky on precomputed max/min, coalesced r/w ----------------
__global__ __launch_bounds__(256) void k_epi(const float* __restrict__ g2,
                                             const float* __restrict__ b2,
                                             float* __restrict__ out) {
  __shared__ float scA[128], shA[128];
  __shared__ float res[16][132];
  int t = threadIdx.x;
  if (t < 128) {
    float ps = 0.f, pq = 0.f;
#pragma unroll
    for (int s = 0; s < 8; s++) { ps += g_p2s[s][t]; pq += g_p2s[s][128 + t]; }
    float m = ps / P_TOTF;
    float v = pq / P_TOTF - m * m;
    float sc = g2[t] / sqrtf(v + EPSV);
    scA[t] = sc; shA[t] = b2[t] - m * sc;
  }
  __syncthreads();
  int cp = t & 63, sl = t >> 6;        // channels 2cp,2cp+1 ; sl in 0..3
  int c0 = cp * 2, c1 = c0 + 1;
  float sc0 = scA[c0], sh0 = shA[c0];
  float sc1 = scA[c1], sh1 = shA[c1];
  int sg0 = blockIdx.x * 16;
  for (int it = 0; it < 4; it++) {
    int sgl = sl * 4 + it;             // 0..15, each once per block
    size_t off = ((size_t)(sg0 + sgl) << 7) + c0;
    float2 vmx = *(const float2*)(g_mx + off);
    float2 vmn = *(const float2*)(g_mn + off);
    float a0 = (sc0 >= 0.f ? vmx.x : vmn.x) * sc0 + sh0; a0 = fmaxf(a0, 0.1f * a0);
    float a1 = (sc1 >= 0.f ? vmx.y : vmn.y) * sc1 + sh1; a1 = fmaxf(a1, 0.1f * a1);
    res[sgl][c0] = a0; res[sgl][c1] = a1;
  }
  __syncthreads();
  int b = sg0 >> 12, s0 = sg0 & 4095;   // block never straddles b (4096 % 16 == 0)
#pragma unroll
  for (int w = 0; w < 2; w++) {
    int fidx = t * 2 + w;               // 0..511
    int c = fidx >> 2, qi = fidx & 3;
    float4 o;
    o.x = res[qi * 4 + 0][c];
    o.y = res[qi * 4 + 1][c];
    o.z = res[qi * 4 + 2][c];
    o.w = res[qi * 4 + 3][c];
    *(float4*)(out + 24576 + (((size_t)(b * 128 + c)) << 12) + s0 + qi * 4) = o;
  }
}

extern "C" void kernel_launch(void* const* d_in, const int* in_sizes, int n_in,
                              void* d_out, int out_size, void* d_ws, size_t ws_size,
                              hipStream_t stream) {
  (void)in_sizes; (void)n_in; (void)out_size; (void)d_ws; (void)ws_size;
  const float* xyz    = (const float*)d_in[0];
  const float* points = (const float*)d_in[1];
  const float* W0     = (const float*)d_in[2];
  const float* W1     = (const float*)d_in[3];
  const float* W2     = (const float*)d_in[4];
  const float* g0     = (const float*)d_in[5];
  const float* b0     = (const float*)d_in[6];
  const float* g1     = (const float*)d_in[7];
  const float* b1     = (const float*)d_in[8];
  const float* g2     = (const float*)d_in[9];
  const float* b2     = (const float*)d_in[10];
  float* out = (float*)d_out;

  hipLaunchKernelGGL(k_pre,   dim3(128),  dim3(256), 0, stream, xyz, out);
  hipLaunchKernelGGL(k_knn,   dim3(2561), dim3(256), 0, stream, points, W0, W1, W2);
  hipLaunchKernelGGL(k_l0,    dim3(2048), dim3(256), 0, stream);
  hipLaunchKernelGGL(k_l1,    dim3(2048), dim3(256), 0, stream, g0, b0);
  hipLaunchKernelGGL(k_l2,    dim3(2048), dim3(256), 0, stream, g1, b1);
  hipLaunchKernelGGL(k_epi,   dim3(512),  dim3(256), 0, stream, g2, b2, out);
}

// Round 17
// 254.578 us; speedup vs baseline: 1.2263x; 1.0199x over previous
//
#include <hip/hip_runtime.h>
#include <hip/hip_bf16.h>
#include <stdint.h>

#define N_ALL   16384
#define NPOINT  4096
#define KNN_K   32
#define BATCH   2
#define P_TOT   (BATCH*NPOINT*KNN_K)   /* 262144 */
#define P_TOTF  262144.0f
#define EPSV    1e-5f

typedef __attribute__((ext_vector_type(8))) short bf16x8;
typedef __attribute__((ext_vector_type(4))) float f32x4;

// ---- all scratch in module-static device memory; d_ws untouched ----
__device__ unsigned short g_knn[P_TOT];                                   // 512 KB
__device__ __attribute__((aligned(16))) float g_pxyzn[BATCH*N_ALL*4];     // 512 KB (x,y,z,|x|^2)
__device__ __attribute__((aligned(16))) short g_ptb[BATCH*N_ALL*64];      // 4 MB  [b,n][64c] bf16
__device__ __attribute__((aligned(16))) short g_x0b[(size_t)P_TOT*64];    // 32 MB [p][64] bf16
__device__ __attribute__((aligned(16))) short g_x1b[(size_t)P_TOT*64];    // 32 MB
__device__ __attribute__((aligned(16))) float g_mx[(size_t)BATCH*NPOINT*128];  // 4 MB
__device__ __attribute__((aligned(16))) float g_mn[(size_t)BATCH*NPOINT*128];  // 4 MB
__device__ __attribute__((aligned(16))) short g_Wb0[4*3*64*8];            // swizzled A-frags
__device__ __attribute__((aligned(16))) short g_Wb1[4*2*64*8];
__device__ __attribute__((aligned(16))) short g_Wb2[8*2*64*8];
__device__ float g_p0s[8][128];      // BN0 stats shadows (2048 blocks / 8 = 256/addr)
__device__ float g_p1s[8][128];      // BN1 stats shadows (2048 blocks / 8 = 256/addr)
__device__ float g_p2s[8][256];      // BN2 stats shadows (2048 blocks / 8 = 256/addr)

__device__ __forceinline__ float b2f(short s) {
  union { unsigned u; float f; } v; v.u = ((unsigned)(unsigned short)s) << 16; return v.f;
}
__device__ __forceinline__ short f2b(float f) {
  union { float f; unsigned u; } v; v.f = f;
  unsigned u = v.u;
  u += 0x7FFFu + ((u >> 16) & 1u);
  return (short)(u >> 16);
}
// packed f32x2 -> bf16x2 (v_cvt_pk_bf16_f32, RNE — bit-identical to f2b pairs)
__device__ __forceinline__ unsigned pkbf(float a, float b) {
  union { __hip_bfloat162 h; unsigned u; } v;
  v.h = __float22bfloat162_rn(make_float2(a, b));
  return v.u;
}
__device__ __forceinline__ unsigned long long bperm64(unsigned long long v, int byteaddr) {
  int lo = __builtin_amdgcn_ds_bpermute(byteaddr, (int)(unsigned)(v & 0xFFFFFFFFULL));
  int hi = __builtin_amdgcn_ds_bpermute(byteaddr, (int)(unsigned)(v >> 32));
  return (((unsigned long long)(unsigned)hi) << 32) | (unsigned)lo;
}
__device__ __forceinline__ unsigned long long u64min(unsigned long long a, unsigned long long b) {
  return a < b ? a : b;
}
// bitonic compare-exchange step: keep min (mx=0) or max (mx=1) of (v, pv)
__device__ __forceinline__ unsigned long long selstage(unsigned long long v,
                                                       unsigned long long pv, bool mx) {
  bool lt = v < pv;
  return (lt != mx) ? v : pv;
}

// sort 32 buffered candidates (vB, one per lane within a 32-lane half) ascending,
// merge lowest-32 of (vL ∪ vB) back into vL (sorted), refresh worst_hi/wd.
__device__ __forceinline__ void knn_merge32(unsigned long long& vL,
                                            unsigned long long& worst,
                                            unsigned& worst_hi, float& wd,
                                            unsigned long long vB, int hl,
                                            int aX1, int aX2, int aX4, int aX8,
                                            int aX16, int aRev, int aW) {
  vB = selstage(vB, bperm64(vB, aX1),  ((hl & 1) != 0) != ((hl & 2) != 0));
  vB = selstage(vB, bperm64(vB, aX2),  ((hl & 2) != 0) != ((hl & 4) != 0));
  vB = selstage(vB, bperm64(vB, aX1),  ((hl & 1) != 0) != ((hl & 4) != 0));
  vB = selstage(vB, bperm64(vB, aX4),  ((hl & 4) != 0) != ((hl & 8) != 0));
  vB = selstage(vB, bperm64(vB, aX2),  ((hl & 2) != 0) != ((hl & 8) != 0));
  vB = selstage(vB, bperm64(vB, aX1),  ((hl & 1) != 0) != ((hl & 8) != 0));
  vB = selstage(vB, bperm64(vB, aX8),  ((hl & 8) != 0) != ((hl & 16) != 0));
  vB = selstage(vB, bperm64(vB, aX4),  ((hl & 4) != 0) != ((hl & 16) != 0));
  vB = selstage(vB, bperm64(vB, aX2),  ((hl & 2) != 0) != ((hl & 16) != 0));
  vB = selstage(vB, bperm64(vB, aX1),  ((hl & 1) != 0) != ((hl & 16) != 0));
  vB = selstage(vB, bperm64(vB, aX16), (hl & 16) != 0);
  vB = selstage(vB, bperm64(vB, aX8),  (hl & 8) != 0);
  vB = selstage(vB, bperm64(vB, aX4),  (hl & 4) != 0);
  vB = selstage(vB, bperm64(vB, aX2),  (hl & 2) != 0);
  vB = selstage(vB, bperm64(vB, aX1),  (hl & 1) != 0);
  // vL asc, vB asc: pair lane i with reversed buffer -> lowest 32 (bitonic), then cleanup
  vL = u64min(vL, bperm64(vB, aRev));
  vL = selstage(vL, bperm64(vL, aX16), (hl & 16) != 0);
  vL = selstage(vL, bperm64(vL, aX8),  (hl & 8) != 0);
  vL = selstage(vL, bperm64(vL, aX4),  (hl & 4) != 0);
  vL = selstage(vL, bperm64(vL, aX2),  (hl & 2) != 0);
  vL = selstage(vL, bperm64(vL, aX1),  (hl & 1) != 0);
  worst = bperm64(vL, aW);
  worst_hi = (unsigned)(worst >> 32);
  unsigned wh = worst_hi;
  unsigned ub = (wh & 0x80000000u) ? (wh ^ 0x80000000u) : ~wh;
  wd = (wh == 0xFFFFFFFFu) ? __builtin_inff() : __uint_as_float(ub);
}

// ---------------- pre: pxyzn pack + out xyz-copy (the only knn dependencies) ----------------
__global__ __launch_bounds__(256) void k_pre(const float* __restrict__ xyz,
                                             float* __restrict__ out) {
#pragma clang fp contract(off)
  int i = blockIdx.x * 256 + threadIdx.x;   // < 32768
  if (i < 24576) {
    int s = i & 4095;
    int c = (i >> 12) % 3;
    int b = i / 12288;
    out[i] = xyz[(b * 3 + c) * N_ALL + s];
  }
  int b = i >> 14, n = i & 16383;
  const float* xb = xyz + b * 3 * N_ALL;
  float x = xb[n], y = xb[N_ALL + n], z = xb[2 * N_ALL + n];
  float4 p; p.x = x; p.y = y; p.z = z; p.w = x * x + y * y + z * z;
  ((float4*)g_pxyzn)[i] = p;
}

// ---------------- knn+setup: blocks 0-511 tpose | 512 wprep | 513+ knn ----------------
__global__ __launch_bounds__(256, 8) void k_knn(const float* __restrict__ points,
                                                const float* __restrict__ W0,
                                                const float* __restrict__ W1,
                                                const float* __restrict__ W2) {
#pragma clang fp contract(off)
  __shared__ __attribute__((aligned(16))) char smem[64 * 65 * 4];   // 16.6 KB arena
  int blk = blockIdx.x;
  int t = threadIdx.x;
  if (blk < 512) {
    // ------- transpose points -> g_ptb (bf16 [b,n][64c]) -------
    float (*tile)[65] = (float(*)[65])smem;
    int b  = blk >> 8;
    int n0 = (blk & 255) << 6;
#pragma unroll
    for (int r = 0; r < 16; r++) {
      int lin = r * 256 + t;
      int c = lin >> 6, nn = lin & 63;
      tile[c][nn] = points[((size_t)(b * 64 + c)) * N_ALL + n0 + nn];
    }
    __syncthreads();
#pragma unroll
    for (int r = 0; r < 16; r++) {
      int lin = r * 256 + t;
      int nn = lin >> 6, c = lin & 63;
      g_ptb[((size_t)(b * N_ALL + n0 + nn)) * 64 + c] = f2b(tile[c][nn]);
    }
    return;
  }
  if (blk == 512) {
    // ------- W-prep + stats-shadow zeroing -------
    for (int i = t; i < 4 * 3 * 64 * 8; i += 256) {
      int j = i & 7, lane = (i >> 3) & 63, rest = i >> 9;
      int kt = rest % 3, mt = rest / 3;
      int m = 16 * mt + (lane & 15);
      int k = 32 * kt + (lane >> 4) * 8 + j;
      float v = 0.f;
      if (k < 64) v = W0[m * 67 + 3 + k];
      else if (k < 67) v = W0[m * 67 + (k - 64)];
      g_Wb0[i] = f2b(v);
    }
    for (int i = t; i < 4 * 2 * 64 * 8; i += 256) {
      int j = i & 7, lane = (i >> 3) & 63;
      int kt = (i >> 9) & 1, mt = i >> 10;
      int m = 16 * mt + (lane & 15);
      int k = 32 * kt + (lane >> 4) * 8 + j;
      g_Wb1[i] = f2b(W1[m * 64 + k]);
    }
    for (int i = t; i < 8 * 2 * 64 * 8; i += 256) {
      int j = i & 7, lane = (i >> 3) & 63;
      int kt = (i >> 9) & 1, mt = i >> 10;
      int m = 16 * mt + (lane & 15);
      int k = 32 * kt + (lane >> 4) * 8 + j;
      g_Wb2[i] = f2b(W2[m * 64 + k]);
    }
    float* z0 = &g_p0s[0][0];
    float* z1 = &g_p1s[0][0];
    float* z2 = &g_p2s[0][0];
    for (int i = t; i < 1024; i += 256) { z0[i] = 0.f; z1[i] = 0.f; }
    for (int i = t; i < 2048; i += 256) z2[i] = 0.f;
    return;
  }
  // ------- KNN: split-N 2-way, 2 queries/wave, float gate, chunk-deferred merges -------
  int kb = blk - 513;                // 0..2047
  int wv = t >> 6;
  int lane = t & 63;
  int half = lane >> 5;            // 0: lanes 0..31 (query A), 1: lanes 32..63 (query B)
  int hl = lane & 31;
  int lanebase = lane & 32;
  unsigned long long* bufh = (unsigned long long*)smem + (wv * 2 + half) * 160;   // 160 entries/half

  int qpair = wv >> 1;             // waves {0,1} share queries, {2,3} share queries
  int range = wv & 1;              // 0: points [0,8192), 1: [8192,16384)
  int q = kb * 4 + qpair * 2 + half;   // 0..8191
  int b = q >> 12, s = q & 4095;
  const float4* pb = (const float4*)g_pxyzn + (b << 14);
  float4 qp = pb[s];
  float qx = qp.x, qy = qp.y, qz = qp.z, qn = qp.w;

  // hoisted cross-lane byte addresses (stay within own 32-lane half)
  int aX1  = (lanebase | (hl ^ 1))  << 2;
  int aX2  = (lanebase | (hl ^ 2))  << 2;
  int aX4  = (lanebase | (hl ^ 4))  << 2;
  int aX8  = (lanebase | (hl ^ 8))  << 2;
  int aX16 = (lanebase | (hl ^ 16)) << 2;
  int aRev = (lanebase | (31 - hl)) << 2;
  int aW   = (lanebase | 31)        << 2;

  unsigned long long vL = ~0ULL;      // per-half sorted top-32 (ascending by lane)
  unsigned long long worst = ~0ULL;   // per-lane copy of own half's vL[31]
  unsigned worst_hi = 0xFFFFFFFFu;
  float wd = __builtin_inff();        // worst distance as float (conservative gate)
  int F = 0;                          // buffered-candidate count (uniform within half, <=159)

  int base = range << 13;
  for (int n0 = base; n0 < base + 8192; n0 += 128) {
    float4 p0 = pb[n0 + hl];
    float4 p1 = pb[n0 + 32 + hl];
    float4 p2 = pb[n0 + 64 + hl];
    float4 p3 = pb[n0 + 96 + hl];
    float d[4];
    {
      float dt0 = (qx * p0.x + qy * p0.y) + qz * p0.z;   // contract off: exact ref order
      float dt1 = (qx * p1.x + qy * p1.y) + qz * p1.z;
      float dt2 = (qx * p2.x + qy * p2.y) + qz * p2.z;
      float dt3 = (qx * p3.x + qy * p3.y) + qz * p3.z;
      d[0] = __builtin_fmaf(-2.0f, dt0, qn + p0.w);      // == (qn+pn) - 2*dt exactly
      d[1] = __builtin_fmaf(-2.0f, dt1, qn + p1.w);
      d[2] = __builtin_fmaf(-2.0f, dt2, qn + p2.w);
      d[3] = __builtin_fmaf(-2.0f, dt3, qn + p3.w);
    }
    float md = fminf(fminf(d[0], d[1]), fminf(d[2], d[3]));
    if (__ballot(md <= wd)) {
#pragma unroll
      for (int u4 = 0; u4 < 4; u4++) {
        bool sv = d[u4] <= wd;          // float gate: conservative superset of exact u64 test
        unsigned long long bl = __ballot(sv);
        unsigned mb = half ? (unsigned)(bl >> 32) : (unsigned)bl;
        if (sv) {                       // survivors only: build exact u64 key (masked, no branch)
          unsigned u = __float_as_uint(d[u4]);
          u ^= ((unsigned)(((int)u) >> 31)) | 0x80000000u;   // order-preserving map
          unsigned long long c = (((unsigned long long)u) << 32)
                               | (unsigned)(n0 + 32 * u4 + hl);
          bufh[F + __popc(mb & ((1u << hl) - 1u))] = c;
        }
        F += __popc(mb);
      }
      while (__ballot(F >= 32)) {       // merge-drain once per chunk (wave-coherent)
        int take = F >= 32 ? 32 : F;    // partner half consumes its partial buffer
        unsigned long long vB = (hl < take) ? bufh[hl] : ~0ULL;
        knn_merge32(vL, worst, worst_hi, wd, vB, hl,
                    aX1, aX2, aX4, aX8, aX16, aRev, aW);
        int R = F - take;               // 0..127
        for (int j = hl; j < R; j += 32)          // reads stay >= one stride ahead of writes
          bufh[j] = bufh[j + take];
        F = R;
      }
    }
  }
  if (__ballot(F > 0)) {   // flush remaining (<32) with +inf padding
    unsigned long long vB = (hl < F) ? bufh[hl] : ~0ULL;
    knn_merge32(vL, worst, worst_hi, wd, vB, hl, aX1, aX2, aX4, aX8, aX16, aRev, aW);
  }

  // cross-wave combine: waves (2k, 2k+1) hold lo/hi top-32 for the same queries
  bufh[hl] = vL;
  __syncthreads();
  unsigned long long vB = *((unsigned long long*)smem + ((wv ^ 1) * 2 + half) * 160 + hl);
  vL = u64min(vL, bperm64(vB, aRev));            // both sorted asc: reverse-pair min
  vL = selstage(vL, bperm64(vL, aX16), (hl & 16) != 0);
  vL = selstage(vL, bperm64(vL, aX8),  (hl & 8) != 0);
  vL = selstage(vL, bperm64(vL, aX4),  (hl & 4) != 0);
  vL = selstage(vL, bperm64(vL, aX2),  (hl & 2) != 0);
  vL = selstage(vL, bperm64(vL, aX1),  (hl & 1) != 0);
  if (range == 0)
    g_knn[((size_t)q << 5) | hl] = (unsigned short)(vL & 0xFFFF);
}

// ---------------- layer0: 128 pts/block (26.6 KB LDS, 6 blk/CU), pxyzn diffs, fused BN0 stats ----------------
__global__ __launch_bounds__(256) void k_l0() {
  __shared__ __attribute__((aligned(16))) short feats[128][104];   // 26.6 KB; reused as 20.5 KB f32 scratch
  int t = threadIdx.x;
  int p0 = blockIdx.x * 128;
  {
    int pt = t >> 1, h = t & 1;       // 2 threads per point
    int p = p0 + pt;
    int idx = g_knn[p];
    int s = (p >> 5) & 4095;
    int b = p >> 17;
    const short* src = g_ptb + ((size_t)((b << 14) + idx) << 6) + h * 32;
#pragma unroll
    for (int i = 0; i < 4; i++)
      ((int4*)&feats[pt][h * 32])[i] = ((const int4*)src)[i];
    if (h == 0) {
      const float4* pb4 = (const float4*)g_pxyzn + (b << 14);
      float4 a = pb4[idx], q = pb4[s];      // exact copies of xyz -> bit-identical diffs
      short4 d3;
      d3.x = f2b(a.x - q.x);
      d3.y = f2b(a.y - q.y);
      d3.z = f2b(a.z - q.z);
      d3.w = 0;
      *(short4*)&feats[pt][64] = d3;
      short4 z4; z4.x = 0; z4.y = 0; z4.z = 0; z4.w = 0;
      *(short4*)&feats[pt][68] = z4;
    } else {
      int4 z; z.x = 0; z.y = 0; z.z = 0; z.w = 0;
      *(int4*)&feats[pt][72] = z;
      *(int4*)&feats[pt][80] = z;
      *(int4*)&feats[pt][88] = z;
    }
  }
  __syncthreads();
  int lane = t & 63, wv = t >> 6;
  int l15 = lane & 15, quad = lane >> 4;
  bf16x8 A[4][3];
#pragma unroll
  for (int mt = 0; mt < 4; mt++)
#pragma unroll
    for (int kt = 0; kt < 3; kt++)
      A[mt][kt] = *(const bf16x8*)(g_Wb0 + (((mt * 3 + kt) * 64 + lane) << 3));
  f32x4 C[4][2];
#pragma unroll
  for (int mt = 0; mt < 4; mt++)
#pragma unroll
    for (int nt = 0; nt < 2; nt++) C[mt][nt] = 0.f;
#pragma unroll
  for (int kt = 0; kt < 3; kt++)
#pragma unroll
    for (int nt = 0; nt < 2; nt++) {
      bf16x8 B = *(const bf16x8*)(&feats[wv * 32 + nt * 16 + l15][kt * 32 + quad * 8]);
#pragma unroll
      for (int mt = 0; mt < 4; mt++)
        C[mt][nt] = __builtin_amdgcn_mfma_f32_16x16x32_bf16(A[mt][kt], B, C[mt][nt], 0, 0, 0);
    }
  float sA[16], qA[16];
#pragma unroll
  for (int i = 0; i < 16; i++) { sA[i] = 0.f; qA[i] = 0.f; }
#pragma unroll
  for (int mt = 0; mt < 4; mt++)
#pragma unroll
    for (int nt = 0; nt < 2; nt++) {
      int p = p0 + wv * 32 + nt * 16 + l15;
      int c0 = mt * 16 + quad * 4;
      uint2 o;
      o.x = pkbf(C[mt][nt][0], C[mt][nt][1]);
      o.y = pkbf(C[mt][nt][2], C[mt][nt][3]);
      *(uint2*)(g_x0b + ((size_t)p << 6) + c0) = o;
      float v0 = __uint_as_float(o.x << 16);
      float v1 = __uint_as_float(o.x & 0xFFFF0000u);
      float v2 = __uint_as_float(o.y << 16);
      float v3 = __uint_as_float(o.y & 0xFFFF0000u);
      int ib = mt * 4;
      sA[ib+0] += v0; qA[ib+0] = fmaf(v0, v0, qA[ib+0]);
      sA[ib+1] += v1; qA[ib+1] = fmaf(v1, v1, qA[ib+1]);
      sA[ib+2] += v2; qA[ib+2] = fmaf(v2, v2, qA[ib+2]);
      sA[ib+3] += v3; qA[ib+3] = fmaf(v3, v3, qA[ib+3]);
    }
  // fused BN0 stats, two-pass (S then Q) through 256x20 f32 scratch (20.5 KB)
  __syncthreads();                       // all waves done reading feats
  float* red = (float*)&feats[0][0];
  int rb = t * 20;
#pragma unroll
  for (int w = 0; w < 4; w++) {
    float4 vs; vs.x = sA[w*4+0]; vs.y = sA[w*4+1]; vs.z = sA[w*4+2]; vs.w = sA[w*4+3];
    *(float4*)&red[rb + w*4] = vs;
  }
  __syncthreads();
  float* sh = &g_p0s[blockIdx.x & 7][0];
  if (t < 64) {
    int qd = (t >> 2) & 3;               // quad of channel t
    int i = ((t >> 4) << 2) | (t & 3);   // register index mt*4+j
    float S = 0.f;
#pragma unroll
    for (int w = 0; w < 4; w++)
#pragma unroll
      for (int l = 0; l < 16; l++)
        S += red[(w * 64 + qd * 16 + l) * 20 + i];
    atomicAdd(sh + t, S);
  }
  __syncthreads();
#pragma unroll
  for (int w = 0; w < 4; w++) {
    float4 vq; vq.x = qA[w*4+0]; vq.y = qA[w*4+1]; vq.z = qA[w*4+2]; vq.w = qA[w*4+3];
    *(float4*)&red[rb + w*4] = vq;
  }
  __syncthreads();
  if (t < 64) {
    int qd = (t >> 2) & 3;
    int i = ((t >> 4) << 2) | (t & 3);
    float Q = 0.f;
#pragma unroll
    for (int w = 0; w < 4; w++)
#pragma unroll
      for (int l = 0; l < 16; l++)
        Q += red[(w * 64 + qd * 16 + l) * 20 + i];
    atomicAdd(sh + 64 + t, Q);
  }
}

// ---------------- layer1: 128 pts/block, C[4][2] (VGPR diet), fused BN1 stats ----------------
__global__ __launch_bounds__(256) void k_l1(const float* __restrict__ g0,
                                            const float* __restrict__ b0) {
  __shared__ float scA[64], shA[64];
  __shared__ __attribute__((aligned(16))) float red[256 * 20];   // 20.5 KB stats scratch
  int t = threadIdx.x;
  if (t < 64) {
    float ps = 0.f, pq = 0.f;
#pragma unroll
    for (int s = 0; s < 8; s++) { ps += g_p0s[s][t]; pq += g_p0s[s][64 + t]; }
    float m = ps / P_TOTF;
    float v = pq / P_TOTF - m * m;
    float sc = g0[t] / sqrtf(v + EPSV);
    scA[t] = sc; shA[t] = b0[t] - m * sc;
  }
  __syncthreads();
  int lane = t & 63, wv = t >> 6;
  int l15 = lane & 15, quad = lane >> 4;
  int p0 = blockIdx.x * 128 + wv * 32;
  float scv[2][8], shv[2][8];
#pragma unroll
  for (int kt = 0; kt < 2; kt++)
#pragma unroll
    for (int j = 0; j < 8; j++) {
      int c = kt * 32 + quad * 8 + j;
      scv[kt][j] = scA[c]; shv[kt][j] = shA[c];
    }
  bf16x8 A[4][2];
#pragma unroll
  for (int mt = 0; mt < 4; mt++)
#pragma unroll
    for (int kt = 0; kt < 2; kt++)
      A[mt][kt] = *(const bf16x8*)(g_Wb1 + (((mt * 2 + kt) * 64 + lane) << 3));
  f32x4 C[4][2];
#pragma unroll
  for (int mt = 0; mt < 4; mt++)
#pragma unroll
    for (int nt = 0; nt < 2; nt++) C[mt][nt] = 0.f;
#pragma unroll
  for (int kt = 0; kt < 2; kt++)
#pragma unroll
    for (int nt = 0; nt < 2; nt++) {
      const short* src = g_x0b + (((size_t)(p0 + nt * 16 + l15)) << 6) + kt * 32 + quad * 8;
      uint4 raw = *(const uint4*)src;
      bf16x8 B;
      unsigned* Bu = (unsigned*)&B;
      unsigned ru[4] = {raw.x, raw.y, raw.z, raw.w};
#pragma unroll
      for (int jj = 0; jj < 4; jj++) {
        float lo = __uint_as_float(ru[jj] << 16);
        float hi = __uint_as_float(ru[jj] & 0xFFFF0000u);
        float a0 = lo * scv[kt][2*jj]   + shv[kt][2*jj];
        float a1 = hi * scv[kt][2*jj+1] + shv[kt][2*jj+1];
        a0 = fmaxf(a0, 0.1f * a0);
        a1 = fmaxf(a1, 0.1f * a1);
        Bu[jj] = pkbf(a0, a1);
      }
#pragma unroll
      for (int mt = 0; mt < 4; mt++)
        C[mt][nt] = __builtin_amdgcn_mfma_f32_16x16x32_bf16(A[mt][kt], B, C[mt][nt], 0, 0, 0);
    }
  float sA[16], qA[16];
#pragma unroll
  for (int i = 0; i < 16; i++) { sA[i] = 0.f; qA[i] = 0.f; }
#pragma unroll
  for (int mt = 0; mt < 4; mt++)
#pragma unroll
    for (int nt = 0; nt < 2; nt++) {
      int p = p0 + nt * 16 + l15;
      int c0 = mt * 16 + quad * 4;
      uint2 o;
      o.x = pkbf(C[mt][nt][0], C[mt][nt][1]);
      o.y = pkbf(C[mt][nt][2], C[mt][nt][3]);
      *(uint2*)(g_x1b + ((size_t)p << 6) + c0) = o;
      float v0 = __uint_as_float(o.x << 16);
      float v1 = __uint_as_float(o.x & 0xFFFF0000u);
      float v2 = __uint_as_float(o.y << 16);
      float v3 = __uint_as_float(o.y & 0xFFFF0000u);
      int ib = mt * 4;
      sA[ib+0] += v0; qA[ib+0] = fmaf(v0, v0, qA[ib+0]);
      sA[ib+1] += v1; qA[ib+1] = fmaf(v1, v1, qA[ib+1]);
      sA[ib+2] += v2; qA[ib+2] = fmaf(v2, v2, qA[ib+2]);
      sA[ib+3] += v3; qA[ib+3] = fmaf(v3, v3, qA[ib+3]);
    }
  // fused BN1 stats, two-pass (S then Q) through 256x20 f32 scratch
  int rb = t * 20;
#pragma unroll
  for (int w = 0; w < 4; w++) {
    float4 vs; vs.x = sA[w*4+0]; vs.y = sA[w*4+1]; vs.z = sA[w*4+2]; vs.w = sA[w*4+3];
    *(float4*)&red[rb + w*4] = vs;
  }
  __syncthreads();
  float* sh = &g_p1s[blockIdx.x & 7][0];
  if (t < 64) {
    int qd = (t >> 2) & 3;
    int i = ((t >> 4) << 2) | (t & 3);
    float S = 0.f;
#pragma unroll
    for (int w = 0; w < 4; w++)
#pragma unroll
      for (int l = 0; l < 16; l++)
        S += red[(w * 64 + qd * 16 + l) * 20 + i];
    atomicAdd(sh + t, S);
  }
  __syncthreads();
#pragma unroll
  for (int w = 0; w < 4; w++) {
    float4 vq; vq.x = qA[w*4+0]; vq.y = qA[w*4+1]; vq.z = qA[w*4+2]; vq.w = qA[w*4+3];
    *(float4*)&red[rb + w*4] = vq;
  }
  __syncthreads();
  if (t < 64) {
    int qd = (t >> 2) & 3;
    int i = ((t >> 4) << 2) | (t & 3);
    float Q = 0.f;
#pragma unroll
    for (int w = 0; w < 4; w++)
#pragma unroll
      for (int l = 0; l < 16; l++)
        Q += red[(w * 64 + qd * 16 + l) * 20 + i];
    atomicAdd(sh + 64 + t, Q);
  }
}

// ---------------- layer2: BN1+leaky, MFMA M=128; fused k-max/min + BN2 stats (x2 never hits HBM) ----------------
__global__ __launch_bounds__(256) void k_l2(const float* __restrict__ g1,
                                            const float* __restrict__ b1) {
  __shared__ float scA[64], shA[64];
  __shared__ __attribute__((aligned(16))) float red[9216];   // 36 KB scratch (phase A: bf16 mx/mn; phase B: stats)
  int t = threadIdx.x;
  if (t < 64) {
    float ps = 0.f, pq = 0.f;
#pragma unroll
    for (int s = 0; s < 8; s++) { ps += g_p1s[s][t]; pq += g_p1s[s][64 + t]; }
    float m = ps / P_TOTF;
    float v = pq / P_TOTF - m * m;
    float sc = g1[t] / sqrtf(v + EPSV);
    scA[t] = sc; shA[t] = b1[t] - m * sc;
  }
  __syncthreads();
  int lane = t & 63, wv = t >> 6;
  int l15 = lane & 15, quad = lane >> 4;
  int chh = wv & 1;                      // channel half
  int p0 = blockIdx.x * 128 + (wv >> 1) * 64;
  float scv[2][8], shv[2][8];
#pragma unroll
  for (int kt = 0; kt < 2; kt++)
#pragma unroll
    for (int j = 0; j < 8; j++) {
      int c = kt * 32 + quad * 8 + j;
      scv[kt][j] = scA[c]; shv[kt][j] = shA[c];
    }
  bf16x8 A[4][2];
#pragma unroll
  for (int mt = 0; mt < 4; mt++)
#pragma unroll
    for (int kt = 0; kt < 2; kt++)
      A[mt][kt] = *(const bf16x8*)(g_Wb2 + ((((4 * chh + mt) * 2 + kt) * 64 + lane) << 3));
  f32x4 C[4][4];
#pragma unroll
  for (int mt = 0; mt < 4; mt++)
#pragma unroll
    for (int nt = 0; nt < 4; nt++) C[mt][nt] = 0.f;
#pragma unroll
  for (int kt = 0; kt < 2; kt++)
#pragma unroll
    for (int nt = 0; nt < 4; nt++) {
      const short* src = g_x1b + (((size_t)(p0 + nt * 16 + l15)) << 6) + kt * 32 + quad * 8;
      uint4 raw = *(const uint4*)src;
      bf16x8 B;
      unsigned* Bu = (unsigned*)&B;
      unsigned ru[4] = {raw.x, raw.y, raw.z, raw.w};
#pragma unroll
      for (int jj = 0; jj < 4; jj++) {
        float lo = __uint_as_float(ru[jj] << 16);
        float hi = __uint_as_float(ru[jj] & 0xFFFF0000u);
        float a0 = lo * scv[kt][2*jj]   + shv[kt][2*jj];
        float a1 = hi * scv[kt][2*jj+1] + shv[kt][2*jj+1];
        a0 = fmaxf(a0, 0.1f * a0);
        a1 = fmaxf(a1, 0.1f * a1);
        Bu[jj] = pkbf(a0, a1);
      }
#pragma unroll
      for (int mt = 0; mt < 4; mt++)
        C[mt][nt] = __builtin_amdgcn_mfma_f32_16x16x32_bf16(A[mt][kt], B, C[mt][nt], 0, 0, 0);
    }
  // per-lane: bf16-rounded values -> stats accum + per-s-subgroup partial max/min
  float sA[16], qA[16];
  float mxP[2][16], mnP[2][16];
#pragma unroll
  for (int i = 0; i < 16; i++) {
    sA[i] = 0.f; qA[i] = 0.f;
    mxP[0][i] = -3.4e38f; mnP[0][i] = 3.4e38f;
    mxP[1][i] = -3.4e38f; mnP[1][i] = 3.4e38f;
  }
#pragma unroll
  for (int mt = 0; mt < 4; mt++)
#pragma unroll
    for (int nt = 0; nt < 4; nt++) {
      unsigned ox = pkbf(C[mt][nt][0], C[mt][nt][1]);
      unsigned oy = pkbf(C[mt][nt][2], C[mt][nt][3]);
      float v0 = __uint_as_float(ox << 16);
      float v1 = __uint_as_float(ox & 0xFFFF0000u);
      float v2 = __uint_as_float(oy << 16);
      float v3 = __uint_as_float(oy & 0xFFFF0000u);
      int ib = mt * 4, sp = nt >> 1;
      sA[ib+0] += v0; qA[ib+0] = fmaf(v0, v0, qA[ib+0]);
      sA[ib+1] += v1; qA[ib+1] = fmaf(v1, v1, qA[ib+1]);
      sA[ib+2] += v2; qA[ib+2] = fmaf(v2, v2, qA[ib+2]);
      sA[ib+3] += v3; qA[ib+3] = fmaf(v3, v3, qA[ib+3]);
      mxP[sp][ib+0] = fmaxf(mxP[sp][ib+0], v0); mnP[sp][ib+0] = fminf(mnP[sp][ib+0], v0);
      mxP[sp][ib+1] = fmaxf(mxP[sp][ib+1], v1); mnP[sp][ib+1] = fminf(mnP[sp][ib+1], v1);
      mxP[sp][ib+2] = fmaxf(mxP[sp][ib+2], v2); mnP[sp][ib+2] = fminf(mnP[sp][ib+2], v2);
      mxP[sp][ib+3] = fmaxf(mxP[sp][ib+3], v3); mnP[sp][ib+3] = fminf(mnP[sp][ib+3], v3);
    }
  // phase A: bf16 partial max/min -> LDS [4 sg][16 l15][132 c], reduce over l15 -> g_mx/g_mn
  short* mxs = (short*)red;              // 4*16*132 shorts = 16896 B
  short* mns = mxs + 8448;               // second 16896 B (total 33792 <= 36864)
  int sgl0 = (wv >> 1) * 2;
#pragma unroll
  for (int sp = 0; sp < 2; sp++)
#pragma unroll
    for (int mt = 0; mt < 4; mt++) {
      int c0 = (4 * chh + mt) * 16 + quad * 4;
      int base = ((sgl0 + sp) * 16 + l15) * 132 + c0;
      short4 m4;
      m4.x = f2b(mxP[sp][mt*4+0]); m4.y = f2b(mxP[sp][mt*4+1]);
      m4.z = f2b(mxP[sp][mt*4+2]); m4.w = f2b(mxP[sp][mt*4+3]);
      *(short4*)&mxs[base] = m4;
      short4 n4;
      n4.x = f2b(mnP[sp][mt*4+0]); n4.y = f2b(mnP[sp][mt*4+1]);
      n4.z = f2b(mnP[sp][mt*4+2]); n4.w = f2b(mnP[sp][mt*4+3]);
      *(short4*)&mns[base] = n4;
    }
  __syncthreads();
  {
    int sg = t >> 6, c0 = (t & 63) * 2;   // each thread: 1 s-group, 2 channels
    float m0 = -3.4e38f, m1 = -3.4e38f, n0 = 3.4e38f, n1 = 3.4e38f;
#pragma unroll
    for (int l = 0; l < 16; l++) {
      unsigned ux = *(const unsigned*)&mxs[(sg * 16 + l) * 132 + c0];
      m0 = fmaxf(m0, __uint_as_float(ux << 16));
      m1 = fmaxf(m1, __uint_as_float(ux & 0xFFFF0000u));
      unsigned un = *(const unsigned*)&mns[(sg * 16 + l) * 132 + c0];
      n0 = fminf(n0, __uint_as_float(un << 16));
      n1 = fminf(n1, __uint_as_float(un & 0xFFFF0000u));
    }
    int sgg = blockIdx.x * 4 + sg;
    float2 vmx; vmx.x = m0; vmx.y = m1;
    float2 vmn; vmn.x = n0; vmn.y = n1;
    *(float2*)(g_mx + ((size_t)sgg << 7) + c0) = vmx;
    *(float2*)(g_mn + ((size_t)sgg << 7) + c0) = vmn;
  }
  __syncthreads();
  // phase B: BN2 stats (r12 pattern), 128 channels from 2 waves each
  int rb = t * 36;
#pragma unroll
  for (int w = 0; w < 4; w++) {
    float4 vs; vs.x = sA[w*4+0]; vs.y = sA[w*4+1]; vs.z = sA[w*4+2]; vs.w = sA[w*4+3];
    float4 vq; vq.x = qA[w*4+0]; vq.y = qA[w*4+1]; vq.z = qA[w*4+2]; vq.w = qA[w*4+3];
    *(float4*)&red[rb + w*4] = vs;
    *(float4*)&red[rb + 16 + w*4] = vq;
  }
  __syncthreads();
  if (t < 128) {
    int c = t;
    int ch2 = c >> 6, mt = (c >> 4) & 3, qd = (c >> 2) & 3, j = c & 3;
    int i = mt * 4 + j;
    float S = 0.f, Q = 0.f;
#pragma unroll
    for (int w = 0; w < 2; w++) {
      int wvv = ch2 + w * 2;
#pragma unroll
      for (int l = 0; l < 16; l++) {
        int row = (wvv * 64 + qd * 16 + l) * 36;
        S += red[row + i];
        Q += red[row + 16 + i];
      }
    }
    float* sh = &g_p2s[blockIdx.x & 7][0];
    atomicAdd(sh + c, S);
    atomicAdd(sh + 128 + c, Q);
  }
}

// ---------------- epilogue: BN2+leaky on precomputed max/min, coalesced r/w ----------------
__global__ __launch_bounds__(256) void k_epi(const float* __restrict__ g2,
                                             const float* __restrict__ b2,
                                             float* __restrict__ out) {
  __shared__ float scA[128], shA[128];
  __shared__ float res[16][132];
  int t = threadIdx.x;
  if (t < 128) {
    float ps = 0.f, pq = 0.f;
#pragma unroll
    for (int s = 0; s < 8; s++) { ps += g_p2s[s][t]; pq += g_p2s[s][128 + t]; }
    float m = ps / P_TOTF;
    float v = pq / P_TOTF - m * m;
    float sc = g2[t] / sqrtf(v + EPSV);
    scA[t] = sc; shA[t] = b2[t] - m * sc;
  }
  __syncthreads();
  int cp = t & 63, sl = t >> 6;        // channels 2cp,2cp+1 ; sl in 0..3
  int c0 = cp * 2, c1 = c0 + 1;
  float sc0 = scA[c0], sh0 = shA[c0];
  float sc1 = scA[c1], sh1 = shA[c1];
  int sg0 = blockIdx.x * 16;
  for (int it = 0; it < 4; it++) {
    int sgl = sl * 4 + it;             // 0..15, each once per block
    size_t off = ((size_t)(sg0 + sgl) << 7) + c0;
    float2 vmx = *(const float2*)(g_mx + off);
    float2 vmn = *(const float2*)(g_mn + off);
    float a0 = (sc0 >= 0.f ? vmx.x : vmn.x) * sc0 + sh0; a0 = fmaxf(a0, 0.1f * a0);
    float a1 = (sc1 >= 0.f ? vmx.y : vmn.y) * sc1 + sh1; a1 = fmaxf(a1, 0.1f * a1);
    res[sgl][c0] = a0; res[sgl][c1] = a1;
  }
  __syncthreads();
  int b = sg0 >> 12, s0 = sg0 & 4095;   // block never straddles b (4096 % 16 == 0)
#pragma unroll
  for (int w = 0; w < 2; w++) {
    int fidx = t * 2 + w;               // 0..511
    int c = fidx >> 2, qi = fidx & 3;
    float4 o;
    o.x = res[qi * 4 + 0][c];
    o.y = res[qi * 4 + 1][c];
    o.z = res[qi * 4 + 2][c];
    o.w = res[qi * 4 + 3][c];
    *(float4*)(out + 24576 + (((size_t)(b * 128 + c)) << 12) + s0 + qi * 4) = o;
  }
}

extern "C" void kernel_launch(void* const* d_in, const int* in_sizes, int n_in,
                              void* d_out, int out_size, void* d_ws, size_t ws_size,
                              hipStream_t stream) {
  (void)in_sizes; (void)n_in; (void)out_size; (void)d_ws; (void)ws_size;
  const float* xyz    = (const float*)d_in[0];
  const float* points = (const float*)d_in[1];
  const float* W0     = (const float*)d_in[2];
  const float* W1     = (const float*)d_in[3];
  const float* W2     = (const float*)d_in[4];
  const float* g0     = (const float*)d_in[5];
  const float* b0     = (const float*)d_in[6];
  const float* g1     = (const float*)d_in[7];
  const float* b1     = (const float*)d_in[8];
  const float* g2     = (const float*)d_in[9];
  const float* b2     = (const float*)d_in[10];
  float* out = (float*)d_out;

  hipLaunchKernelGGL(k_pre,   dim3(128),  dim3(256), 0, stream, xyz, out);
  hipLaunchKernelGGL(k_knn,   dim3(2561), dim3(256), 0, stream, points, W0, W1, W2);
  hipLaunchKernelGGL(k_l0,    dim3(2048), dim3(256), 0, stream);
  hipLaunchKernelGGL(k_l1,    dim3(2048), dim3(256), 0, stream, g0, b0);
  hipLaunchKernelGGL(k_l2,    dim3(2048), dim3(256), 0, stream, g1, b1);
  hipLaunchKernelGGL(k_epi,   dim3(512),  dim3(256), 0, stream, g2, b2, out);
}